// Round 1
// baseline (1464.168 us; speedup 1.0000x reference)
//
#include <hip/hip_runtime.h>

typedef unsigned short u16;
typedef unsigned int u32;
typedef unsigned long long u64;
typedef __attribute__((ext_vector_type(4))) unsigned short u16x4;
typedef __attribute__((ext_vector_type(8))) unsigned short u16x8;
typedef __attribute__((ext_vector_type(4))) float f32x4;
typedef __attribute__((ext_vector_type(8))) __bf16 bf16x8;

#define DD 2048
#define TT 2048
#define FSH 11008

__device__ __forceinline__ float bf2f(u16 u) {
  union { u32 i; float f; } v; v.i = ((u32)u) << 16; return v.f;
}
__device__ __forceinline__ u16 f2bf(float f) {
  union { float f; u32 i; } v; v.f = f;
  u32 r = v.i + 0x7fffu + ((v.i >> 16) & 1u);
  return (u16)(r >> 16);
}
__device__ __forceinline__ void gld16(const void* g, void* l) {
  __builtin_amdgcn_global_load_lds((const __attribute__((address_space(1))) void*)g,
                                   (__attribute__((address_space(3))) void*)l, 16, 0, 0);
}

// ---------------- RMSNorm: f32 row -> bf16 row ----------------
__global__ __launch_bounds__(256) void rmsnorm_k(const float* __restrict__ x,
                                                 const float* __restrict__ w,
                                                 u16* __restrict__ out) {
  const int t = threadIdx.x;
  const float* xr = x + (size_t)blockIdx.x * DD;
  float4 a = *(const float4*)(xr + t * 8);
  float4 b = *(const float4*)(xr + t * 8 + 4);
  float ss = a.x*a.x + a.y*a.y + a.z*a.z + a.w*a.w
           + b.x*b.x + b.y*b.y + b.z*b.z + b.w*b.w;
#pragma unroll
  for (int m = 1; m < 64; m <<= 1) ss += __shfl_xor(ss, m);
  __shared__ float red[4];
  if ((t & 63) == 0) red[t >> 6] = ss;
  __syncthreads();
  float sc = rsqrtf((red[0] + red[1] + red[2] + red[3]) * (1.f / DD) + 1e-6f);
  float4 wa = *(const float4*)(w + t * 8);
  float4 wb = *(const float4*)(w + t * 8 + 4);
  u16x8 o;
  o[0] = f2bf(a.x * sc * wa.x); o[1] = f2bf(a.y * sc * wa.y);
  o[2] = f2bf(a.z * sc * wa.z); o[3] = f2bf(a.w * sc * wa.w);
  o[4] = f2bf(b.x * sc * wb.x); o[5] = f2bf(b.y * sc * wb.y);
  o[6] = f2bf(b.z * sc * wb.z); o[7] = f2bf(b.w * sc * wb.w);
  *(u16x8*)(out + (size_t)blockIdx.x * DD + t * 8) = o;
}

// ---------------- Transpose+convert: W[R][C] f32 -> Wt[C][R] bf16 ----------------
__global__ __launch_bounds__(256) void transp_k(const float* __restrict__ W,
                                                u16* __restrict__ Wt, int R, int C) {
  __shared__ u16 tile[64 * 72];
  const size_t msz = (size_t)R * C;
  const float* Wm = W + msz * blockIdx.z;
  u16* Wtm = Wt + msz * blockIdx.z;
  const int t = threadIdx.x;
  const int n0 = blockIdx.x * 64, k0 = blockIdx.y * 64;
#pragma unroll
  for (int p = 0; p < 4; ++p) {
    const int kk = (t >> 4) + p * 16;
    const int nn = (t & 15) * 4;
    float4 v = *(const float4*)(Wm + (size_t)(k0 + kk) * C + n0 + nn);
    u16x4 o; o[0] = f2bf(v.x); o[1] = f2bf(v.y); o[2] = f2bf(v.z); o[3] = f2bf(v.w);
    *(u16x4*)(tile + kk * 72 + nn) = o;
  }
  __syncthreads();
#pragma unroll
  for (int p = 0; p < 2; ++p) {
    const int n = (t >> 3) + p * 32;
    const int kb = t & 7;
#pragma unroll
    for (int j = 0; j < 8; ++j) {
      const int k = kb + j * 8;
      Wtm[(size_t)(n0 + n) * R + k0 + k] = tile[k * 72 + n];
    }
  }
}

// ---------------- GEMM: C[M][N] = A[M][K](bf16) * Bt[N][K](bf16)^T, m97-style ----------------
// EPI: 0=f32 store, 1=f32 aux+acc, 2=bf16 store, 3=bf16 silu(aux)*acc, 4=f32 slotw[row]*acc
template <int EPI, bool EXPERT>
__global__ __launch_bounds__(256) void gemm_k(
    const u16* __restrict__ A, const u16* __restrict__ Bt, void* __restrict__ Cp,
    const void* __restrict__ aux, const float* __restrict__ slotw,
    const int* __restrict__ eoff, const int* __restrict__ ecnt,
    int M, int N, int K, int ebase) {
  __shared__ u16 lA[128 * 32];
  __shared__ u16 lB[128 * 32];
  const int t = threadIdx.x, w = t >> 6, l = t & 63;
  const int n0 = blockIdx.x * 128;
  int m0, rowlim;
  if (EXPERT) {
    const int e = ebase + blockIdx.z;
    const int off = eoff[e], cnt = ecnt[e];
    if ((int)blockIdx.y * 128 >= cnt) return;
    m0 = off + blockIdx.y * 128;
    rowlim = off + cnt;
    Bt += (size_t)blockIdx.z * ((size_t)N * K);
  } else {
    m0 = blockIdx.y * 128;
    rowlim = M;
  }
  const int srow = w * 16 + (l >> 2);
  const int scol = (l & 3) * 8;
  int ar0 = m0 + srow, ar1 = m0 + srow + 64;
  if (EXPERT) {
    ar0 = ar0 < rowlim ? ar0 : rowlim - 1;
    ar1 = ar1 < rowlim ? ar1 : rowlim - 1;
  }
  const u16* ag0 = A + (size_t)ar0 * K + scol;
  const u16* ag1 = A + (size_t)ar1 * K + scol;
  const u16* bg0 = Bt + (size_t)(n0 + srow) * K + scol;
  const u16* bg1 = Bt + (size_t)(n0 + srow + 64) * K + scol;
  u16* la = lA + w * 512;
  u16* lb = lB + w * 512;
  const int l15 = l & 15, l4 = l >> 4;
  const int wm = w >> 1, wn = w & 1;
  const int fa = (wm * 64 + l15) * 32 + l4 * 8;
  const int fb = (wn * 64 + l15) * 32 + l4 * 8;
  f32x4 acc[4][4] = {};
  for (int ko = 0; ko < K; ko += 32) {
    __syncthreads();
    gld16(ag0 + ko, la);
    gld16(ag1 + ko, la + 2048);
    gld16(bg0 + ko, lb);
    gld16(bg1 + ko, lb + 2048);
    asm volatile("s_waitcnt vmcnt(0)" ::: "memory");
    __syncthreads();
    bf16x8 af[4], bf[4];
#pragma unroll
    for (int i = 0; i < 4; ++i) {
      af[i] = *(const bf16x8*)(lA + fa + i * 512);
      bf[i] = *(const bf16x8*)(lB + fb + i * 512);
    }
#pragma unroll
    for (int mi = 0; mi < 4; ++mi)
#pragma unroll
      for (int ni = 0; ni < 4; ++ni)
        acc[mi][ni] = __builtin_amdgcn_mfma_f32_16x16x32_bf16(af[mi], bf[ni], acc[mi][ni], 0, 0, 0);
  }
#pragma unroll
  for (int mi = 0; mi < 4; ++mi) {
#pragma unroll
    for (int r = 0; r < 4; ++r) {
      const int row = m0 + wm * 64 + mi * 16 + l4 * 4 + r;
      if (EXPERT && row >= rowlim) continue;
#pragma unroll
      for (int ni = 0; ni < 4; ++ni) {
        const int col = n0 + wn * 64 + ni * 16 + l15;
        const size_t idx = (size_t)row * N + col;
        const float v = acc[mi][ni][r];
        if (EPI == 0) ((float*)Cp)[idx] = v;
        else if (EPI == 1) ((float*)Cp)[idx] = ((const float*)aux)[idx] + v;
        else if (EPI == 2) ((u16*)Cp)[idx] = f2bf(v);
        else if (EPI == 3) {
          const float g = bf2f(((const u16*)aux)[idx]);
          ((u16*)Cp)[idx] = f2bf(v * g / (1.f + __expf(-g)));
        } else {
          ((float*)Cp)[idx] = slotw[row] * v;
        }
      }
    }
  }
}

// ---------------- RoPE + pack Q/K/V + emit new_k/new_v ----------------
__global__ __launch_bounds__(256) void rope_k(
    const float* __restrict__ qkv, const float* __restrict__ cosb, const float* __restrict__ sinb,
    const float* __restrict__ bq, const float* __restrict__ bk, const float* __restrict__ bv,
    u16* __restrict__ QR, u16* __restrict__ KR, u16* __restrict__ VB,
    float* __restrict__ NK, float* __restrict__ NV) {
  const int s = blockIdx.x, b = blockIdx.y, t = threadIdx.x;
  const size_t tok = (size_t)b * 1024 + s;
  const float* row = qkv + tok * 3072;
  const float* cr = cosb + s * 128;
  const float* sr = sinb + s * 128;
  // Q: 16 heads x 64 pairs
  for (int i = t; i < 1024; i += 256) {
    const int h = i >> 6, d = i & 63;
    const float v1 = row[h * 128 + d] + bq[h * 128 + d];
    const float v2 = row[h * 128 + d + 64] + bq[h * 128 + d + 64];
    const float o1 = v1 * cr[d] - v2 * sr[d];
    const float o2 = v2 * cr[d + 64] + v1 * sr[d + 64];
    const size_t qb = (((size_t)(b * 16 + h)) * 1024 + s) * 128;
    QR[qb + d] = f2bf(o1);
    QR[qb + d + 64] = f2bf(o2);
  }
  // K: 4 heads x 64 pairs (t in [0,256))
  {
    const int h = t >> 6, d = t & 63;
    const float v1 = row[2048 + h * 128 + d] + bk[h * 128 + d];
    const float v2 = row[2048 + h * 128 + d + 64] + bk[h * 128 + d + 64];
    const float o1 = v1 * cr[d] - v2 * sr[d];
    const float o2 = v2 * cr[d + 64] + v1 * sr[d + 64];
    const size_t kb = (((size_t)(b * 4 + h)) * 1024 + s) * 128;
    KR[kb + d] = f2bf(o1);
    KR[kb + d + 64] = f2bf(o2);
    const size_t ob = tok * 2048;
#pragma unroll
    for (int rep = 0; rep < 4; ++rep) {
      NK[ob + (h * 4 + rep) * 128 + d] = o1;
      NK[ob + (h * 4 + rep) * 128 + d + 64] = o2;
    }
  }
  // V: 4 heads x 128
  for (int i = t; i < 512; i += 256) {
    const int h = i >> 7, d = i & 127;
    const float v = row[2560 + i] + bv[i];
    VB[(((size_t)(b * 4 + h)) * 1024 + s) * 128 + d] = f2bf(v);
    const size_t ob = tok * 2048;
#pragma unroll
    for (int rep = 0; rep < 4; ++rep) NV[ob + (h * 4 + rep) * 128 + d] = v;
  }
}

// ---------------- Flash attention, 64 q-rows per block, 4 waves x 16 rows ----------------
__global__ __launch_bounds__(256) void attn_k(const u16* __restrict__ Q,
                                              const u16* __restrict__ Kc,
                                              const u16* __restrict__ Vc,
                                              u16* __restrict__ O) {
  const int qt = blockIdx.x, h = blockIdx.y, b = blockIdx.z;
  const int t = threadIdx.x, w = t >> 6, l = t & 63;
  const int kvh = h >> 2;
  __shared__ u16 Ks[64 * 128];     // XOR-swizzled rows
  __shared__ u16 Vt[128 * 66];     // transposed V [d][key], stride 66
  __shared__ u16 Ps[4][16 * 68];   // per-wave P [q][key], stride 68
  const int l15 = l & 15, l4 = l >> 4;
  bf16x8 qf[4];
  {
    const u16* qb = Q + (((size_t)(b * 16 + h)) * 1024 + qt * 64 + w * 16 + l15) * 128 + l4 * 8;
#pragma unroll
    for (int c = 0; c < 4; ++c) qf[c] = *(const bf16x8*)(qb + c * 32);
  }
  float m_run[4] = {-1e30f, -1e30f, -1e30f, -1e30f};
  float l_run[4] = {0.f, 0.f, 0.f, 0.f};
  f32x4 accO[8] = {};
  const size_t kvbase = ((size_t)(b * 4 + kvh)) * 1024 * 128;
  const int ntiles = qt + 1;
  for (int kt = 0; kt < ntiles; ++kt) {
    __syncthreads();
    {
      const int key = t >> 2;
      const u16* kg = Kc + kvbase + (size_t)(kt * 64 + key) * 128;
      const u16* vg = Vc + kvbase + (size_t)(kt * 64 + key) * 128;
      const int sw = (key & 7) << 4;
#pragma unroll
      for (int p = 0; p < 4; ++p) {
        const int ch = (t & 3) * 4 + p;
        *(u16x8*)((char*)Ks + key * 256 + ((ch * 16) ^ sw)) = *(const u16x8*)(kg + ch * 8);
        const int d0 = ch * 8;
        u16x8 vv = *(const u16x8*)(vg + d0);
#pragma unroll
        for (int j = 0; j < 8; ++j) Vt[(d0 + j) * 66 + key] = vv[j];
      }
    }
    __syncthreads();
    f32x4 sf[4] = {};
#pragma unroll
    for (int nf = 0; nf < 4; ++nf) {
      const int keyl = nf * 16 + l15;
      const int sw = (keyl & 7) << 4;
      const char* kbase = (const char*)Ks + keyl * 256;
#pragma unroll
      for (int c = 0; c < 4; ++c) {
        bf16x8 kf = *(const bf16x8*)(kbase + ((c * 64 + l4 * 16) ^ sw));
        sf[nf] = __builtin_amdgcn_mfma_f32_16x16x32_bf16(qf[c], kf, sf[nf], 0, 0, 0);
      }
    }
    const int qg0 = qt * 64 + w * 16 + l4 * 4;
    float alpha[4];
#pragma unroll
    for (int r = 0; r < 4; ++r) {
      const int qg = qg0 + r;
      float tm = -1e30f;
#pragma unroll
      for (int nf = 0; nf < 4; ++nf) {
        const int kg = kt * 64 + nf * 16 + l15;
        float sv = sf[nf][r] * 0.088388347648318447f;
        sv = (kg <= qg) ? sv : -1e30f;
        sf[nf][r] = sv;
        tm = fmaxf(tm, sv);
      }
#pragma unroll
      for (int mm = 1; mm < 16; mm <<= 1) tm = fmaxf(tm, __shfl_xor(tm, mm));
      const float mn = fmaxf(m_run[r], tm);
      alpha[r] = __expf(m_run[r] - mn);
      m_run[r] = mn;
      float rs = 0.f;
#pragma unroll
      for (int nf = 0; nf < 4; ++nf) {
        const float p = __expf(sf[nf][r] - mn);
        sf[nf][r] = p;
        rs += p;
      }
#pragma unroll
      for (int mm = 1; mm < 16; mm <<= 1) rs += __shfl_xor(rs, mm);
      l_run[r] = l_run[r] * alpha[r] + rs;
    }
#pragma unroll
    for (int nf = 0; nf < 8; ++nf)
#pragma unroll
      for (int r = 0; r < 4; ++r) accO[nf][r] *= alpha[r];
#pragma unroll
    for (int nf = 0; nf < 4; ++nf)
#pragma unroll
      for (int r = 0; r < 4; ++r)
        Ps[w][(l4 * 4 + r) * 68 + nf * 16 + l15] = f2bf(sf[nf][r]);
    __syncthreads();
#pragma unroll
    for (int kc = 0; kc < 2; ++kc) {
      const u16* pb = &Ps[w][0] + l15 * 68 + kc * 32 + l4 * 8;
      union { u16x4 q[2]; bf16x8 v; } pu;
      pu.q[0] = *(const u16x4*)pb;
      pu.q[1] = *(const u16x4*)(pb + 4);
#pragma unroll
      for (int nf = 0; nf < 8; ++nf) {
        const int dd = nf * 16 + l15;
        const u16* vp = &Vt[0] + dd * 66 + kc * 32 + l4 * 8;
        union { u32 u[4]; bf16x8 v; } vu;
        vu.u[0] = *(const u32*)(vp);
        vu.u[1] = *(const u32*)(vp + 2);
        vu.u[2] = *(const u32*)(vp + 4);
        vu.u[3] = *(const u32*)(vp + 6);
        accO[nf] = __builtin_amdgcn_mfma_f32_16x16x32_bf16(pu.v, vu.v, accO[nf], 0, 0, 0);
      }
    }
  }
  const int qg0 = qt * 64 + w * 16 + l4 * 4;
#pragma unroll
  for (int nf = 0; nf < 8; ++nf) {
    const int dd = nf * 16 + l15;
#pragma unroll
    for (int r = 0; r < 4; ++r) {
      const float o = accO[nf][r] / l_run[r];
      O[((size_t)(b * 1024 + qg0 + r)) * 2048 + h * 128 + dd] = f2bf(o);
    }
  }
}

// ---------------- Router: f32-exact rmsnorm+logits, softmax, top2, counts, pmean ----------------
__global__ __launch_bounds__(256) void router_k(
    const float* __restrict__ x2, const float* __restrict__ wn, const float* __restrict__ rw,
    int* __restrict__ topi2, float* __restrict__ topw2,
    int* __restrict__ counts, u64* __restrict__ pmean) {
  const int t = threadIdx.x, w = t >> 6, l = t & 63;
  const int tok = blockIdx.x * 4 + w;
  __shared__ int lc[8];
  __shared__ u64 lp[8];
  if (t < 8) { lc[t] = 0; lp[t] = 0ull; }
  __syncthreads();
  const float* xr = x2 + (size_t)tok * DD;
  float ss = 0.f;
#pragma unroll
  for (int i = 0; i < 8; ++i) {
    float4 v = *(const float4*)(xr + l * 32 + i * 4);
    ss += v.x * v.x + v.y * v.y + v.z * v.z + v.w * v.w;
  }
#pragma unroll
  for (int m = 1; m < 64; m <<= 1) ss += __shfl_xor(ss, m);
  const float sc = rsqrtf(ss * (1.f / DD) + 1e-6f);
  float acc[8] = {};
  for (int i = 0; i < 32; ++i) {
    const int d = l * 32 + i;
    const float hv = xr[d] * sc * wn[d];
    float4 r0 = *(const float4*)(rw + d * 8);
    float4 r1 = *(const float4*)(rw + d * 8 + 4);
    acc[0] += hv * r0.x; acc[1] += hv * r0.y; acc[2] += hv * r0.z; acc[3] += hv * r0.w;
    acc[4] += hv * r1.x; acc[5] += hv * r1.y; acc[6] += hv * r1.z; acc[7] += hv * r1.w;
  }
#pragma unroll
  for (int m = 1; m < 64; m <<= 1)
#pragma unroll
    for (int e = 0; e < 8; ++e) acc[e] += __shfl_xor(acc[e], m);
  if (l == 0) {
    float mx = acc[0];
#pragma unroll
    for (int e = 1; e < 8; ++e) mx = fmaxf(mx, acc[e]);
    float p[8], sum = 0.f;
#pragma unroll
    for (int e = 0; e < 8; ++e) { p[e] = __expf(acc[e] - mx); sum += p[e]; }
    const float inv = 1.f / sum;
#pragma unroll
    for (int e = 0; e < 8; ++e) p[e] *= inv;
    int e0 = 0; float v0 = p[0];
#pragma unroll
    for (int e = 1; e < 8; ++e) if (p[e] > v0) { v0 = p[e]; e0 = e; }
    int e1 = (e0 == 0) ? 1 : 0; float v1 = p[e1];
#pragma unroll
    for (int e = 0; e < 8; ++e) if (e != e0 && p[e] > v1) { v1 = p[e]; e1 = e; }
    const float wsum = v0 + v1;
    topi2[tok * 2] = e0; topi2[tok * 2 + 1] = e1;
    topw2[tok * 2] = v0 / wsum; topw2[tok * 2 + 1] = v1 / wsum;
    atomicAdd(&lc[e0], 1); atomicAdd(&lc[e1], 1);
#pragma unroll
    for (int e = 0; e < 8; ++e) atomicAdd(&lp[e], (u64)((double)p[e] * 4294967296.0));
  }
  __syncthreads();
  if (t < 8) {
    if (lc[t]) atomicAdd(&counts[t], lc[t]);
    if (lp[t]) atomicAdd(&pmean[t], lp[t]);
  }
}

__global__ void zero_k(int* counts, u64* pmean) {
  const int t = threadIdx.x;
  if (t < 8) { counts[t] = 0; pmean[t] = 0ull; }
}

__global__ void scan_k(const int* __restrict__ counts, int* __restrict__ offsets,
                       int* __restrict__ cursors, const u64* __restrict__ pmean,
                       float* __restrict__ auxout) {
  if (threadIdx.x == 0) {
    int off = 0;
    double aux = 0.0;
    for (int e = 0; e < 8; ++e) {
      offsets[e] = off; cursors[e] = off; off += counts[e];
      const double pm = ((double)pmean[e] / 4294967296.0) / 2048.0;
      aux += ((double)counts[e] / 4096.0) * pm;
    }
    *auxout = (float)(8.0 * aux);
  }
}

__global__ __launch_bounds__(256) void assign_k(const int* __restrict__ topi2,
                                                const float* __restrict__ topw2,
                                                int* __restrict__ cursors,
                                                int* __restrict__ slot_tok,
                                                float* __restrict__ slot_w,
                                                int* __restrict__ tok_slot) {
  const int tok = blockIdx.x * 256 + threadIdx.x;
#pragma unroll
  for (int j = 0; j < 2; ++j) {
    const int e = topi2[tok * 2 + j];
    const int s = atomicAdd(&cursors[e], 1);
    slot_tok[s] = tok;
    slot_w[s] = topw2[tok * 2 + j];
    tok_slot[tok * 2 + j] = s;
  }
}

__global__ __launch_bounds__(256) void gather_k(const u16* __restrict__ hn,
                                                const int* __restrict__ slot_tok,
                                                u16* __restrict__ hperm) {
  const int slot = blockIdx.x;
  const int tok = slot_tok[slot];
  const u16x8* src = (const u16x8*)(hn + (size_t)tok * DD);
  u16x8* dst = (u16x8*)(hperm + (size_t)slot * DD);
  dst[threadIdx.x] = src[threadIdx.x];
}

__global__ __launch_bounds__(256) void final_k(float* __restrict__ out,
                                               const float* __restrict__ routed,
                                               const int* __restrict__ tok_slot) {
  const int gi = blockIdx.x * 256 + threadIdx.x;  // float4 index
  const int row = gi >> 9;
  const int c = gi & 511;
  const int s0 = tok_slot[row * 2], s1 = tok_slot[row * 2 + 1];
  float4 o = ((const float4*)out)[gi];
  const float4 a = ((const float4*)routed)[(size_t)s0 * 512 + c];
  const float4 b = ((const float4*)routed)[(size_t)s1 * 512 + c];
  o.x += a.x + b.x; o.y += a.y + b.y; o.z += a.z + b.z; o.w += a.w + b.w;
  ((float4*)out)[gi] = o;
}

extern "C" void kernel_launch(void* const* d_in, const int* in_sizes, int n_in,
                              void* d_out, int out_size, void* d_ws, size_t ws_size,
                              hipStream_t stream) {
  (void)in_sizes; (void)n_in; (void)out_size; (void)ws_size;
  const float* x    = (const float*)d_in[0];
  const float* rc   = (const float*)d_in[1];
  const float* rs   = (const float*)d_in[2];
  const float* anw  = (const float*)d_in[3];
  const float* fnw  = (const float*)d_in[4];
  const float* wq   = (const float*)d_in[5];
  const float* bq   = (const float*)d_in[6];
  const float* wk   = (const float*)d_in[7];
  const float* bk   = (const float*)d_in[8];
  const float* wv   = (const float*)d_in[9];
  const float* bv   = (const float*)d_in[10];
  const float* wo   = (const float*)d_in[11];
  const float* rw   = (const float*)d_in[12];
  const float* wg   = (const float*)d_in[13];
  const float* wu   = (const float*)d_in[14];
  const float* wd   = (const float*)d_in[15];
  const float* wsg  = (const float*)d_in[16];
  const float* wsu  = (const float*)d_in[17];
  const float* wsd  = (const float*)d_in[18];

  const size_t MB = (size_t)1 << 20;
  char* ws = (char*)d_ws;
  float* X2      = (float*)(ws + 0);            // 16MB [wo .. end]
  u16*   HN      = (u16*)(ws + 16 * MB);        // 8MB
  float* ROUTED  = (float*)(ws + 24 * MB);      // 32MB
  u16*   WT      = (u16*)(ws + 56 * MB);        // 44MB rotating transposed weights
  char*  E       = ws + 100 * MB;               // 48MB phase region
  u16*   H       = (u16*)(E);                   // 8MB   (attn-norm hidden)
  float* QKVF    = (float*)(E + 8 * MB);        // 24MB  (qkv f32)
  u16*   QR      = (u16*)(E + 32 * MB);         // 8MB
  u16*   KR      = (u16*)(E + 40 * MB);         // 2MB
  u16*   VBb     = (u16*)(E + 42 * MB);         // 2MB
  u16*   ATTNO   = (u16*)(E + 8 * MB);          // 8MB (over QKVF, dead)
  u16*   HPERM   = (u16*)(E);                   // 16MB (over H/ATTNO, dead)
  u16*   GEXP    = (u16*)(E + 16 * MB);         // 16MB
  u16*   AEXP    = (u16*)(E + 32 * MB);         // 16MB
  u16*   GSH     = (u16*)(E);                   // 43MB (shared gate/act, over expert bufs, dead)
  char*  SM      = ws + 100 * MB - 262144;      // small area in WT tail gap
  int*   CNT     = (int*)(SM);
  int*   OFFS    = (int*)(SM + 64);
  int*   CURS    = (int*)(SM + 128);
  u64*   PM      = (u64*)(SM + 192);
  int*   TOPI    = (int*)(SM + 1024);
  float* TOPW    = (float*)(SM + 1024 + 16384);
  int*   STOK    = (int*)(SM + 1024 + 32768);
  float* SW      = (float*)(SM + 1024 + 49152);
  int*   TSLOT   = (int*)(SM + 1024 + 65536);

  float* out  = (float*)d_out;
  float* NK   = out + 4194304;
  float* NV   = out + 2 * 4194304;
  float* AUXO = out + 3 * 4194304;

  const dim3 b256(256);

  // 1) h = rmsnorm(x, attn_norm_w)
  rmsnorm_k<<<TT, b256, 0, stream>>>(x, anw, H);
  // 2) QKV combined GEMM (N=3072)
  transp_k<<<dim3(32, 32, 1), b256, 0, stream>>>(wq, WT, 2048, 2048);
  transp_k<<<dim3(8, 32, 1), b256, 0, stream>>>(wk, WT + (size_t)2048 * 2048, 2048, 512);
  transp_k<<<dim3(8, 32, 1), b256, 0, stream>>>(wv, WT + (size_t)2560 * 2048, 2048, 512);
  gemm_k<0, false><<<dim3(24, 16, 1), b256, 0, stream>>>(H, WT, QKVF, nullptr, nullptr, nullptr, nullptr, TT, 3072, 2048, 0);
  // 3) RoPE + pack + new_k/new_v
  rope_k<<<dim3(1024, 2), b256, 0, stream>>>(QKVF, rc, rs, bq, bk, bv, QR, KR, VBb, NK, NV);
  // 4) attention
  attn_k<<<dim3(16, 16, 2), b256, 0, stream>>>(QR, KR, VBb, ATTNO);
  // 5) x2 = x + attno @ wo
  transp_k<<<dim3(32, 32, 1), b256, 0, stream>>>(wo, WT, 2048, 2048);
  gemm_k<1, false><<<dim3(16, 16, 1), b256, 0, stream>>>(ATTNO, WT, X2, x, nullptr, nullptr, nullptr, TT, 2048, 2048, 0);
  // 6) hn = rmsnorm(x2, ffn_norm_w)
  rmsnorm_k<<<TT, b256, 0, stream>>>(X2, fnw, HN);
  // 7) routing (f32-exact logits from X2)
  zero_k<<<1, 64, 0, stream>>>(CNT, PM);
  router_k<<<512, b256, 0, stream>>>(X2, fnw, rw, TOPI, TOPW, CNT, PM);
  scan_k<<<1, 64, 0, stream>>>(CNT, OFFS, CURS, PM, AUXO);
  assign_k<<<8, b256, 0, stream>>>(TOPI, TOPW, CURS, STOK, SW, TSLOT);
  gather_k<<<4096, b256, 0, stream>>>(HN, STOK, HPERM);
  // 8) routed experts (2 chunks of 4)
  for (int cb = 0; cb < 2; ++cb) {
    const int eb = cb * 4;
    transp_k<<<dim3(32, 32, 4), b256, 0, stream>>>(wg + (size_t)eb * 2048 * 2048, WT, 2048, 2048);
    gemm_k<2, true><<<dim3(16, 16, 4), b256, 0, stream>>>(HPERM, WT, GEXP, nullptr, nullptr, OFFS, CNT, 4096, 2048, 2048, eb);
    transp_k<<<dim3(32, 32, 4), b256, 0, stream>>>(wu + (size_t)eb * 2048 * 2048, WT, 2048, 2048);
    gemm_k<3, true><<<dim3(16, 16, 4), b256, 0, stream>>>(HPERM, WT, AEXP, GEXP, nullptr, OFFS, CNT, 4096, 2048, 2048, eb);
    transp_k<<<dim3(32, 32, 4), b256, 0, stream>>>(wd + (size_t)eb * 2048 * 2048, WT, 2048, 2048);
    gemm_k<4, true><<<dim3(16, 16, 4), b256, 0, stream>>>(AEXP, WT, ROUTED, nullptr, SW, OFFS, CNT, 4096, 2048, 2048, eb);
  }
  // 9) shared expert
  transp_k<<<dim3(172, 32, 1), b256, 0, stream>>>(wsg, WT, 2048, FSH);
  gemm_k<2, false><<<dim3(86, 16, 1), b256, 0, stream>>>(HN, WT, GSH, nullptr, nullptr, nullptr, nullptr, TT, FSH, 2048, 0);
  transp_k<<<dim3(172, 32, 1), b256, 0, stream>>>(wsu, WT, 2048, FSH);
  gemm_k<3, false><<<dim3(86, 16, 1), b256, 0, stream>>>(HN, WT, GSH, GSH, nullptr, nullptr, nullptr, TT, FSH, 2048, 0);
  transp_k<<<dim3(32, 172, 1), b256, 0, stream>>>(wsd, WT, FSH, 2048);
  gemm_k<1, false><<<dim3(16, 16, 1), b256, 0, stream>>>(GSH, WT, out, X2, nullptr, nullptr, nullptr, TT, 2048, FSH, 0);
  // 10) out += routed contributions
  final_k<<<4096, b256, 0, stream>>>(out, ROUTED, TSLOT);
}

// Round 2
// 1149.725 us; speedup vs baseline: 1.2735x; 1.2735x over previous
//
#include <hip/hip_runtime.h>

typedef unsigned short u16;
typedef unsigned int u32;
typedef unsigned long long u64;
typedef __attribute__((ext_vector_type(4))) unsigned short u16x4;
typedef __attribute__((ext_vector_type(8))) unsigned short u16x8;
typedef __attribute__((ext_vector_type(4))) float f32x4;
typedef __attribute__((ext_vector_type(8))) __bf16 bf16x8;

#define DD 2048
#define TT 2048
#define FSH 11008

__device__ __forceinline__ float bf2f(u16 u) {
  union { u32 i; float f; } v; v.i = ((u32)u) << 16; return v.f;
}
__device__ __forceinline__ u16 f2bf(float f) {
  union { float f; u32 i; } v; v.f = f;
  u32 r = v.i + 0x7fffu + ((v.i >> 16) & 1u);
  return (u16)(r >> 16);
}
__device__ __forceinline__ void gld16(const void* g, void* l) {
  __builtin_amdgcn_global_load_lds((const __attribute__((address_space(1))) void*)g,
                                   (__attribute__((address_space(3))) void*)l, 16, 0, 0);
}

// ---------------- RMSNorm: f32 row -> bf16 row ----------------
__global__ __launch_bounds__(256) void rmsnorm_k(const float* __restrict__ x,
                                                 const float* __restrict__ w,
                                                 u16* __restrict__ out) {
  const int t = threadIdx.x;
  const float* xr = x + (size_t)blockIdx.x * DD;
  float4 a = *(const float4*)(xr + t * 8);
  float4 b = *(const float4*)(xr + t * 8 + 4);
  float ss = a.x*a.x + a.y*a.y + a.z*a.z + a.w*a.w
           + b.x*b.x + b.y*b.y + b.z*b.z + b.w*b.w;
#pragma unroll
  for (int m = 1; m < 64; m <<= 1) ss += __shfl_xor(ss, m);
  __shared__ float red[4];
  if ((t & 63) == 0) red[t >> 6] = ss;
  __syncthreads();
  float sc = rsqrtf((red[0] + red[1] + red[2] + red[3]) * (1.f / DD) + 1e-6f);
  float4 wa = *(const float4*)(w + t * 8);
  float4 wb = *(const float4*)(w + t * 8 + 4);
  u16x8 o;
  o[0] = f2bf(a.x * sc * wa.x); o[1] = f2bf(a.y * sc * wa.y);
  o[2] = f2bf(a.z * sc * wa.z); o[3] = f2bf(a.w * sc * wa.w);
  o[4] = f2bf(b.x * sc * wb.x); o[5] = f2bf(b.y * sc * wb.y);
  o[6] = f2bf(b.z * sc * wb.z); o[7] = f2bf(b.w * sc * wb.w);
  *(u16x8*)(out + (size_t)blockIdx.x * DD + t * 8) = o;
}

// ---------------- Transpose+convert: W[R][C] f32 -> Wt[C][R] bf16 ----------------
__global__ __launch_bounds__(256) void transp_k(const float* __restrict__ W,
                                                u16* __restrict__ Wt, int R, int C) {
  __shared__ u16 tile[64 * 72];
  const size_t msz = (size_t)R * C;
  const float* Wm = W + msz * blockIdx.z;
  u16* Wtm = Wt + msz * blockIdx.z;
  const int t = threadIdx.x;
  const int n0 = blockIdx.x * 64, k0 = blockIdx.y * 64;
#pragma unroll
  for (int p = 0; p < 4; ++p) {
    const int kk = (t >> 4) + p * 16;
    const int nn = (t & 15) * 4;
    float4 v = *(const float4*)(Wm + (size_t)(k0 + kk) * C + n0 + nn);
    u16x4 o; o[0] = f2bf(v.x); o[1] = f2bf(v.y); o[2] = f2bf(v.z); o[3] = f2bf(v.w);
    *(u16x4*)(tile + kk * 72 + nn) = o;
  }
  __syncthreads();
#pragma unroll
  for (int p = 0; p < 2; ++p) {
    const int n = (t >> 3) + p * 32;
    const int kb = t & 7;
#pragma unroll
    for (int j = 0; j < 8; ++j) {
      const int k = kb + j * 8;
      Wtm[(size_t)(n0 + n) * R + k0 + k] = tile[k * 72 + n];
    }
  }
}

// ---------------- GEMM2: C[M][N] = A[M][K](bf16) * Bt[N][K](bf16)^T ----------------
// EPI: 0=f32 store, 2=bf16 store, 3=bf16 silu(aux)*acc, 4=bf16 slotw[row]*acc
// EXPERT: blockIdx.y indexes padded tile table (expert, m0); Bt per-expert.
// INDIR : A row r -> HN row slot_tok[r].
// SPLITK: blockIdx.z covers K-range [z*Kc, z*Kc+Kc); EPI0 writes parts + z*M*N.
template <int EPI, bool EXPERT, bool INDIR, bool SPLITK>
__global__ __launch_bounds__(256) void gemm2(
    const u16* __restrict__ A, const u16* __restrict__ Bt, void* __restrict__ Cp,
    const void* __restrict__ aux, const float* __restrict__ slotw,
    const int* __restrict__ slot_tok, const int* __restrict__ tiletab,
    int M, int N, int K, int Kc) {
  __shared__ u16 lA[128 * 32];
  __shared__ u16 lB[128 * 32];
  const int t = threadIdx.x, w = t >> 6, l = t & 63;
  const int n0 = blockIdx.x * 128;
  int m0;
  if constexpr (EXPERT) {
    const int ntil = tiletab[0];
    if ((int)blockIdx.y >= ntil) return;
    const int e = tiletab[1 + blockIdx.y * 2];
    m0 = tiletab[2 + blockIdx.y * 2];
    Bt += (size_t)e * N * K;
  } else {
    m0 = blockIdx.y * 128;
  }
  int kbase = 0, KC = K;
  if constexpr (SPLITK) { kbase = blockIdx.z * Kc; KC = Kc; }
  const int srow = w * 16 + (l >> 2);
  const int scol = (l & 3) * 8;
  const int r0 = m0 + srow, r1 = m0 + srow + 64;
  const u16 *ag0, *ag1;
  if constexpr (INDIR) {
    ag0 = A + (size_t)slot_tok[r0] * K + scol + kbase;
    ag1 = A + (size_t)slot_tok[r1] * K + scol + kbase;
  } else {
    ag0 = A + (size_t)r0 * K + scol + kbase;
    ag1 = A + (size_t)r1 * K + scol + kbase;
  }
  const u16* bg0 = Bt + (size_t)(n0 + srow) * K + scol + kbase;
  const u16* bg1 = Bt + (size_t)(n0 + srow + 64) * K + scol + kbase;
  u16* la = lA + w * 512;
  u16* lb = lB + w * 512;
  const int l15 = l & 15, l4 = l >> 4;
  const int wm = w >> 1, wn = w & 1;
  const int fa = (wm * 64 + l15) * 32 + l4 * 8;
  const int fb = (wn * 64 + l15) * 32 + l4 * 8;
  f32x4 acc[4][4] = {};
  for (int ko = 0; ko < KC; ko += 32) {
    __syncthreads();
    gld16(ag0 + ko, la);
    gld16(ag1 + ko, la + 2048);
    gld16(bg0 + ko, lb);
    gld16(bg1 + ko, lb + 2048);
    asm volatile("s_waitcnt vmcnt(0)" ::: "memory");
    __syncthreads();
    bf16x8 af[4], bf[4];
#pragma unroll
    for (int i = 0; i < 4; ++i) {
      af[i] = *(const bf16x8*)(lA + fa + i * 512);
      bf[i] = *(const bf16x8*)(lB + fb + i * 512);
    }
#pragma unroll
    for (int mi = 0; mi < 4; ++mi)
#pragma unroll
      for (int ni = 0; ni < 4; ++ni)
        acc[mi][ni] = __builtin_amdgcn_mfma_f32_16x16x32_bf16(af[mi], bf[ni], acc[mi][ni], 0, 0, 0);
  }
  float* Cf = (float*)Cp;
  if constexpr (SPLITK) Cf += (size_t)blockIdx.z * M * N;
#pragma unroll
  for (int mi = 0; mi < 4; ++mi) {
#pragma unroll
    for (int r = 0; r < 4; ++r) {
      const int row = m0 + wm * 64 + mi * 16 + l4 * 4 + r;
#pragma unroll
      for (int ni = 0; ni < 4; ++ni) {
        const int col = n0 + wn * 64 + ni * 16 + l15;
        const size_t idx = (size_t)row * N + col;
        const float v = acc[mi][ni][r];
        if constexpr (EPI == 0) Cf[idx] = v;
        else if constexpr (EPI == 2) ((u16*)Cp)[idx] = f2bf(v);
        else if constexpr (EPI == 3) {
          const float g = bf2f(((const u16*)aux)[idx]);
          ((u16*)Cp)[idx] = f2bf(v * g / (1.f + __expf(-g)));
        } else {
          ((u16*)Cp)[idx] = f2bf(slotw[row] * v);
        }
      }
    }
  }
}

// ---------------- split-K reduce: dst = (base?) + sum of NP partials ----------------
template <int NP, bool ADDB>
__global__ __launch_bounds__(256) void red_k(float* __restrict__ dst,
                                             const float* __restrict__ base,
                                             const float* __restrict__ parts,
                                             int mn4) {
  const int i = blockIdx.x * 256 + threadIdx.x;
  float4 s;
  if constexpr (ADDB) s = ((const float4*)base)[i];
  else { s.x = s.y = s.z = s.w = 0.f; }
#pragma unroll
  for (int p = 0; p < NP; ++p) {
    const float4 v = ((const float4*)parts)[(size_t)p * mn4 + i];
    s.x += v.x; s.y += v.y; s.z += v.z; s.w += v.w;
  }
  ((float4*)dst)[i] = s;
}

// ---------------- RoPE + pack Q/K/V + emit new_k/new_v ----------------
__global__ __launch_bounds__(256) void rope_k(
    const float* __restrict__ qkv, const float* __restrict__ cosb, const float* __restrict__ sinb,
    const float* __restrict__ bq, const float* __restrict__ bk, const float* __restrict__ bv,
    u16* __restrict__ QR, u16* __restrict__ KR, u16* __restrict__ VB,
    float* __restrict__ NK, float* __restrict__ NV) {
  const int s = blockIdx.x, b = blockIdx.y, t = threadIdx.x;
  const size_t tok = (size_t)b * 1024 + s;
  const float* row = qkv + tok * 3072;
  const float* cr = cosb + s * 128;
  const float* sr = sinb + s * 128;
  for (int i = t; i < 1024; i += 256) {
    const int h = i >> 6, d = i & 63;
    const float v1 = row[h * 128 + d] + bq[h * 128 + d];
    const float v2 = row[h * 128 + d + 64] + bq[h * 128 + d + 64];
    const float o1 = v1 * cr[d] - v2 * sr[d];
    const float o2 = v2 * cr[d + 64] + v1 * sr[d + 64];
    const size_t qb = (((size_t)(b * 16 + h)) * 1024 + s) * 128;
    QR[qb + d] = f2bf(o1);
    QR[qb + d + 64] = f2bf(o2);
  }
  {
    const int h = t >> 6, d = t & 63;
    const float v1 = row[2048 + h * 128 + d] + bk[h * 128 + d];
    const float v2 = row[2048 + h * 128 + d + 64] + bk[h * 128 + d + 64];
    const float o1 = v1 * cr[d] - v2 * sr[d];
    const float o2 = v2 * cr[d + 64] + v1 * sr[d + 64];
    const size_t kb = (((size_t)(b * 4 + h)) * 1024 + s) * 128;
    KR[kb + d] = f2bf(o1);
    KR[kb + d + 64] = f2bf(o2);
    const size_t ob = tok * 2048;
#pragma unroll
    for (int rep = 0; rep < 4; ++rep) {
      NK[ob + (h * 4 + rep) * 128 + d] = o1;
      NK[ob + (h * 4 + rep) * 128 + d + 64] = o2;
    }
  }
  for (int i = t; i < 512; i += 256) {
    const int h = i >> 7, d = i & 127;
    const float v = row[2560 + i] + bv[i];
    VB[(((size_t)(b * 4 + h)) * 1024 + s) * 128 + d] = f2bf(v);
    const size_t ob = tok * 2048;
#pragma unroll
    for (int rep = 0; rep < 4; ++rep) NV[ob + (h * 4 + rep) * 128 + d] = v;
  }
}

// ---------------- Flash attention, 64 q-rows per block ----------------
__global__ __launch_bounds__(256) void attn_k(const u16* __restrict__ Q,
                                              const u16* __restrict__ Kc,
                                              const u16* __restrict__ Vc,
                                              u16* __restrict__ O) {
  const int qt = blockIdx.x, h = blockIdx.y, b = blockIdx.z;
  const int t = threadIdx.x, w = t >> 6, l = t & 63;
  const int kvh = h >> 2;
  __shared__ u16 Ks[64 * 128];
  __shared__ u16 Vt[128 * 66];
  __shared__ u16 Ps[4][16 * 68];
  const int l15 = l & 15, l4 = l >> 4;
  bf16x8 qf[4];
  {
    const u16* qb = Q + (((size_t)(b * 16 + h)) * 1024 + qt * 64 + w * 16 + l15) * 128 + l4 * 8;
#pragma unroll
    for (int c = 0; c < 4; ++c) qf[c] = *(const bf16x8*)(qb + c * 32);
  }
  float m_run[4] = {-1e30f, -1e30f, -1e30f, -1e30f};
  float l_run[4] = {0.f, 0.f, 0.f, 0.f};
  f32x4 accO[8] = {};
  const size_t kvbase = ((size_t)(b * 4 + kvh)) * 1024 * 128;
  const int ntiles = qt + 1;
  for (int kt = 0; kt < ntiles; ++kt) {
    __syncthreads();
    {
      const int key = t >> 2;
      const u16* kg = Kc + kvbase + (size_t)(kt * 64 + key) * 128;
      const u16* vg = Vc + kvbase + (size_t)(kt * 64 + key) * 128;
      const int sw = (key & 7) << 4;
#pragma unroll
      for (int p = 0; p < 4; ++p) {
        const int ch = (t & 3) * 4 + p;
        *(u16x8*)((char*)Ks + key * 256 + ((ch * 16) ^ sw)) = *(const u16x8*)(kg + ch * 8);
        const int d0 = ch * 8;
        u16x8 vv = *(const u16x8*)(vg + d0);
#pragma unroll
        for (int j = 0; j < 8; ++j) Vt[(d0 + j) * 66 + key] = vv[j];
      }
    }
    __syncthreads();
    f32x4 sf[4] = {};
#pragma unroll
    for (int nf = 0; nf < 4; ++nf) {
      const int keyl = nf * 16 + l15;
      const int sw = (keyl & 7) << 4;
      const char* kbase = (const char*)Ks + keyl * 256;
#pragma unroll
      for (int c = 0; c < 4; ++c) {
        bf16x8 kf = *(const bf16x8*)(kbase + ((c * 64 + l4 * 16) ^ sw));
        sf[nf] = __builtin_amdgcn_mfma_f32_16x16x32_bf16(qf[c], kf, sf[nf], 0, 0, 0);
      }
    }
    const int qg0 = qt * 64 + w * 16 + l4 * 4;
    float alpha[4];
#pragma unroll
    for (int r = 0; r < 4; ++r) {
      const int qg = qg0 + r;
      float tm = -1e30f;
#pragma unroll
      for (int nf = 0; nf < 4; ++nf) {
        const int kg = kt * 64 + nf * 16 + l15;
        float sv = sf[nf][r] * 0.088388347648318447f;
        sv = (kg <= qg) ? sv : -1e30f;
        sf[nf][r] = sv;
        tm = fmaxf(tm, sv);
      }
#pragma unroll
      for (int mm = 1; mm < 16; mm <<= 1) tm = fmaxf(tm, __shfl_xor(tm, mm));
      const float mn = fmaxf(m_run[r], tm);
      alpha[r] = __expf(m_run[r] - mn);
      m_run[r] = mn;
      float rs = 0.f;
#pragma unroll
      for (int nf = 0; nf < 4; ++nf) {
        const float p = __expf(sf[nf][r] - mn);
        sf[nf][r] = p;
        rs += p;
      }
#pragma unroll
      for (int mm = 1; mm < 16; mm <<= 1) rs += __shfl_xor(rs, mm);
      l_run[r] = l_run[r] * alpha[r] + rs;
    }
#pragma unroll
    for (int nf = 0; nf < 8; ++nf)
#pragma unroll
      for (int r = 0; r < 4; ++r) accO[nf][r] *= alpha[r];
#pragma unroll
    for (int nf = 0; nf < 4; ++nf)
#pragma unroll
      for (int r = 0; r < 4; ++r)
        Ps[w][(l4 * 4 + r) * 68 + nf * 16 + l15] = f2bf(sf[nf][r]);
    __syncthreads();
#pragma unroll
    for (int kc = 0; kc < 2; ++kc) {
      const u16* pb = &Ps[w][0] + l15 * 68 + kc * 32 + l4 * 8;
      union { u16x4 q[2]; bf16x8 v; } pu;
      pu.q[0] = *(const u16x4*)pb;
      pu.q[1] = *(const u16x4*)(pb + 4);
#pragma unroll
      for (int nf = 0; nf < 8; ++nf) {
        const int dd = nf * 16 + l15;
        const u16* vp = &Vt[0] + dd * 66 + kc * 32 + l4 * 8;
        union { u32 u[4]; bf16x8 v; } vu;
        vu.u[0] = *(const u32*)(vp);
        vu.u[1] = *(const u32*)(vp + 2);
        vu.u[2] = *(const u32*)(vp + 4);
        vu.u[3] = *(const u32*)(vp + 6);
        accO[nf] = __builtin_amdgcn_mfma_f32_16x16x32_bf16(pu.v, vu.v, accO[nf], 0, 0, 0);
      }
    }
  }
  const int qg0 = qt * 64 + w * 16 + l4 * 4;
#pragma unroll
  for (int nf = 0; nf < 8; ++nf) {
    const int dd = nf * 16 + l15;
#pragma unroll
    for (int r = 0; r < 4; ++r) {
      const float o = accO[nf][r] / l_run[r];
      O[((size_t)(b * 1024 + qg0 + r)) * 2048 + h * 128 + dd] = f2bf(o);
    }
  }
}

// ---------------- Router ----------------
__global__ __launch_bounds__(256) void router_k(
    const float* __restrict__ x2, const float* __restrict__ wn, const float* __restrict__ rw,
    int* __restrict__ topi2, float* __restrict__ topw2,
    int* __restrict__ counts, u64* __restrict__ pmean) {
  const int t = threadIdx.x, w = t >> 6, l = t & 63;
  const int tok = blockIdx.x * 4 + w;
  __shared__ int lc[8];
  __shared__ u64 lp[8];
  if (t < 8) { lc[t] = 0; lp[t] = 0ull; }
  __syncthreads();
  const float* xr = x2 + (size_t)tok * DD;
  float ss = 0.f;
#pragma unroll
  for (int i = 0; i < 8; ++i) {
    float4 v = *(const float4*)(xr + l * 32 + i * 4);
    ss += v.x * v.x + v.y * v.y + v.z * v.z + v.w * v.w;
  }
#pragma unroll
  for (int m = 1; m < 64; m <<= 1) ss += __shfl_xor(ss, m);
  const float sc = rsqrtf(ss * (1.f / DD) + 1e-6f);
  float acc[8] = {};
  for (int i = 0; i < 32; ++i) {
    const int d = l * 32 + i;
    const float hv = xr[d] * sc * wn[d];
    float4 r0 = *(const float4*)(rw + d * 8);
    float4 r1 = *(const float4*)(rw + d * 8 + 4);
    acc[0] += hv * r0.x; acc[1] += hv * r0.y; acc[2] += hv * r0.z; acc[3] += hv * r0.w;
    acc[4] += hv * r1.x; acc[5] += hv * r1.y; acc[6] += hv * r1.z; acc[7] += hv * r1.w;
  }
#pragma unroll
  for (int m = 1; m < 64; m <<= 1)
#pragma unroll
    for (int e = 0; e < 8; ++e) acc[e] += __shfl_xor(acc[e], m);
  if (l == 0) {
    float mx = acc[0];
#pragma unroll
    for (int e = 1; e < 8; ++e) mx = fmaxf(mx, acc[e]);
    float p[8], sum = 0.f;
#pragma unroll
    for (int e = 0; e < 8; ++e) { p[e] = __expf(acc[e] - mx); sum += p[e]; }
    const float inv = 1.f / sum;
#pragma unroll
    for (int e = 0; e < 8; ++e) p[e] *= inv;
    int e0 = 0; float v0 = p[0];
#pragma unroll
    for (int e = 1; e < 8; ++e) if (p[e] > v0) { v0 = p[e]; e0 = e; }
    int e1 = (e0 == 0) ? 1 : 0; float v1 = p[e1];
#pragma unroll
    for (int e = 0; e < 8; ++e) if (e != e0 && p[e] > v1) { v1 = p[e]; e1 = e; }
    const float wsum = v0 + v1;
    topi2[tok * 2] = e0; topi2[tok * 2 + 1] = e1;
    topw2[tok * 2] = v0 / wsum; topw2[tok * 2 + 1] = v1 / wsum;
    atomicAdd(&lc[e0], 1); atomicAdd(&lc[e1], 1);
#pragma unroll
    for (int e = 0; e < 8; ++e) atomicAdd(&lp[e], (u64)((double)p[e] * 4294967296.0));
  }
  __syncthreads();
  if (t < 8) {
    if (lc[t]) atomicAdd(&counts[t], lc[t]);
    if (lp[t]) atomicAdd(&pmean[t], lp[t]);
  }
}

__global__ __launch_bounds__(256) void zero_k(int* __restrict__ counts, u64* __restrict__ pmean,
                                              int* __restrict__ slot_tok, float* __restrict__ slot_w) {
  const int i = blockIdx.x * 256 + threadIdx.x;
  if (i < 5120) { slot_tok[i] = 0; slot_w[i] = 0.f; }
  if (i < 8) { counts[i] = 0; pmean[i] = 0ull; }
}

// scan: padded offsets (x128), cursors, tile table, aux loss
__global__ void scan_k(const int* __restrict__ counts, int* __restrict__ cursors,
                       int* __restrict__ tiletab, const u64* __restrict__ pmean,
                       float* __restrict__ auxout) {
  if (threadIdx.x == 0) {
    int off = 0, nt = 0;
    double aux = 0.0;
    for (int e = 0; e < 8; ++e) {
      cursors[e] = off;
      const int c = counts[e];
      const int nte = (c + 127) >> 7;
      for (int i = 0; i < nte; ++i) {
        tiletab[1 + nt * 2] = e;
        tiletab[2 + nt * 2] = off + i * 128;
        ++nt;
      }
      off += nte * 128;
      const double pm = ((double)pmean[e] / 4294967296.0) / 2048.0;
      aux += ((double)c / 4096.0) * pm;
    }
    tiletab[0] = nt;
    *auxout = (float)(8.0 * aux);
  }
}

__global__ __launch_bounds__(256) void assign_k(const int* __restrict__ topi2,
                                                const float* __restrict__ topw2,
                                                int* __restrict__ cursors,
                                                int* __restrict__ slot_tok,
                                                float* __restrict__ slot_w,
                                                int* __restrict__ tok_slot) {
  const int tok = blockIdx.x * 256 + threadIdx.x;
#pragma unroll
  for (int j = 0; j < 2; ++j) {
    const int e = topi2[tok * 2 + j];
    const int s = atomicAdd(&cursors[e], 1);
    slot_tok[s] = tok;
    slot_w[s] = topw2[tok * 2 + j];
    tok_slot[tok * 2 + j] = s;
  }
}

// out[tok] += routed[s0] + routed[s1]  (routed is bf16)
__global__ __launch_bounds__(256) void final_k(float* __restrict__ out,
                                               const u16* __restrict__ routed,
                                               const int* __restrict__ tok_slot) {
  const int tok = blockIdx.x, t = threadIdx.x;
  const int s0 = tok_slot[tok * 2], s1 = tok_slot[tok * 2 + 1];
  u16x8 a = ((const u16x8*)(routed + (size_t)s0 * DD))[t];
  u16x8 b = ((const u16x8*)(routed + (size_t)s1 * DD))[t];
  float* o = out + (size_t)tok * DD + t * 8;
  float4 o0 = *(const float4*)o;
  float4 o1 = *(const float4*)(o + 4);
  o0.x += bf2f(a[0]) + bf2f(b[0]); o0.y += bf2f(a[1]) + bf2f(b[1]);
  o0.z += bf2f(a[2]) + bf2f(b[2]); o0.w += bf2f(a[3]) + bf2f(b[3]);
  o1.x += bf2f(a[4]) + bf2f(b[4]); o1.y += bf2f(a[5]) + bf2f(b[5]);
  o1.z += bf2f(a[6]) + bf2f(b[6]); o1.w += bf2f(a[7]) + bf2f(b[7]);
  *(float4*)o = o0;
  *(float4*)(o + 4) = o1;
}

extern "C" void kernel_launch(void* const* d_in, const int* in_sizes, int n_in,
                              void* d_out, int out_size, void* d_ws, size_t ws_size,
                              hipStream_t stream) {
  (void)in_sizes; (void)n_in; (void)out_size; (void)ws_size;
  const float* x    = (const float*)d_in[0];
  const float* rc   = (const float*)d_in[1];
  const float* rs   = (const float*)d_in[2];
  const float* anw  = (const float*)d_in[3];
  const float* fnw  = (const float*)d_in[4];
  const float* wq   = (const float*)d_in[5];
  const float* bq   = (const float*)d_in[6];
  const float* wk   = (const float*)d_in[7];
  const float* bk   = (const float*)d_in[8];
  const float* wv   = (const float*)d_in[9];
  const float* bv   = (const float*)d_in[10];
  const float* wo   = (const float*)d_in[11];
  const float* rw   = (const float*)d_in[12];
  const float* wg   = (const float*)d_in[13];
  const float* wu   = (const float*)d_in[14];
  const float* wd   = (const float*)d_in[15];
  const float* wsg  = (const float*)d_in[16];
  const float* wsu  = (const float*)d_in[17];
  const float* wsd  = (const float*)d_in[18];

  const size_t MB = (size_t)1 << 20;
  char* ws = (char*)d_ws;
  // persistent
  float* X2  = (float*)(ws + 0);          // 16 MiB
  u16*   HN  = (u16*)(ws + 16 * MB);      // 8 MiB
  char*  SM  = ws + 24 * MB;              // 1 MiB small
  char*  AR  = ws + 25 * MB;              // 123 MiB arena

  int*   CNT   = (int*)(SM);
  u64*   PM    = (u64*)(SM + 64);
  int*   CURS  = (int*)(SM + 256);
  int*   TILT  = (int*)(SM + 512);
  int*   TOPI  = (int*)(SM + 4096);
  float* TOPW  = (float*)(SM + 40960);
  int*   STOK  = (int*)(SM + 73728);
  float* SW    = (float*)(SM + 98304);
  int*   TSLOT = (int*)(SM + 131072);

  // phase P1 (qkv)
  u16*   H      = (u16*)(AR);             // 8 MiB
  u16*   WTQ    = (u16*)(AR + 8 * MB);    // 12 MiB
  float* PARTSQ = (float*)(AR + 20 * MB); // 48 MiB (2 x 24)
  float* QKVF   = (float*)(AR + 68 * MB); // 24 MiB
  // phase P2 (attn)
  u16*   QR    = (u16*)(AR);              // 8 MiB
  u16*   KR    = (u16*)(AR + 8 * MB);     // 2 MiB
  u16*   VBb   = (u16*)(AR + 10 * MB);    // 2 MiB
  u16*   ATTNO = (u16*)(AR + 12 * MB);    // 8 MiB
  // phase P3 (wo)
  u16*   WTO    = (u16*)(AR + 20 * MB);   // 8 MiB
  float* PARTSW = (float*)(AR + 28 * MB); // 64 MiB (4 x 16)
  // phase P5 (shared expert)
  u16*   GSH    = (u16*)(AR);             // 43 MiB
  u16*   WTS    = (u16*)(AR + 43 * MB);   // 43 MiB
  float* PARTSD = (float*)(AR + 86 * MB); // 32 MiB (2 x 16)
  // phase P6 (routed experts)
  u16*   WTE    = (u16*)(AR);             // 64 MiB (8 experts)
  u16*   GEXP   = (u16*)(AR + 64 * MB);   // 20 MiB (5120 x 2048)
  u16*   ROUTED = (u16*)(AR + 84 * MB);   // 20 MiB

  float* out  = (float*)d_out;
  float* NK   = out + 4194304;
  float* NV   = out + 2 * 4194304;
  float* AUXO = out + 3 * 4194304;

  const dim3 b256(256);

  // P1: attn rmsnorm + QKV projection (split-K x2)
  rmsnorm_k<<<TT, b256, 0, stream>>>(x, anw, H);
  transp_k<<<dim3(32, 32, 1), b256, 0, stream>>>(wq, WTQ, 2048, 2048);
  transp_k<<<dim3(8, 32, 1), b256, 0, stream>>>(wk, WTQ + (size_t)2048 * 2048, 2048, 512);
  transp_k<<<dim3(8, 32, 1), b256, 0, stream>>>(wv, WTQ + (size_t)2560 * 2048, 2048, 512);
  gemm2<0, false, false, true><<<dim3(24, 16, 2), b256, 0, stream>>>(
      H, WTQ, PARTSQ, nullptr, nullptr, nullptr, nullptr, TT, 3072, 2048, 1024);
  red_k<2, false><<<6144, b256, 0, stream>>>(QKVF, nullptr, PARTSQ, 1572864);
  // P2: rope + attention
  rope_k<<<dim3(1024, 2), b256, 0, stream>>>(QKVF, rc, rs, bq, bk, bv, QR, KR, VBb, NK, NV);
  attn_k<<<dim3(16, 16, 2), b256, 0, stream>>>(QR, KR, VBb, ATTNO);
  // P3: x2 = x + attno @ wo (split-K x4)
  transp_k<<<dim3(32, 32, 1), b256, 0, stream>>>(wo, WTO, 2048, 2048);
  gemm2<0, false, false, true><<<dim3(16, 16, 4), b256, 0, stream>>>(
      ATTNO, WTO, PARTSW, nullptr, nullptr, nullptr, nullptr, TT, 2048, 2048, 512);
  red_k<4, true><<<4096, b256, 0, stream>>>(X2, x, PARTSW, 1048576);
  // P4: ffn rmsnorm + routing
  rmsnorm_k<<<TT, b256, 0, stream>>>(X2, fnw, HN);
  zero_k<<<20, b256, 0, stream>>>(CNT, PM, STOK, SW);
  router_k<<<512, b256, 0, stream>>>(X2, fnw, rw, TOPI, TOPW, CNT, PM);
  scan_k<<<1, 64, 0, stream>>>(CNT, CURS, TILT, PM, AUXO);
  assign_k<<<8, b256, 0, stream>>>(TOPI, TOPW, CURS, STOK, SW, TSLOT);
  // P5: shared expert (gate, up-silu in place, down split-K x2)
  transp_k<<<dim3(172, 32, 1), b256, 0, stream>>>(wsg, WTS, 2048, FSH);
  gemm2<2, false, false, false><<<dim3(86, 16, 1), b256, 0, stream>>>(
      HN, WTS, GSH, nullptr, nullptr, nullptr, nullptr, TT, FSH, 2048, 0);
  transp_k<<<dim3(172, 32, 1), b256, 0, stream>>>(wsu, WTS, 2048, FSH);
  gemm2<3, false, false, false><<<dim3(86, 16, 1), b256, 0, stream>>>(
      HN, WTS, GSH, GSH, nullptr, nullptr, nullptr, TT, FSH, 2048, 0);
  transp_k<<<dim3(32, 172, 1), b256, 0, stream>>>(wsd, WTS, FSH, 2048);
  gemm2<0, false, false, true><<<dim3(16, 16, 2), b256, 0, stream>>>(
      GSH, WTS, PARTSD, nullptr, nullptr, nullptr, nullptr, TT, 2048, FSH, 5504);
  red_k<2, true><<<4096, b256, 0, stream>>>(out, X2, PARTSD, 1048576);
  // P6: routed experts — all 8 per dispatch via padded tile table
  transp_k<<<dim3(32, 32, 8), b256, 0, stream>>>(wg, WTE, 2048, 2048);
  gemm2<2, true, true, false><<<dim3(16, 40, 1), b256, 0, stream>>>(
      HN, WTE, GEXP, nullptr, nullptr, STOK, TILT, 5120, 2048, 2048, 0);
  transp_k<<<dim3(32, 32, 8), b256, 0, stream>>>(wu, WTE, 2048, 2048);
  gemm2<3, true, true, false><<<dim3(16, 40, 1), b256, 0, stream>>>(
      HN, WTE, GEXP, GEXP, nullptr, STOK, TILT, 5120, 2048, 2048, 0);
  transp_k<<<dim3(32, 32, 8), b256, 0, stream>>>(wd, WTE, 2048, 2048);
  gemm2<4, true, false, false><<<dim3(16, 40, 1), b256, 0, stream>>>(
      GEXP, WTE, ROUTED, nullptr, SW, STOK, TILT, 5120, 2048, 2048, 0);
  // P7: out += routed
  final_k<<<TT, b256, 0, stream>>>(out, ROUTED, TSLOT);
}

// Round 3
// 1036.108 us; speedup vs baseline: 1.4131x; 1.1097x over previous
//
#include <hip/hip_runtime.h>

typedef unsigned short u16;
typedef unsigned int u32;
typedef unsigned long long u64;
typedef __attribute__((ext_vector_type(4))) unsigned short u16x4;
typedef __attribute__((ext_vector_type(8))) unsigned short u16x8;
typedef __attribute__((ext_vector_type(4))) float f32x4;
typedef __attribute__((ext_vector_type(8))) __bf16 bf16x8;

#define DD 2048
#define TT 2048
#define FSH 11008

__device__ __forceinline__ float bf2f(u16 u) {
  union { u32 i; float f; } v; v.i = ((u32)u) << 16; return v.f;
}
__device__ __forceinline__ u16 f2bf(float f) {
  union { float f; u32 i; } v; v.f = f;
  u32 r = v.i + 0x7fffu + ((v.i >> 16) & 1u);
  return (u16)(r >> 16);
}
__device__ __forceinline__ void gld16(const void* g, void* l) {
  __builtin_amdgcn_global_load_lds((const __attribute__((address_space(1))) void*)g,
                                   (__attribute__((address_space(3))) void*)l, 16, 0, 0);
}

#define MFMA16(d, a, b) d = __builtin_amdgcn_mfma_f32_16x16x32_bf16(a, b, d, 0, 0, 0)

// ---------------- RMSNorm: f32 row -> bf16 row ----------------
__global__ __launch_bounds__(256) void rmsnorm_k(const float* __restrict__ x,
                                                 const float* __restrict__ w,
                                                 u16* __restrict__ out) {
  const int t = threadIdx.x;
  const float* xr = x + (size_t)blockIdx.x * DD;
  float4 a = *(const float4*)(xr + t * 8);
  float4 b = *(const float4*)(xr + t * 8 + 4);
  float ss = a.x*a.x + a.y*a.y + a.z*a.z + a.w*a.w
           + b.x*b.x + b.y*b.y + b.z*b.z + b.w*b.w;
#pragma unroll
  for (int m = 1; m < 64; m <<= 1) ss += __shfl_xor(ss, m);
  __shared__ float red[4];
  if ((t & 63) == 0) red[t >> 6] = ss;
  __syncthreads();
  float sc = rsqrtf((red[0] + red[1] + red[2] + red[3]) * (1.f / DD) + 1e-6f);
  float4 wa = *(const float4*)(w + t * 8);
  float4 wb = *(const float4*)(w + t * 8 + 4);
  u16x8 o;
  o[0] = f2bf(a.x * sc * wa.x); o[1] = f2bf(a.y * sc * wa.y);
  o[2] = f2bf(a.z * sc * wa.z); o[3] = f2bf(a.w * sc * wa.w);
  o[4] = f2bf(b.x * sc * wb.x); o[5] = f2bf(b.y * sc * wb.y);
  o[6] = f2bf(b.z * sc * wb.z); o[7] = f2bf(b.w * sc * wb.w);
  *(u16x8*)(out + (size_t)blockIdx.x * DD + t * 8) = o;
}

// ---------------- Transpose+convert: W[R][C] f32 -> Wt[C][R] bf16 ----------------
__global__ __launch_bounds__(256) void transp_k(const float* __restrict__ W,
                                                u16* __restrict__ Wt, int R, int C) {
  __shared__ u16 tile[64 * 72];
  const size_t msz = (size_t)R * C;
  const float* Wm = W + msz * blockIdx.z;
  u16* Wtm = Wt + msz * blockIdx.z;
  const int t = threadIdx.x;
  const int n0 = blockIdx.x * 64, k0 = blockIdx.y * 64;
#pragma unroll
  for (int p = 0; p < 4; ++p) {
    const int kk = (t >> 4) + p * 16;
    const int nn = (t & 15) * 4;
    float4 v = *(const float4*)(Wm + (size_t)(k0 + kk) * C + n0 + nn);
    u16x4 o; o[0] = f2bf(v.x); o[1] = f2bf(v.y); o[2] = f2bf(v.z); o[3] = f2bf(v.w);
    *(u16x4*)(tile + kk * 72 + nn) = o;
  }
  __syncthreads();
#pragma unroll
  for (int p = 0; p < 2; ++p) {
    const int n = (t >> 3) + p * 32;
    const int kb = t & 7;
#pragma unroll
    for (int j = 0; j < 8; ++j) {
      const int k = kb + j * 8;
      Wtm[(size_t)(n0 + n) * R + k0 + k] = tile[k * 72 + n];
    }
  }
}

// ---------------- GEMM2 (128^2 m97-style) ----------------
// EPI: 0=f32 store(splitK parts), 2=bf16 store, 3=bf16 silu(aux)*acc, 4=bf16 slotw[row]*acc
template <int EPI, bool EXPERT, bool INDIR, bool SPLITK>
__global__ __launch_bounds__(256) void gemm2(
    const u16* __restrict__ A, const u16* __restrict__ Bt, void* __restrict__ Cp,
    const void* __restrict__ aux, const float* __restrict__ slotw,
    const int* __restrict__ slot_tok, const int* __restrict__ tiletab,
    int M, int N, int K, int Kc) {
  __shared__ u16 lA[128 * 32];
  __shared__ u16 lB[128 * 32];
  const int t = threadIdx.x, w = t >> 6, l = t & 63;
  const int n0 = blockIdx.x * 128;
  int m0;
  if constexpr (EXPERT) {
    const int ntil = tiletab[0];
    if ((int)blockIdx.y >= ntil) return;
    const int e = tiletab[1 + blockIdx.y * 2];
    m0 = tiletab[2 + blockIdx.y * 2];
    Bt += (size_t)e * N * K;
  } else {
    m0 = blockIdx.y * 128;
  }
  int kbase = 0, KC = K;
  if constexpr (SPLITK) { kbase = blockIdx.z * Kc; KC = Kc; }
  const int srow = w * 16 + (l >> 2);
  const int scol = (l & 3) * 8;
  const int r0 = m0 + srow, r1 = m0 + srow + 64;
  const u16 *ag0, *ag1;
  if constexpr (INDIR) {
    ag0 = A + (size_t)slot_tok[r0] * K + scol + kbase;
    ag1 = A + (size_t)slot_tok[r1] * K + scol + kbase;
  } else {
    ag0 = A + (size_t)r0 * K + scol + kbase;
    ag1 = A + (size_t)r1 * K + scol + kbase;
  }
  const u16* bg0 = Bt + (size_t)(n0 + srow) * K + scol + kbase;
  const u16* bg1 = Bt + (size_t)(n0 + srow + 64) * K + scol + kbase;
  u16* la = lA + w * 512;
  u16* lb = lB + w * 512;
  const int l15 = l & 15, l4 = l >> 4;
  const int wm = w >> 1, wn = w & 1;
  const int fa = (wm * 64 + l15) * 32 + l4 * 8;
  const int fb = (wn * 64 + l15) * 32 + l4 * 8;
  f32x4 acc[4][4] = {};
  for (int ko = 0; ko < KC; ko += 32) {
    __syncthreads();
    gld16(ag0 + ko, la);
    gld16(ag1 + ko, la + 2048);
    gld16(bg0 + ko, lb);
    gld16(bg1 + ko, lb + 2048);
    asm volatile("s_waitcnt vmcnt(0)" ::: "memory");
    __syncthreads();
    bf16x8 af[4], bf[4];
#pragma unroll
    for (int i = 0; i < 4; ++i) {
      af[i] = *(const bf16x8*)(lA + fa + i * 512);
      bf[i] = *(const bf16x8*)(lB + fb + i * 512);
    }
#pragma unroll
    for (int mi = 0; mi < 4; ++mi)
#pragma unroll
      for (int ni = 0; ni < 4; ++ni)
        MFMA16(acc[mi][ni], af[mi], bf[ni]);
  }
  float* Cf = (float*)Cp;
  if constexpr (SPLITK) Cf += (size_t)blockIdx.z * M * N;
#pragma unroll
  for (int mi = 0; mi < 4; ++mi) {
#pragma unroll
    for (int r = 0; r < 4; ++r) {
      const int row = m0 + wm * 64 + mi * 16 + l4 * 4 + r;
#pragma unroll
      for (int ni = 0; ni < 4; ++ni) {
        const int col = n0 + wn * 64 + ni * 16 + l15;
        const size_t idx = (size_t)row * N + col;
        const float v = acc[mi][ni][r];
        if constexpr (EPI == 0) Cf[idx] = v;
        else if constexpr (EPI == 2) ((u16*)Cp)[idx] = f2bf(v);
        else if constexpr (EPI == 3) {
          const float g = bf2f(((const u16*)aux)[idx]);
          ((u16*)Cp)[idx] = f2bf(v * g / (1.f + __expf(-g)));
        } else {
          ((u16*)Cp)[idx] = f2bf(slotw[row] * v);
        }
      }
    }
  }
}

// ---------------- GEMM8: 256^2, 8-wave, 8-phase, T2 swizzle + counted vmcnt + setprio ----
// EPI: 2=bf16 store, 3=bf16 silu(aux)*acc, 10=bf16 split-K parts (+z*M*N)
// SPLITK: z-slab of 2816 K-columns (last slab = remainder, tile count stays even)
template <int EPI, bool SPLITK>
__global__ __launch_bounds__(512, 2) void gemm8(
    const u16* __restrict__ A, const u16* __restrict__ Bt, void* __restrict__ Cp,
    const u16* __restrict__ aux, int M, int N, int K) {
  __shared__ char lds[131072];  // [buf][A 32K | B 32K]
  const int t = threadIdx.x, w = t >> 6, l = t & 63;
  const int gx = gridDim.x;
  const int nwg = gx * gridDim.y;     // must be % 8 == 0
  int wg = blockIdx.y * gx + blockIdx.x;
  wg = (wg & 7) * (nwg >> 3) + (wg >> 3);   // XCD swizzle (bijective, nwg%8==0)
  const int n0 = (wg % gx) * 256;
  const int m0 = (wg / gx) * 256;
  int kbase = 0, KC = K;
  if constexpr (SPLITK) {
    kbase = blockIdx.z * 2816;
    const int rem = K - kbase;
    KC = rem < 2816 ? rem : 2816;
  }
  const int ktiles = KC >> 6;         // must be even
  const int wm = w >> 2, wn = w & 3;
  const int l15 = l & 15, l4 = l >> 4;
  const int sro = l >> 3, sc = l & 7;

  // stage one half-tile (A-half h = rows bit6==h; B-half h = rows bit5==h)
  // LDS layout per tile: row r (0..255), chunk c (0..7, 16B): byte = r*128 + (c^(r&7))*16
  auto stage = [&](int b, int isB, int h, int kt) {
    if (kt >= ktiles) kt = ktiles - 1;
    const u16* src = isB ? Bt : A;
    const int row0 = isB ? n0 : m0;
    char* base = lds + b * 65536 + isB * 32768;
#pragma unroll
    for (int i = 0; i < 2; ++i) {
      const int q = i * 8 + w;
      const int r0 = isB ? (((q >> 2) << 6) + h * 32 + (q & 3) * 8)
                         : (((q & 8) << 4) + h * 64 + (q & 7) * 8);
      const int r = r0 + sro;
      const int cl = sc ^ (r & 7);
      gld16(src + (size_t)(row0 + r) * K + kbase + kt * 64 + cl * 8, base + r0 * 128);
    }
  };
  auto ldA = [&](int b, int mi, int ks) {
    const int row = wm * 128 + mi * 16 + l15;
    const int ch = (ks * 4 + l4) ^ (row & 7);
    return *(const bf16x8*)(lds + b * 65536 + row * 128 + ch * 16);
  };
  auto ldB = [&](int b, int ni, int ks) {
    const int row = wn * 64 + ni * 16 + l15;
    const int ch = (ks * 4 + l4) ^ (row & 7);
    return *(const bf16x8*)(lds + b * 65536 + 32768 + row * 128 + ch * 16);
  };

  f32x4 acc[8][4] = {};
  bf16x8 aR[4][2], b0[2][2], b1[2][2];

  // prologue: tile0 full (buf0) + tile1 {A0,B1,A1} (buf1); B0(1) staged at P1
  stage(0, 0, 0, 0); stage(0, 1, 0, 0); stage(0, 1, 1, 0); stage(0, 0, 1, 0);
  stage(1, 0, 0, 1); stage(1, 1, 1, 1); stage(1, 0, 1, 1);
  asm volatile("s_waitcnt vmcnt(6)" ::: "memory");
  __builtin_amdgcn_s_barrier();

  for (int kt = 0; kt < ktiles; kt += 2) {
    // P1: read A-h0,B-h0 of buf0; stage B0(kt+1)->buf1; MFMA (mh0,nh0)
#pragma unroll
    for (int mi = 0; mi < 4; ++mi) { aR[mi][0] = ldA(0, mi, 0); aR[mi][1] = ldA(0, mi, 1); }
#pragma unroll
    for (int ni = 0; ni < 2; ++ni) { b0[ni][0] = ldB(0, ni, 0); b0[ni][1] = ldB(0, ni, 1); }
    stage(1, 1, 0, kt + 1);
    __builtin_amdgcn_s_barrier();
    asm volatile("s_waitcnt lgkmcnt(0)" ::: "memory");
    __builtin_amdgcn_s_setprio(1);
#pragma unroll
    for (int mi = 0; mi < 4; ++mi)
#pragma unroll
      for (int ni = 0; ni < 2; ++ni) {
        MFMA16(acc[mi][ni], aR[mi][0], b0[ni][0]);
        MFMA16(acc[mi][ni], aR[mi][1], b0[ni][1]);
      }
    __builtin_amdgcn_s_setprio(0);
    __builtin_amdgcn_s_barrier();
    // P2: read B-h1(buf0); stage A0(kt+2)->buf0; MFMA (mh0,nh1)
#pragma unroll
    for (int ni = 0; ni < 2; ++ni) { b1[ni][0] = ldB(0, ni + 2, 0); b1[ni][1] = ldB(0, ni + 2, 1); }
    stage(0, 0, 0, kt + 2);
    __builtin_amdgcn_s_barrier();
    asm volatile("s_waitcnt lgkmcnt(0)" ::: "memory");
    __builtin_amdgcn_s_setprio(1);
#pragma unroll
    for (int mi = 0; mi < 4; ++mi)
#pragma unroll
      for (int ni = 0; ni < 2; ++ni) {
        MFMA16(acc[mi][ni + 2], aR[mi][0], b1[ni][0]);
        MFMA16(acc[mi][ni + 2], aR[mi][1], b1[ni][1]);
      }
    __builtin_amdgcn_s_setprio(0);
    __builtin_amdgcn_s_barrier();
    // P3: read A-h1(buf0); stage B1(kt+2)->buf0; MFMA (mh1,nh1)
#pragma unroll
    for (int mi = 0; mi < 4; ++mi) { aR[mi][0] = ldA(0, mi + 4, 0); aR[mi][1] = ldA(0, mi + 4, 1); }
    stage(0, 1, 1, kt + 2);
    __builtin_amdgcn_s_barrier();
    asm volatile("s_waitcnt lgkmcnt(0)" ::: "memory");
    __builtin_amdgcn_s_setprio(1);
#pragma unroll
    for (int mi = 0; mi < 4; ++mi)
#pragma unroll
      for (int ni = 0; ni < 2; ++ni) {
        MFMA16(acc[mi + 4][ni + 2], aR[mi][0], b1[ni][0]);
        MFMA16(acc[mi + 4][ni + 2], aR[mi][1], b1[ni][1]);
      }
    __builtin_amdgcn_s_setprio(0);
    __builtin_amdgcn_s_barrier();
    // P4: stage A1(kt+2)->buf0; MFMA (mh1,nh0); vmcnt(6) then barrier
    stage(0, 0, 1, kt + 2);
    __builtin_amdgcn_s_barrier();
    __builtin_amdgcn_s_setprio(1);
#pragma unroll
    for (int mi = 0; mi < 4; ++mi)
#pragma unroll
      for (int ni = 0; ni < 2; ++ni) {
        MFMA16(acc[mi + 4][ni], aR[mi][0], b0[ni][0]);
        MFMA16(acc[mi + 4][ni], aR[mi][1], b0[ni][1]);
      }
    __builtin_amdgcn_s_setprio(0);
    asm volatile("s_waitcnt vmcnt(6)" ::: "memory");
    __builtin_amdgcn_s_barrier();
    // P5: read A-h0,B-h0 of buf1 (tile kt+1); stage B0(kt+2)->buf0; MFMA (mh0,nh0)
#pragma unroll
    for (int mi = 0; mi < 4; ++mi) { aR[mi][0] = ldA(1, mi, 0); aR[mi][1] = ldA(1, mi, 1); }
#pragma unroll
    for (int ni = 0; ni < 2; ++ni) { b0[ni][0] = ldB(1, ni, 0); b0[ni][1] = ldB(1, ni, 1); }
    stage(0, 1, 0, kt + 2);
    __builtin_amdgcn_s_barrier();
    asm volatile("s_waitcnt lgkmcnt(0)" ::: "memory");
    __builtin_amdgcn_s_setprio(1);
#pragma unroll
    for (int mi = 0; mi < 4; ++mi)
#pragma unroll
      for (int ni = 0; ni < 2; ++ni) {
        MFMA16(acc[mi][ni], aR[mi][0], b0[ni][0]);
        MFMA16(acc[mi][ni], aR[mi][1], b0[ni][1]);
      }
    __builtin_amdgcn_s_setprio(0);
    __builtin_amdgcn_s_barrier();
    // P6: read B-h1(buf1); stage A0(kt+3)->buf1; MFMA (mh0,nh1)
#pragma unroll
    for (int ni = 0; ni < 2; ++ni) { b1[ni][0] = ldB(1, ni + 2, 0); b1[ni][1] = ldB(1, ni + 2, 1); }
    stage(1, 0, 0, kt + 3);
    __builtin_amdgcn_s_barrier();
    asm volatile("s_waitcnt lgkmcnt(0)" ::: "memory");
    __builtin_amdgcn_s_setprio(1);
#pragma unroll
    for (int mi = 0; mi < 4; ++mi)
#pragma unroll
      for (int ni = 0; ni < 2; ++ni) {
        MFMA16(acc[mi][ni + 2], aR[mi][0], b1[ni][0]);
        MFMA16(acc[mi][ni + 2], aR[mi][1], b1[ni][1]);
      }
    __builtin_amdgcn_s_setprio(0);
    __builtin_amdgcn_s_barrier();
    // P7: read A-h1(buf1); stage B1(kt+3)->buf1; MFMA (mh1,nh1)
#pragma unroll
    for (int mi = 0; mi < 4; ++mi) { aR[mi][0] = ldA(1, mi + 4, 0); aR[mi][1] = ldA(1, mi + 4, 1); }
    stage(1, 1, 1, kt + 3);
    __builtin_amdgcn_s_barrier();
    asm volatile("s_waitcnt lgkmcnt(0)" ::: "memory");
    __builtin_amdgcn_s_setprio(1);
#pragma unroll
    for (int mi = 0; mi < 4; ++mi)
#pragma unroll
      for (int ni = 0; ni < 2; ++ni) {
        MFMA16(acc[mi + 4][ni + 2], aR[mi][0], b1[ni][0]);
        MFMA16(acc[mi + 4][ni + 2], aR[mi][1], b1[ni][1]);
      }
    __builtin_amdgcn_s_setprio(0);
    __builtin_amdgcn_s_barrier();
    // P8: stage A1(kt+3)->buf1; MFMA (mh1,nh0); vmcnt(6) then barrier
    stage(1, 0, 1, kt + 3);
    __builtin_amdgcn_s_barrier();
    __builtin_amdgcn_s_setprio(1);
#pragma unroll
    for (int mi = 0; mi < 4; ++mi)
#pragma unroll
      for (int ni = 0; ni < 2; ++ni) {
        MFMA16(acc[mi + 4][ni], aR[mi][0], b0[ni][0]);
        MFMA16(acc[mi + 4][ni], aR[mi][1], b0[ni][1]);
      }
    __builtin_amdgcn_s_setprio(0);
    asm volatile("s_waitcnt vmcnt(6)" ::: "memory");
    __builtin_amdgcn_s_barrier();
  }

  u16* C16 = (u16*)Cp;
  if constexpr (EPI == 10) C16 += (size_t)blockIdx.z * ((size_t)M * N);
#pragma unroll
  for (int mi = 0; mi < 8; ++mi)
#pragma unroll
    for (int rr = 0; rr < 4; ++rr) {
      const int row = m0 + wm * 128 + mi * 16 + l4 * 4 + rr;
#pragma unroll
      for (int ni = 0; ni < 4; ++ni) {
        const int col = n0 + wn * 64 + ni * 16 + l15;
        const size_t idx = (size_t)row * N + col;
        const float v = acc[mi][ni][rr];
        if constexpr (EPI == 3) {
          const float g = bf2f(aux[idx]);
          C16[idx] = f2bf(v * g / (1.f + __expf(-g)));
        } else {
          C16[idx] = f2bf(v);
        }
      }
    }
}

// ---------------- split-K reduce (f32 parts) ----------------
template <int NP, bool ADDB>
__global__ __launch_bounds__(256) void red_k(float* __restrict__ dst,
                                             const float* __restrict__ base,
                                             const float* __restrict__ parts,
                                             int mn4) {
  const int i = blockIdx.x * 256 + threadIdx.x;
  float4 s;
  if constexpr (ADDB) s = ((const float4*)base)[i];
  else { s.x = s.y = s.z = s.w = 0.f; }
#pragma unroll
  for (int p = 0; p < NP; ++p) {
    const float4 v = ((const float4*)parts)[(size_t)p * mn4 + i];
    s.x += v.x; s.y += v.y; s.z += v.z; s.w += v.w;
  }
  ((float4*)dst)[i] = s;
}

// ---------------- split-K reduce (bf16 parts x4): dst = base + sum ----------------
__global__ __launch_bounds__(256) void redbf_k(float* __restrict__ dst,
                                               const float* __restrict__ base,
                                               const u16* __restrict__ parts) {
  const int i = blockIdx.x * 256 + threadIdx.x;   // u16x8 index, total 524288
  float s[8];
  const float* bp = base + (size_t)i * 8;
#pragma unroll
  for (int j = 0; j < 8; ++j) s[j] = bp[j];
#pragma unroll
  for (int p = 0; p < 4; ++p) {
    u16x8 v = ((const u16x8*)parts)[(size_t)p * 524288 + i];
#pragma unroll
    for (int j = 0; j < 8; ++j) s[j] += bf2f(v[j]);
  }
  float* dp = dst + (size_t)i * 8;
#pragma unroll
  for (int j = 0; j < 8; ++j) dp[j] = s[j];
}

// ---------------- RoPE + pack Q/K/V + emit new_k/new_v ----------------
__global__ __launch_bounds__(256) void rope_k(
    const float* __restrict__ qkv, const float* __restrict__ cosb, const float* __restrict__ sinb,
    const float* __restrict__ bq, const float* __restrict__ bk, const float* __restrict__ bv,
    u16* __restrict__ QR, u16* __restrict__ KR, u16* __restrict__ VB,
    float* __restrict__ NK, float* __restrict__ NV) {
  const int s = blockIdx.x, b = blockIdx.y, t = threadIdx.x;
  const size_t tok = (size_t)b * 1024 + s;
  const float* row = qkv + tok * 3072;
  const float* cr = cosb + s * 128;
  const float* sr = sinb + s * 128;
  for (int i = t; i < 1024; i += 256) {
    const int h = i >> 6, d = i & 63;
    const float v1 = row[h * 128 + d] + bq[h * 128 + d];
    const float v2 = row[h * 128 + d + 64] + bq[h * 128 + d + 64];
    const float o1 = v1 * cr[d] - v2 * sr[d];
    const float o2 = v2 * cr[d + 64] + v1 * sr[d + 64];
    const size_t qb = (((size_t)(b * 16 + h)) * 1024 + s) * 128;
    QR[qb + d] = f2bf(o1);
    QR[qb + d + 64] = f2bf(o2);
  }
  {
    const int h = t >> 6, d = t & 63;
    const float v1 = row[2048 + h * 128 + d] + bk[h * 128 + d];
    const float v2 = row[2048 + h * 128 + d + 64] + bk[h * 128 + d + 64];
    const float o1 = v1 * cr[d] - v2 * sr[d];
    const float o2 = v2 * cr[d + 64] + v1 * sr[d + 64];
    const size_t kb = (((size_t)(b * 4 + h)) * 1024 + s) * 128;
    KR[kb + d] = f2bf(o1);
    KR[kb + d + 64] = f2bf(o2);
    const size_t ob = tok * 2048;
#pragma unroll
    for (int rep = 0; rep < 4; ++rep) {
      NK[ob + (h * 4 + rep) * 128 + d] = o1;
      NK[ob + (h * 4 + rep) * 128 + d + 64] = o2;
    }
  }
  for (int i = t; i < 512; i += 256) {
    const int h = i >> 7, d = i & 127;
    const float v = row[2560 + i] + bv[i];
    VB[(((size_t)(b * 4 + h)) * 1024 + s) * 128 + d] = f2bf(v);
    const size_t ob = tok * 2048;
#pragma unroll
    for (int rep = 0; rep < 4; ++rep) NV[ob + (h * 4 + rep) * 128 + d] = v;
  }
}

// ---------------- Flash attention, 64 q-rows per block ----------------
__global__ __launch_bounds__(256) void attn_k(const u16* __restrict__ Q,
                                              const u16* __restrict__ Kc,
                                              const u16* __restrict__ Vc,
                                              u16* __restrict__ O) {
  const int qt = blockIdx.x, h = blockIdx.y, b = blockIdx.z;
  const int t = threadIdx.x, w = t >> 6, l = t & 63;
  const int kvh = h >> 2;
  __shared__ u16 Ks[64 * 128];
  __shared__ u16 Vt[128 * 66];
  __shared__ u16 Ps[4][16 * 68];
  const int l15 = l & 15, l4 = l >> 4;
  bf16x8 qf[4];
  {
    const u16* qb = Q + (((size_t)(b * 16 + h)) * 1024 + qt * 64 + w * 16 + l15) * 128 + l4 * 8;
#pragma unroll
    for (int c = 0; c < 4; ++c) qf[c] = *(const bf16x8*)(qb + c * 32);
  }
  float m_run[4] = {-1e30f, -1e30f, -1e30f, -1e30f};
  float l_run[4] = {0.f, 0.f, 0.f, 0.f};
  f32x4 accO[8] = {};
  const size_t kvbase = ((size_t)(b * 4 + kvh)) * 1024 * 128;
  const int ntiles = qt + 1;
  for (int kt = 0; kt < ntiles; ++kt) {
    __syncthreads();
    {
      const int key = t >> 2;
      const u16* kg = Kc + kvbase + (size_t)(kt * 64 + key) * 128;
      const u16* vg = Vc + kvbase + (size_t)(kt * 64 + key) * 128;
      const int sw = (key & 7) << 4;
#pragma unroll
      for (int p = 0; p < 4; ++p) {
        const int ch = (t & 3) * 4 + p;
        *(u16x8*)((char*)Ks + key * 256 + ((ch * 16) ^ sw)) = *(const u16x8*)(kg + ch * 8);
        const int d0 = ch * 8;
        u16x8 vv = *(const u16x8*)(vg + d0);
#pragma unroll
        for (int j = 0; j < 8; ++j) Vt[(d0 + j) * 66 + key] = vv[j];
      }
    }
    __syncthreads();
    f32x4 sf[4] = {};
#pragma unroll
    for (int nf = 0; nf < 4; ++nf) {
      const int keyl = nf * 16 + l15;
      const int sw = (keyl & 7) << 4;
      const char* kbase = (const char*)Ks + keyl * 256;
#pragma unroll
      for (int c = 0; c < 4; ++c) {
        bf16x8 kf = *(const bf16x8*)(kbase + ((c * 64 + l4 * 16) ^ sw));
        sf[nf] = __builtin_amdgcn_mfma_f32_16x16x32_bf16(qf[c], kf, sf[nf], 0, 0, 0);
      }
    }
    const int qg0 = qt * 64 + w * 16 + l4 * 4;
    float alpha[4];
#pragma unroll
    for (int r = 0; r < 4; ++r) {
      const int qg = qg0 + r;
      float tm = -1e30f;
#pragma unroll
      for (int nf = 0; nf < 4; ++nf) {
        const int kg = kt * 64 + nf * 16 + l15;
        float sv = sf[nf][r] * 0.088388347648318447f;
        sv = (kg <= qg) ? sv : -1e30f;
        sf[nf][r] = sv;
        tm = fmaxf(tm, sv);
      }
#pragma unroll
      for (int mm = 1; mm < 16; mm <<= 1) tm = fmaxf(tm, __shfl_xor(tm, mm));
      const float mn = fmaxf(m_run[r], tm);
      alpha[r] = __expf(m_run[r] - mn);
      m_run[r] = mn;
      float rs = 0.f;
#pragma unroll
      for (int nf = 0; nf < 4; ++nf) {
        const float p = __expf(sf[nf][r] - mn);
        sf[nf][r] = p;
        rs += p;
      }
#pragma unroll
      for (int mm = 1; mm < 16; mm <<= 1) rs += __shfl_xor(rs, mm);
      l_run[r] = l_run[r] * alpha[r] + rs;
    }
#pragma unroll
    for (int nf = 0; nf < 8; ++nf)
#pragma unroll
      for (int r = 0; r < 4; ++r) accO[nf][r] *= alpha[r];
#pragma unroll
    for (int nf = 0; nf < 4; ++nf)
#pragma unroll
      for (int r = 0; r < 4; ++r)
        Ps[w][(l4 * 4 + r) * 68 + nf * 16 + l15] = f2bf(sf[nf][r]);
    __syncthreads();
#pragma unroll
    for (int kc = 0; kc < 2; ++kc) {
      const u16* pb = &Ps[w][0] + l15 * 68 + kc * 32 + l4 * 8;
      union { u16x4 q[2]; bf16x8 v; } pu;
      pu.q[0] = *(const u16x4*)pb;
      pu.q[1] = *(const u16x4*)(pb + 4);
#pragma unroll
      for (int nf = 0; nf < 8; ++nf) {
        const int dd = nf * 16 + l15;
        const u16* vp = &Vt[0] + dd * 66 + kc * 32 + l4 * 8;
        union { u32 u[4]; bf16x8 v; } vu;
        vu.u[0] = *(const u32*)(vp);
        vu.u[1] = *(const u32*)(vp + 2);
        vu.u[2] = *(const u32*)(vp + 4);
        vu.u[3] = *(const u32*)(vp + 6);
        accO[nf] = __builtin_amdgcn_mfma_f32_16x16x32_bf16(pu.v, vu.v, accO[nf], 0, 0, 0);
      }
    }
  }
  const int qg0 = qt * 64 + w * 16 + l4 * 4;
#pragma unroll
  for (int nf = 0; nf < 8; ++nf) {
    const int dd = nf * 16 + l15;
#pragma unroll
    for (int r = 0; r < 4; ++r) {
      const float o = accO[nf][r] / l_run[r];
      O[((size_t)(b * 1024 + qg0 + r)) * 2048 + h * 128 + dd] = f2bf(o);
    }
  }
}

// ---------------- Router ----------------
__global__ __launch_bounds__(256) void router_k(
    const float* __restrict__ x2, const float* __restrict__ wn, const float* __restrict__ rw,
    int* __restrict__ topi2, float* __restrict__ topw2,
    int* __restrict__ counts, u64* __restrict__ pmean) {
  const int t = threadIdx.x, w = t >> 6, l = t & 63;
  const int tok = blockIdx.x * 4 + w;
  __shared__ int lc[8];
  __shared__ u64 lp[8];
  if (t < 8) { lc[t] = 0; lp[t] = 0ull; }
  __syncthreads();
  const float* xr = x2 + (size_t)tok * DD;
  float ss = 0.f;
#pragma unroll
  for (int i = 0; i < 8; ++i) {
    float4 v = *(const float4*)(xr + l * 32 + i * 4);
    ss += v.x * v.x + v.y * v.y + v.z * v.z + v.w * v.w;
  }
#pragma unroll
  for (int m = 1; m < 64; m <<= 1) ss += __shfl_xor(ss, m);
  const float sc = rsqrtf(ss * (1.f / DD) + 1e-6f);
  float acc[8] = {};
  for (int i = 0; i < 32; ++i) {
    const int d = l * 32 + i;
    const float hv = xr[d] * sc * wn[d];
    float4 r0 = *(const float4*)(rw + d * 8);
    float4 r1 = *(const float4*)(rw + d * 8 + 4);
    acc[0] += hv * r0.x; acc[1] += hv * r0.y; acc[2] += hv * r0.z; acc[3] += hv * r0.w;
    acc[4] += hv * r1.x; acc[5] += hv * r1.y; acc[6] += hv * r1.z; acc[7] += hv * r1.w;
  }
#pragma unroll
  for (int m = 1; m < 64; m <<= 1)
#pragma unroll
    for (int e = 0; e < 8; ++e) acc[e] += __shfl_xor(acc[e], m);
  if (l == 0) {
    float mx = acc[0];
#pragma unroll
    for (int e = 1; e < 8; ++e) mx = fmaxf(mx, acc[e]);
    float p[8], sum = 0.f;
#pragma unroll
    for (int e = 0; e < 8; ++e) { p[e] = __expf(acc[e] - mx); sum += p[e]; }
    const float inv = 1.f / sum;
#pragma unroll
    for (int e = 0; e < 8; ++e) p[e] *= inv;
    int e0 = 0; float v0 = p[0];
#pragma unroll
    for (int e = 1; e < 8; ++e) if (p[e] > v0) { v0 = p[e]; e0 = e; }
    int e1 = (e0 == 0) ? 1 : 0; float v1 = p[e1];
#pragma unroll
    for (int e = 0; e < 8; ++e) if (e != e0 && p[e] > v1) { v1 = p[e]; e1 = e; }
    const float wsum = v0 + v1;
    topi2[tok * 2] = e0; topi2[tok * 2 + 1] = e1;
    topw2[tok * 2] = v0 / wsum; topw2[tok * 2 + 1] = v1 / wsum;
    atomicAdd(&lc[e0], 1); atomicAdd(&lc[e1], 1);
#pragma unroll
    for (int e = 0; e < 8; ++e) atomicAdd(&lp[e], (u64)((double)p[e] * 4294967296.0));
  }
  __syncthreads();
  if (t < 8) {
    if (lc[t]) atomicAdd(&counts[t], lc[t]);
    if (lp[t]) atomicAdd(&pmean[t], lp[t]);
  }
}

__global__ __launch_bounds__(256) void zero_k(int* __restrict__ counts, u64* __restrict__ pmean,
                                              int* __restrict__ slot_tok, float* __restrict__ slot_w) {
  const int i = blockIdx.x * 256 + threadIdx.x;
  if (i < 5120) { slot_tok[i] = 0; slot_w[i] = 0.f; }
  if (i < 8) { counts[i] = 0; pmean[i] = 0ull; }
}

__global__ void scan_k(const int* __restrict__ counts, int* __restrict__ cursors,
                       int* __restrict__ tiletab, const u64* __restrict__ pmean,
                       float* __restrict__ auxout) {
  if (threadIdx.x == 0) {
    int off = 0, nt = 0;
    double aux = 0.0;
    for (int e = 0; e < 8; ++e) {
      cursors[e] = off;
      const int c = counts[e];
      const int nte = (c + 127) >> 7;
      for (int i = 0; i < nte; ++i) {
        tiletab[1 + nt * 2] = e;
        tiletab[2 + nt * 2] = off + i * 128;
        ++nt;
      }
      off += nte * 128;
      const double pm = ((double)pmean[e] / 4294967296.0) / 2048.0;
      aux += ((double)c / 4096.0) * pm;
    }
    tiletab[0] = nt;
    *auxout = (float)(8.0 * aux);
  }
}

__global__ __launch_bounds__(256) void assign_k(const int* __restrict__ topi2,
                                                const float* __restrict__ topw2,
                                                int* __restrict__ cursors,
                                                int* __restrict__ slot_tok,
                                                float* __restrict__ slot_w,
                                                int* __restrict__ tok_slot) {
  const int tok = blockIdx.x * 256 + threadIdx.x;
#pragma unroll
  for (int j = 0; j < 2; ++j) {
    const int e = topi2[tok * 2 + j];
    const int s = atomicAdd(&cursors[e], 1);
    slot_tok[s] = tok;
    slot_w[s] = topw2[tok * 2 + j];
    tok_slot[tok * 2 + j] = s;
  }
}

__global__ __launch_bounds__(256) void final_k(float* __restrict__ out,
                                               const u16* __restrict__ routed,
                                               const int* __restrict__ tok_slot) {
  const int tok = blockIdx.x, t = threadIdx.x;
  const int s0 = tok_slot[tok * 2], s1 = tok_slot[tok * 2 + 1];
  u16x8 a = ((const u16x8*)(routed + (size_t)s0 * DD))[t];
  u16x8 b = ((const u16x8*)(routed + (size_t)s1 * DD))[t];
  float* o = out + (size_t)tok * DD + t * 8;
  float4 o0 = *(const float4*)o;
  float4 o1 = *(const float4*)(o + 4);
  o0.x += bf2f(a[0]) + bf2f(b[0]); o0.y += bf2f(a[1]) + bf2f(b[1]);
  o0.z += bf2f(a[2]) + bf2f(b[2]); o0.w += bf2f(a[3]) + bf2f(b[3]);
  o1.x += bf2f(a[4]) + bf2f(b[4]); o1.y += bf2f(a[5]) + bf2f(b[5]);
  o1.z += bf2f(a[6]) + bf2f(b[6]); o1.w += bf2f(a[7]) + bf2f(b[7]);
  *(float4*)o = o0;
  *(float4*)(o + 4) = o1;
}

extern "C" void kernel_launch(void* const* d_in, const int* in_sizes, int n_in,
                              void* d_out, int out_size, void* d_ws, size_t ws_size,
                              hipStream_t stream) {
  (void)in_sizes; (void)n_in; (void)out_size; (void)ws_size;
  const float* x    = (const float*)d_in[0];
  const float* rc   = (const float*)d_in[1];
  const float* rs   = (const float*)d_in[2];
  const float* anw  = (const float*)d_in[3];
  const float* fnw  = (const float*)d_in[4];
  const float* wq   = (const float*)d_in[5];
  const float* bq   = (const float*)d_in[6];
  const float* wk   = (const float*)d_in[7];
  const float* bk   = (const float*)d_in[8];
  const float* wv   = (const float*)d_in[9];
  const float* bv   = (const float*)d_in[10];
  const float* wo   = (const float*)d_in[11];
  const float* rw   = (const float*)d_in[12];
  const float* wg   = (const float*)d_in[13];
  const float* wu   = (const float*)d_in[14];
  const float* wd   = (const float*)d_in[15];
  const float* wsg  = (const float*)d_in[16];
  const float* wsu  = (const float*)d_in[17];
  const float* wsd  = (const float*)d_in[18];

  const size_t MB = (size_t)1 << 20;
  char* ws = (char*)d_ws;
  float* X2  = (float*)(ws + 0);          // 16 MiB
  u16*   HN  = (u16*)(ws + 16 * MB);      // 8 MiB
  char*  SM  = ws + 24 * MB;              // 1 MiB small
  char*  AR  = ws + 25 * MB;              // 123 MiB arena

  int*   CNT   = (int*)(SM);
  u64*   PM    = (u64*)(SM + 64);
  int*   CURS  = (int*)(SM + 256);
  int*   TILT  = (int*)(SM + 512);
  int*   TOPI  = (int*)(SM + 4096);
  float* TOPW  = (float*)(SM + 40960);
  int*   STOK  = (int*)(SM + 73728);
  float* SW    = (float*)(SM + 98304);
  int*   TSLOT = (int*)(SM + 131072);

  // P1 (qkv)
  u16*   H      = (u16*)(AR);             // 8 MiB
  u16*   WTQ    = (u16*)(AR + 8 * MB);    // 12 MiB
  float* PARTSQ = (float*)(AR + 20 * MB); // 48 MiB
  float* QKVF   = (float*)(AR + 68 * MB); // 24 MiB
  // P2 (attn)
  u16*   QR    = (u16*)(AR);              // 8 MiB
  u16*   KR    = (u16*)(AR + 8 * MB);     // 2 MiB
  u16*   VBb   = (u16*)(AR + 10 * MB);    // 2 MiB
  u16*   ATTNO = (u16*)(AR + 12 * MB);    // 8 MiB
  // P3 (wo)
  u16*   WTO    = (u16*)(AR + 20 * MB);   // 8 MiB
  float* PARTSW = (float*)(AR + 28 * MB); // 64 MiB
  // P5 (shared expert, gemm8)
  u16*   WTS    = (u16*)(AR);             // 44 MiB (transposed wsg -> wsu -> wsd)
  u16*   G      = (u16*)(AR + 44 * MB);   // 44 MiB (gate, then silu(g)*u in place)
  u16*   PARTSD = (u16*)(AR + 88 * MB);   // 32 MiB (4 x 8 MiB bf16 parts)
  // P6 (routed experts)
  u16*   WTE    = (u16*)(AR);             // 64 MiB
  u16*   GEXP   = (u16*)(AR + 64 * MB);   // 20 MiB
  u16*   ROUTED = (u16*)(AR + 84 * MB);   // 20 MiB

  float* out  = (float*)d_out;
  float* NK   = out + 4194304;
  float* NV   = out + 2 * 4194304;
  float* AUXO = out + 3 * 4194304;

  const dim3 b256(256);
  const dim3 b512(512);

  // P1: attn rmsnorm + QKV projection (split-K x2, 128^2)
  rmsnorm_k<<<TT, b256, 0, stream>>>(x, anw, H);
  transp_k<<<dim3(32, 32, 1), b256, 0, stream>>>(wq, WTQ, 2048, 2048);
  transp_k<<<dim3(8, 32, 1), b256, 0, stream>>>(wk, WTQ + (size_t)2048 * 2048, 2048, 512);
  transp_k<<<dim3(8, 32, 1), b256, 0, stream>>>(wv, WTQ + (size_t)2560 * 2048, 2048, 512);
  gemm2<0, false, false, true><<<dim3(24, 16, 2), b256, 0, stream>>>(
      H, WTQ, PARTSQ, nullptr, nullptr, nullptr, nullptr, TT, 3072, 2048, 1024);
  red_k<2, false><<<6144, b256, 0, stream>>>(QKVF, nullptr, PARTSQ, 1572864);
  // P2: rope + attention
  rope_k<<<dim3(1024, 2), b256, 0, stream>>>(QKVF, rc, rs, bq, bk, bv, QR, KR, VBb, NK, NV);
  attn_k<<<dim3(16, 16, 2), b256, 0, stream>>>(QR, KR, VBb, ATTNO);
  // P3: x2 = x + attno @ wo (split-K x4, 128^2)
  transp_k<<<dim3(32, 32, 1), b256, 0, stream>>>(wo, WTO, 2048, 2048);
  gemm2<0, false, false, true><<<dim3(16, 16, 4), b256, 0, stream>>>(
      ATTNO, WTO, PARTSW, nullptr, nullptr, nullptr, nullptr, TT, 2048, 2048, 512);
  red_k<4, true><<<4096, b256, 0, stream>>>(X2, x, PARTSW, 1048576);
  // P4: ffn rmsnorm + routing
  rmsnorm_k<<<TT, b256, 0, stream>>>(X2, fnw, HN);
  zero_k<<<20, b256, 0, stream>>>(CNT, PM, STOK, SW);
  router_k<<<512, b256, 0, stream>>>(X2, fnw, rw, TOPI, TOPW, CNT, PM);
  scan_k<<<1, 64, 0, stream>>>(CNT, CURS, TILT, PM, AUXO);
  assign_k<<<8, b256, 0, stream>>>(TOPI, TOPW, CURS, STOK, SW, TSLOT);
  // P5: shared expert via gemm8 (256^2 8-phase)
  transp_k<<<dim3(172, 32, 1), b256, 0, stream>>>(wsg, WTS, 2048, FSH);
  gemm8<2, false><<<dim3(43, 8, 1), b512, 0, stream>>>(HN, WTS, G, nullptr, TT, FSH, 2048);
  transp_k<<<dim3(172, 32, 1), b256, 0, stream>>>(wsu, WTS, 2048, FSH);
  gemm8<3, false><<<dim3(43, 8, 1), b512, 0, stream>>>(HN, WTS, G, G, TT, FSH, 2048);
  transp_k<<<dim3(32, 172, 1), b256, 0, stream>>>(wsd, WTS, FSH, 2048);
  gemm8<10, true><<<dim3(8, 8, 4), b512, 0, stream>>>(G, WTS, PARTSD, nullptr, TT, 2048, FSH);
  redbf_k<<<2048, b256, 0, stream>>>(out, X2, PARTSD);
  // P6: routed experts (128^2, padded tile table)
  transp_k<<<dim3(32, 32, 8), b256, 0, stream>>>(wg, WTE, 2048, 2048);
  gemm2<2, true, true, false><<<dim3(16, 40, 1), b256, 0, stream>>>(
      HN, WTE, GEXP, nullptr, nullptr, STOK, TILT, 5120, 2048, 2048, 0);
  transp_k<<<dim3(32, 32, 8), b256, 0, stream>>>(wu, WTE, 2048, 2048);
  gemm2<3, true, true, false><<<dim3(16, 40, 1), b256, 0, stream>>>(
      HN, WTE, GEXP, GEXP, nullptr, STOK, TILT, 5120, 2048, 2048, 0);
  transp_k<<<dim3(32, 32, 8), b256, 0, stream>>>(wd, WTE, 2048, 2048);
  gemm2<4, true, false, false><<<dim3(16, 40, 1), b256, 0, stream>>>(
      GEXP, WTE, ROUTED, nullptr, SW, STOK, TILT, 5120, 2048, 2048, 0);
  // P7: out += routed
  final_k<<<TT, b256, 0, stream>>>(out, ROUTED, TSLOT);
}

// Round 4
// 990.857 us; speedup vs baseline: 1.4777x; 1.0457x over previous
//
#include <hip/hip_runtime.h>

typedef unsigned short u16;
typedef unsigned int u32;
typedef unsigned long long u64;
typedef __attribute__((ext_vector_type(4))) unsigned short u16x4;
typedef __attribute__((ext_vector_type(8))) unsigned short u16x8;
typedef __attribute__((ext_vector_type(4))) float f32x4;
typedef __attribute__((ext_vector_type(8))) __bf16 bf16x8;

#define DD 2048
#define TT 2048
#define FSH 11008

__device__ __forceinline__ float bf2f(u16 u) {
  union { u32 i; float f; } v; v.i = ((u32)u) << 16; return v.f;
}
__device__ __forceinline__ u16 f2bf(float f) {
  union { float f; u32 i; } v; v.f = f;
  u32 r = v.i + 0x7fffu + ((v.i >> 16) & 1u);
  return (u16)(r >> 16);
}
__device__ __forceinline__ void gld16(const void* g, void* l) {
  __builtin_amdgcn_global_load_lds((const __attribute__((address_space(1))) void*)g,
                                   (__attribute__((address_space(3))) void*)l, 16, 0, 0);
}

#define MFMA16(d, a, b) d = __builtin_amdgcn_mfma_f32_16x16x32_bf16(a, b, d, 0, 0, 0)

// ---------------- RMSNorm: f32 row -> bf16 row ----------------
__global__ __launch_bounds__(256) void rmsnorm_k(const float* __restrict__ x,
                                                 const float* __restrict__ w,
                                                 u16* __restrict__ out) {
  const int t = threadIdx.x;
  const float* xr = x + (size_t)blockIdx.x * DD;
  float4 a = *(const float4*)(xr + t * 8);
  float4 b = *(const float4*)(xr + t * 8 + 4);
  float ss = a.x*a.x + a.y*a.y + a.z*a.z + a.w*a.w
           + b.x*b.x + b.y*b.y + b.z*b.z + b.w*b.w;
#pragma unroll
  for (int m = 1; m < 64; m <<= 1) ss += __shfl_xor(ss, m);
  __shared__ float red[4];
  if ((t & 63) == 0) red[t >> 6] = ss;
  __syncthreads();
  float sc = rsqrtf((red[0] + red[1] + red[2] + red[3]) * (1.f / DD) + 1e-6f);
  float4 wa = *(const float4*)(w + t * 8);
  float4 wb = *(const float4*)(w + t * 8 + 4);
  u16x8 o;
  o[0] = f2bf(a.x * sc * wa.x); o[1] = f2bf(a.y * sc * wa.y);
  o[2] = f2bf(a.z * sc * wa.z); o[3] = f2bf(a.w * sc * wa.w);
  o[4] = f2bf(b.x * sc * wb.x); o[5] = f2bf(b.y * sc * wb.y);
  o[6] = f2bf(b.z * sc * wb.z); o[7] = f2bf(b.w * sc * wb.w);
  *(u16x8*)(out + (size_t)blockIdx.x * DD + t * 8) = o;
}

// ---------------- Transpose+convert v2: W[R][C] f32 -> Wt[C][R] bf16 ----------------
// LDS tile stored [n][k] (stride 80, 16B-aligned); writes are 16B/lane coalesced.
__global__ __launch_bounds__(256) void transp_k(const float* __restrict__ W,
                                                u16* __restrict__ Wt, int R, int C) {
  __shared__ u16 tile[64 * 80];
  const size_t msz = (size_t)R * C;
  const float* Wm = W + msz * blockIdx.z;
  u16* Wtm = Wt + msz * blockIdx.z;
  const int t = threadIdx.x;
  const int n0 = blockIdx.x * 64, k0 = blockIdx.y * 64;
#pragma unroll
  for (int p = 0; p < 4; ++p) {
    const int kk = (t >> 4) + p * 16;
    const int nn = (t & 15) * 4;
    float4 v = *(const float4*)(Wm + (size_t)(k0 + kk) * C + n0 + nn);
    tile[(nn + 0) * 80 + kk] = f2bf(v.x);
    tile[(nn + 1) * 80 + kk] = f2bf(v.y);
    tile[(nn + 2) * 80 + kk] = f2bf(v.z);
    tile[(nn + 3) * 80 + kk] = f2bf(v.w);
  }
  __syncthreads();
#pragma unroll
  for (int p = 0; p < 2; ++p) {
    const int n = (t >> 3) + p * 32;
    const int c = t & 7;
    u16x8 v = *(const u16x8*)(tile + n * 80 + c * 8);
    *(u16x8*)(Wtm + (size_t)(n0 + n) * R + k0 + c * 8) = v;
  }
}

// ---------------- GEMM2 (128^2 m97-style) ----------------
// EPI: 0=f32 store(splitK parts), 2=bf16 store, 3=bf16 silu(aux)*acc, 4=bf16 slotw[row]*acc
template <int EPI, bool EXPERT, bool INDIR, bool SPLITK>
__global__ __launch_bounds__(256) void gemm2(
    const u16* __restrict__ A, const u16* __restrict__ Bt, void* __restrict__ Cp,
    const void* __restrict__ aux, const float* __restrict__ slotw,
    const int* __restrict__ slot_tok, const int* __restrict__ tiletab,
    int M, int N, int K, int Kc) {
  __shared__ u16 lA[128 * 32];
  __shared__ u16 lB[128 * 32];
  const int t = threadIdx.x, w = t >> 6, l = t & 63;
  const int n0 = blockIdx.x * 128;
  int m0;
  if constexpr (EXPERT) {
    const int ntil = tiletab[0];
    if ((int)blockIdx.y >= ntil) return;
    const int e = tiletab[1 + blockIdx.y * 2];
    m0 = tiletab[2 + blockIdx.y * 2];
    Bt += (size_t)e * N * K;
  } else {
    m0 = blockIdx.y * 128;
  }
  int kbase = 0, KC = K;
  if constexpr (SPLITK) { kbase = blockIdx.z * Kc; KC = Kc; }
  const int srow = w * 16 + (l >> 2);
  const int scol = (l & 3) * 8;
  const int r0 = m0 + srow, r1 = m0 + srow + 64;
  const u16 *ag0, *ag1;
  if constexpr (INDIR) {
    ag0 = A + (size_t)slot_tok[r0] * K + scol + kbase;
    ag1 = A + (size_t)slot_tok[r1] * K + scol + kbase;
  } else {
    ag0 = A + (size_t)r0 * K + scol + kbase;
    ag1 = A + (size_t)r1 * K + scol + kbase;
  }
  const u16* bg0 = Bt + (size_t)(n0 + srow) * K + scol + kbase;
  const u16* bg1 = Bt + (size_t)(n0 + srow + 64) * K + scol + kbase;
  u16* la = lA + w * 512;
  u16* lb = lB + w * 512;
  const int l15 = l & 15, l4 = l >> 4;
  const int wm = w >> 1, wn = w & 1;
  const int fa = (wm * 64 + l15) * 32 + l4 * 8;
  const int fb = (wn * 64 + l15) * 32 + l4 * 8;
  f32x4 acc[4][4] = {};
  for (int ko = 0; ko < KC; ko += 32) {
    __syncthreads();
    gld16(ag0 + ko, la);
    gld16(ag1 + ko, la + 2048);
    gld16(bg0 + ko, lb);
    gld16(bg1 + ko, lb + 2048);
    asm volatile("s_waitcnt vmcnt(0)" ::: "memory");
    __syncthreads();
    bf16x8 af[4], bf[4];
#pragma unroll
    for (int i = 0; i < 4; ++i) {
      af[i] = *(const bf16x8*)(lA + fa + i * 512);
      bf[i] = *(const bf16x8*)(lB + fb + i * 512);
    }
#pragma unroll
    for (int mi = 0; mi < 4; ++mi)
#pragma unroll
      for (int ni = 0; ni < 4; ++ni)
        MFMA16(acc[mi][ni], af[mi], bf[ni]);
  }
  float* Cf = (float*)Cp;
  if constexpr (SPLITK) Cf += (size_t)blockIdx.z * M * N;
#pragma unroll
  for (int mi = 0; mi < 4; ++mi) {
#pragma unroll
    for (int r = 0; r < 4; ++r) {
      const int row = m0 + wm * 64 + mi * 16 + l4 * 4 + r;
#pragma unroll
      for (int ni = 0; ni < 4; ++ni) {
        const int col = n0 + wn * 64 + ni * 16 + l15;
        const size_t idx = (size_t)row * N + col;
        const float v = acc[mi][ni][r];
        if constexpr (EPI == 0) Cf[idx] = v;
        else if constexpr (EPI == 2) ((u16*)Cp)[idx] = f2bf(v);
        else if constexpr (EPI == 3) {
          const float g = bf2f(((const u16*)aux)[idx]);
          ((u16*)Cp)[idx] = f2bf(v * g / (1.f + __expf(-g)));
        } else {
          ((u16*)Cp)[idx] = f2bf(slotw[row] * v);
        }
      }
    }
  }
}

// ---------------- GEMM8: 256^2, 8-wave, 8-phase, hoisted stage addresses ----------------
// EPI: 2=bf16 store, 3=bf16 silu(aux)*acc, 10=bf16 split-K parts, 11=f32 split-K parts
template <int EPI, bool SPLITK>
__global__ __launch_bounds__(512, 2) void gemm8(
    const u16* __restrict__ A, const u16* __restrict__ Bt, void* __restrict__ Cp,
    const u16* __restrict__ aux, int M, int N, int K, int Kc) {
  __shared__ char lds[131072];  // [buf][A 32K | B 32K]
  const int t = threadIdx.x, w = t >> 6, l = t & 63;
  const int gx = gridDim.x;
  const int nwg = gx * gridDim.y;     // % 8 == 0
  int wg = blockIdx.y * gx + blockIdx.x;
  wg = (wg & 7) * (nwg >> 3) + (wg >> 3);   // XCD swizzle (bijective)
  const int n0 = (wg % gx) * 256;
  const int m0 = (wg / gx) * 256;
  int kbase = 0, KC = K;
  if constexpr (SPLITK) {
    kbase = blockIdx.z * Kc;
    const int rem = K - kbase;
    KC = rem < Kc ? rem : Kc;
  }
  const int ktiles = KC >> 6;         // even
  const int wm = w >> 2, wn = w & 3;
  const int l15 = l & 15, l4 = l >> 4;
  const int sro = l >> 3, sc = l & 7;

  // hoisted stage addresses: [isB][h][i] lane pointer + wave-uniform LDS offset
  const u16* sgp[2][2][2];
  u32 sdo[2][2][2];
#pragma unroll
  for (int isB = 0; isB < 2; ++isB)
#pragma unroll
    for (int h = 0; h < 2; ++h)
#pragma unroll
      for (int i = 0; i < 2; ++i) {
        const int q = i * 8 + w;
        const int r0 = isB ? (((q >> 2) << 6) + h * 32 + (q & 3) * 8)
                           : (((q & 8) << 4) + h * 64 + (q & 7) * 8);
        const int r = r0 + sro;
        const int cl = sc ^ (r & 7);
        const u16* base = isB ? (Bt + (size_t)(n0 + r) * K) : (A + (size_t)(m0 + r) * K);
        sgp[isB][h][i] = base + kbase + cl * 8;
        sdo[isB][h][i] = (u32)(isB * 32768 + r0 * 128);
      }
  auto stage = [&](int b, int isB, int h, int kt) {
    const int kk = kt < ktiles ? kt : ktiles - 1;
#pragma unroll
    for (int i = 0; i < 2; ++i)
      gld16(sgp[isB][h][i] + kk * 64, lds + b * 65536 + sdo[isB][h][i]);
  };
  auto ldA = [&](int b, int mi, int ks) {
    const int row = wm * 128 + mi * 16 + l15;
    const int ch = (ks * 4 + l4) ^ (row & 7);
    return *(const bf16x8*)(lds + b * 65536 + row * 128 + ch * 16);
  };
  auto ldB = [&](int b, int ni, int ks) {
    const int row = wn * 64 + ni * 16 + l15;
    const int ch = (ks * 4 + l4) ^ (row & 7);
    return *(const bf16x8*)(lds + b * 65536 + 32768 + row * 128 + ch * 16);
  };

  f32x4 acc[8][4] = {};
  bf16x8 aR[4][2], b0[2][2], b1[2][2];

  // prologue: tile0 full (buf0) + tile1 {A0,B1,A1} (buf1); B0(1) staged at P1
  stage(0, 0, 0, 0); stage(0, 1, 0, 0); stage(0, 1, 1, 0); stage(0, 0, 1, 0);
  stage(1, 0, 0, 1); stage(1, 1, 1, 1); stage(1, 0, 1, 1);
  asm volatile("s_waitcnt vmcnt(6)" ::: "memory");
  __builtin_amdgcn_s_barrier();

  for (int kt = 0; kt < ktiles; kt += 2) {
    // P1
#pragma unroll
    for (int mi = 0; mi < 4; ++mi) { aR[mi][0] = ldA(0, mi, 0); aR[mi][1] = ldA(0, mi, 1); }
#pragma unroll
    for (int ni = 0; ni < 2; ++ni) { b0[ni][0] = ldB(0, ni, 0); b0[ni][1] = ldB(0, ni, 1); }
    stage(1, 1, 0, kt + 1);
    __builtin_amdgcn_s_barrier();
    asm volatile("s_waitcnt lgkmcnt(0)" ::: "memory");
    __builtin_amdgcn_s_setprio(1);
#pragma unroll
    for (int mi = 0; mi < 4; ++mi)
#pragma unroll
      for (int ni = 0; ni < 2; ++ni) {
        MFMA16(acc[mi][ni], aR[mi][0], b0[ni][0]);
        MFMA16(acc[mi][ni], aR[mi][1], b0[ni][1]);
      }
    __builtin_amdgcn_s_setprio(0);
    __builtin_amdgcn_s_barrier();
    // P2
#pragma unroll
    for (int ni = 0; ni < 2; ++ni) { b1[ni][0] = ldB(0, ni + 2, 0); b1[ni][1] = ldB(0, ni + 2, 1); }
    stage(0, 0, 0, kt + 2);
    __builtin_amdgcn_s_barrier();
    asm volatile("s_waitcnt lgkmcnt(0)" ::: "memory");
    __builtin_amdgcn_s_setprio(1);
#pragma unroll
    for (int mi = 0; mi < 4; ++mi)
#pragma unroll
      for (int ni = 0; ni < 2; ++ni) {
        MFMA16(acc[mi][ni + 2], aR[mi][0], b1[ni][0]);
        MFMA16(acc[mi][ni + 2], aR[mi][1], b1[ni][1]);
      }
    __builtin_amdgcn_s_setprio(0);
    __builtin_amdgcn_s_barrier();
    // P3
#pragma unroll
    for (int mi = 0; mi < 4; ++mi) { aR[mi][0] = ldA(0, mi + 4, 0); aR[mi][1] = ldA(0, mi + 4, 1); }
    stage(0, 1, 1, kt + 2);
    __builtin_amdgcn_s_barrier();
    asm volatile("s_waitcnt lgkmcnt(0)" ::: "memory");
    __builtin_amdgcn_s_setprio(1);
#pragma unroll
    for (int mi = 0; mi < 4; ++mi)
#pragma unroll
      for (int ni = 0; ni < 2; ++ni) {
        MFMA16(acc[mi + 4][ni + 2], aR[mi][0], b1[ni][0]);
        MFMA16(acc[mi + 4][ni + 2], aR[mi][1], b1[ni][1]);
      }
    __builtin_amdgcn_s_setprio(0);
    __builtin_amdgcn_s_barrier();
    // P4
    stage(0, 0, 1, kt + 2);
    __builtin_amdgcn_s_barrier();
    __builtin_amdgcn_s_setprio(1);
#pragma unroll
    for (int mi = 0; mi < 4; ++mi)
#pragma unroll
      for (int ni = 0; ni < 2; ++ni) {
        MFMA16(acc[mi + 4][ni], aR[mi][0], b0[ni][0]);
        MFMA16(acc[mi + 4][ni], aR[mi][1], b0[ni][1]);
      }
    __builtin_amdgcn_s_setprio(0);
    asm volatile("s_waitcnt vmcnt(6)" ::: "memory");
    __builtin_amdgcn_s_barrier();
    // P5
#pragma unroll
    for (int mi = 0; mi < 4; ++mi) { aR[mi][0] = ldA(1, mi, 0); aR[mi][1] = ldA(1, mi, 1); }
#pragma unroll
    for (int ni = 0; ni < 2; ++ni) { b0[ni][0] = ldB(1, ni, 0); b0[ni][1] = ldB(1, ni, 1); }
    stage(0, 1, 0, kt + 2);
    __builtin_amdgcn_s_barrier();
    asm volatile("s_waitcnt lgkmcnt(0)" ::: "memory");
    __builtin_amdgcn_s_setprio(1);
#pragma unroll
    for (int mi = 0; mi < 4; ++mi)
#pragma unroll
      for (int ni = 0; ni < 2; ++ni) {
        MFMA16(acc[mi][ni], aR[mi][0], b0[ni][0]);
        MFMA16(acc[mi][ni], aR[mi][1], b0[ni][1]);
      }
    __builtin_amdgcn_s_setprio(0);
    __builtin_amdgcn_s_barrier();
    // P6
#pragma unroll
    for (int ni = 0; ni < 2; ++ni) { b1[ni][0] = ldB(1, ni + 2, 0); b1[ni][1] = ldB(1, ni + 2, 1); }
    stage(1, 0, 0, kt + 3);
    __builtin_amdgcn_s_barrier();
    asm volatile("s_waitcnt lgkmcnt(0)" ::: "memory");
    __builtin_amdgcn_s_setprio(1);
#pragma unroll
    for (int mi = 0; mi < 4; ++mi)
#pragma unroll
      for (int ni = 0; ni < 2; ++ni) {
        MFMA16(acc[mi][ni + 2], aR[mi][0], b1[ni][0]);
        MFMA16(acc[mi][ni + 2], aR[mi][1], b1[ni][1]);
      }
    __builtin_amdgcn_s_setprio(0);
    __builtin_amdgcn_s_barrier();
    // P7
#pragma unroll
    for (int mi = 0; mi < 4; ++mi) { aR[mi][0] = ldA(1, mi + 4, 0); aR[mi][1] = ldA(1, mi + 4, 1); }
    stage(1, 1, 1, kt + 3);
    __builtin_amdgcn_s_barrier();
    asm volatile("s_waitcnt lgkmcnt(0)" ::: "memory");
    __builtin_amdgcn_s_setprio(1);
#pragma unroll
    for (int mi = 0; mi < 4; ++mi)
#pragma unroll
      for (int ni = 0; ni < 2; ++ni) {
        MFMA16(acc[mi + 4][ni + 2], aR[mi][0], b1[ni][0]);
        MFMA16(acc[mi + 4][ni + 2], aR[mi][1], b1[ni][1]);
      }
    __builtin_amdgcn_s_setprio(0);
    __builtin_amdgcn_s_barrier();
    // P8
    stage(1, 0, 1, kt + 3);
    __builtin_amdgcn_s_barrier();
    __builtin_amdgcn_s_setprio(1);
#pragma unroll
    for (int mi = 0; mi < 4; ++mi)
#pragma unroll
      for (int ni = 0; ni < 2; ++ni) {
        MFMA16(acc[mi + 4][ni], aR[mi][0], b0[ni][0]);
        MFMA16(acc[mi + 4][ni], aR[mi][1], b0[ni][1]);
      }
    __builtin_amdgcn_s_setprio(0);
    asm volatile("s_waitcnt vmcnt(6)" ::: "memory");
    __builtin_amdgcn_s_barrier();
  }

  u16* C16 = (u16*)Cp;
  float* Cf = (float*)Cp;
  if constexpr (EPI == 10) C16 += (size_t)blockIdx.z * ((size_t)M * N);
  if constexpr (EPI == 11) Cf += (size_t)blockIdx.z * ((size_t)M * N);
#pragma unroll
  for (int mi = 0; mi < 8; ++mi)
#pragma unroll
    for (int rr = 0; rr < 4; ++rr) {
      const int row = m0 + wm * 128 + mi * 16 + l4 * 4 + rr;
#pragma unroll
      for (int ni = 0; ni < 4; ++ni) {
        const int col = n0 + wn * 64 + ni * 16 + l15;
        const size_t idx = (size_t)row * N + col;
        const float v = acc[mi][ni][rr];
        if constexpr (EPI == 11) {
          Cf[idx] = v;
        } else if constexpr (EPI == 3) {
          const float g = bf2f(aux[idx]);
          C16[idx] = f2bf(v * g / (1.f + __expf(-g)));
        } else {
          C16[idx] = f2bf(v);
        }
      }
    }
}

// ---------------- split-K reduce (f32 parts) ----------------
template <int NP, bool ADDB>
__global__ __launch_bounds__(256) void red_k(float* __restrict__ dst,
                                             const float* __restrict__ base,
                                             const float* __restrict__ parts,
                                             int mn4) {
  const int i = blockIdx.x * 256 + threadIdx.x;
  float4 s;
  if constexpr (ADDB) s = ((const float4*)base)[i];
  else { s.x = s.y = s.z = s.w = 0.f; }
#pragma unroll
  for (int p = 0; p < NP; ++p) {
    const float4 v = ((const float4*)parts)[(size_t)p * mn4 + i];
    s.x += v.x; s.y += v.y; s.z += v.z; s.w += v.w;
  }
  ((float4*)dst)[i] = s;
}

// ---------------- split-K reduce (bf16 parts x4): dst = base + sum ----------------
__global__ __launch_bounds__(256) void redbf_k(float* __restrict__ dst,
                                               const float* __restrict__ base,
                                               const u16* __restrict__ parts) {
  const int i = blockIdx.x * 256 + threadIdx.x;
  float s[8];
  const float* bp = base + (size_t)i * 8;
#pragma unroll
  for (int j = 0; j < 8; ++j) s[j] = bp[j];
#pragma unroll
  for (int p = 0; p < 4; ++p) {
    u16x8 v = ((const u16x8*)parts)[(size_t)p * 524288 + i];
#pragma unroll
    for (int j = 0; j < 8; ++j) s[j] += bf2f(v[j]);
  }
  float* dp = dst + (size_t)i * 8;
#pragma unroll
  for (int j = 0; j < 8; ++j) dp[j] = s[j];
}

// ---------------- RoPE + pack Q/K/V + emit new_k/new_v ----------------
__global__ __launch_bounds__(256) void rope_k(
    const float* __restrict__ qkv, const float* __restrict__ cosb, const float* __restrict__ sinb,
    const float* __restrict__ bq, const float* __restrict__ bk, const float* __restrict__ bv,
    u16* __restrict__ QR, u16* __restrict__ KR, u16* __restrict__ VB,
    float* __restrict__ NK, float* __restrict__ NV) {
  const int s = blockIdx.x, b = blockIdx.y, t = threadIdx.x;
  const size_t tok = (size_t)b * 1024 + s;
  const float* row = qkv + tok * 3072;
  const float* cr = cosb + s * 128;
  const float* sr = sinb + s * 128;
  for (int i = t; i < 1024; i += 256) {
    const int h = i >> 6, d = i & 63;
    const float v1 = row[h * 128 + d] + bq[h * 128 + d];
    const float v2 = row[h * 128 + d + 64] + bq[h * 128 + d + 64];
    const float o1 = v1 * cr[d] - v2 * sr[d];
    const float o2 = v2 * cr[d + 64] + v1 * sr[d + 64];
    const size_t qb = (((size_t)(b * 16 + h)) * 1024 + s) * 128;
    QR[qb + d] = f2bf(o1);
    QR[qb + d + 64] = f2bf(o2);
  }
  {
    const int h = t >> 6, d = t & 63;
    const float v1 = row[2048 + h * 128 + d] + bk[h * 128 + d];
    const float v2 = row[2048 + h * 128 + d + 64] + bk[h * 128 + d + 64];
    const float o1 = v1 * cr[d] - v2 * sr[d];
    const float o2 = v2 * cr[d + 64] + v1 * sr[d + 64];
    const size_t kb = (((size_t)(b * 4 + h)) * 1024 + s) * 128;
    KR[kb + d] = f2bf(o1);
    KR[kb + d + 64] = f2bf(o2);
    const size_t ob = tok * 2048;
#pragma unroll
    for (int rep = 0; rep < 4; ++rep) {
      NK[ob + (h * 4 + rep) * 128 + d] = o1;
      NK[ob + (h * 4 + rep) * 128 + d + 64] = o2;
    }
  }
  for (int i = t; i < 512; i += 256) {
    const int h = i >> 7, d = i & 127;
    const float v = row[2560 + i] + bv[i];
    VB[(((size_t)(b * 4 + h)) * 1024 + s) * 128 + d] = f2bf(v);
    const size_t ob = tok * 2048;
#pragma unroll
    for (int rep = 0; rep < 4; ++rep) NV[ob + (h * 4 + rep) * 128 + d] = v;
  }
}

// ---------------- Flash attention, 64 q-rows per block ----------------
__global__ __launch_bounds__(256) void attn_k(const u16* __restrict__ Q,
                                              const u16* __restrict__ Kc,
                                              const u16* __restrict__ Vc,
                                              u16* __restrict__ O) {
  const int qt = blockIdx.x, h = blockIdx.y, b = blockIdx.z;
  const int t = threadIdx.x, w = t >> 6, l = t & 63;
  const int kvh = h >> 2;
  __shared__ u16 Ks[64 * 128];
  __shared__ u16 Vt[128 * 66];
  __shared__ u16 Ps[4][16 * 68];
  const int l15 = l & 15, l4 = l >> 4;
  bf16x8 qf[4];
  {
    const u16* qb = Q + (((size_t)(b * 16 + h)) * 1024 + qt * 64 + w * 16 + l15) * 128 + l4 * 8;
#pragma unroll
    for (int c = 0; c < 4; ++c) qf[c] = *(const bf16x8*)(qb + c * 32);
  }
  float m_run[4] = {-1e30f, -1e30f, -1e30f, -1e30f};
  float l_run[4] = {0.f, 0.f, 0.f, 0.f};
  f32x4 accO[8] = {};
  const size_t kvbase = ((size_t)(b * 4 + kvh)) * 1024 * 128;
  const int ntiles = qt + 1;
  for (int kt = 0; kt < ntiles; ++kt) {
    __syncthreads();
    {
      const int key = t >> 2;
      const u16* kg = Kc + kvbase + (size_t)(kt * 64 + key) * 128;
      const u16* vg = Vc + kvbase + (size_t)(kt * 64 + key) * 128;
      const int sw = (key & 7) << 4;
#pragma unroll
      for (int p = 0; p < 4; ++p) {
        const int ch = (t & 3) * 4 + p;
        *(u16x8*)((char*)Ks + key * 256 + ((ch * 16) ^ sw)) = *(const u16x8*)(kg + ch * 8);
        const int d0 = ch * 8;
        u16x8 vv = *(const u16x8*)(vg + d0);
#pragma unroll
        for (int j = 0; j < 8; ++j) Vt[(d0 + j) * 66 + key] = vv[j];
      }
    }
    __syncthreads();
    f32x4 sf[4] = {};
#pragma unroll
    for (int nf = 0; nf < 4; ++nf) {
      const int keyl = nf * 16 + l15;
      const int sw = (keyl & 7) << 4;
      const char* kbase = (const char*)Ks + keyl * 256;
#pragma unroll
      for (int c = 0; c < 4; ++c) {
        bf16x8 kf = *(const bf16x8*)(kbase + ((c * 64 + l4 * 16) ^ sw));
        sf[nf] = __builtin_amdgcn_mfma_f32_16x16x32_bf16(qf[c], kf, sf[nf], 0, 0, 0);
      }
    }
    const int qg0 = qt * 64 + w * 16 + l4 * 4;
    float alpha[4];
#pragma unroll
    for (int r = 0; r < 4; ++r) {
      const int qg = qg0 + r;
      float tm = -1e30f;
#pragma unroll
      for (int nf = 0; nf < 4; ++nf) {
        const int kg = kt * 64 + nf * 16 + l15;
        float sv = sf[nf][r] * 0.088388347648318447f;
        sv = (kg <= qg) ? sv : -1e30f;
        sf[nf][r] = sv;
        tm = fmaxf(tm, sv);
      }
#pragma unroll
      for (int mm = 1; mm < 16; mm <<= 1) tm = fmaxf(tm, __shfl_xor(tm, mm));
      const float mn = fmaxf(m_run[r], tm);
      alpha[r] = __expf(m_run[r] - mn);
      m_run[r] = mn;
      float rs = 0.f;
#pragma unroll
      for (int nf = 0; nf < 4; ++nf) {
        const float p = __expf(sf[nf][r] - mn);
        sf[nf][r] = p;
        rs += p;
      }
#pragma unroll
      for (int mm = 1; mm < 16; mm <<= 1) rs += __shfl_xor(rs, mm);
      l_run[r] = l_run[r] * alpha[r] + rs;
    }
#pragma unroll
    for (int nf = 0; nf < 8; ++nf)
#pragma unroll
      for (int r = 0; r < 4; ++r) accO[nf][r] *= alpha[r];
#pragma unroll
    for (int nf = 0; nf < 4; ++nf)
#pragma unroll
      for (int r = 0; r < 4; ++r)
        Ps[w][(l4 * 4 + r) * 68 + nf * 16 + l15] = f2bf(sf[nf][r]);
    __syncthreads();
#pragma unroll
    for (int kc = 0; kc < 2; ++kc) {
      const u16* pb = &Ps[w][0] + l15 * 68 + kc * 32 + l4 * 8;
      union { u16x4 q[2]; bf16x8 v; } pu;
      pu.q[0] = *(const u16x4*)pb;
      pu.q[1] = *(const u16x4*)(pb + 4);
#pragma unroll
      for (int nf = 0; nf < 8; ++nf) {
        const int dd = nf * 16 + l15;
        const u16* vp = &Vt[0] + dd * 66 + kc * 32 + l4 * 8;
        union { u32 u[4]; bf16x8 v; } vu;
        vu.u[0] = *(const u32*)(vp);
        vu.u[1] = *(const u32*)(vp + 2);
        vu.u[2] = *(const u32*)(vp + 4);
        vu.u[3] = *(const u32*)(vp + 6);
        accO[nf] = __builtin_amdgcn_mfma_f32_16x16x32_bf16(pu.v, vu.v, accO[nf], 0, 0, 0);
      }
    }
  }
  const int qg0 = qt * 64 + w * 16 + l4 * 4;
#pragma unroll
  for (int nf = 0; nf < 8; ++nf) {
    const int dd = nf * 16 + l15;
#pragma unroll
    for (int r = 0; r < 4; ++r) {
      const float o = accO[nf][r] / l_run[r];
      O[((size_t)(b * 1024 + qg0 + r)) * 2048 + h * 128 + dd] = f2bf(o);
    }
  }
}

// ---------------- Router ----------------
__global__ __launch_bounds__(256) void router_k(
    const float* __restrict__ x2, const float* __restrict__ wn, const float* __restrict__ rw,
    int* __restrict__ topi2, float* __restrict__ topw2,
    int* __restrict__ counts, u64* __restrict__ pmean) {
  const int t = threadIdx.x, w = t >> 6, l = t & 63;
  const int tok = blockIdx.x * 4 + w;
  __shared__ int lc[8];
  __shared__ u64 lp[8];
  if (t < 8) { lc[t] = 0; lp[t] = 0ull; }
  __syncthreads();
  const float* xr = x2 + (size_t)tok * DD;
  float ss = 0.f;
#pragma unroll
  for (int i = 0; i < 8; ++i) {
    float4 v = *(const float4*)(xr + l * 32 + i * 4);
    ss += v.x * v.x + v.y * v.y + v.z * v.z + v.w * v.w;
  }
#pragma unroll
  for (int m = 1; m < 64; m <<= 1) ss += __shfl_xor(ss, m);
  const float sc = rsqrtf(ss * (1.f / DD) + 1e-6f);
  float acc[8] = {};
  for (int i = 0; i < 32; ++i) {
    const int d = l * 32 + i;
    const float hv = xr[d] * sc * wn[d];
    float4 r0 = *(const float4*)(rw + d * 8);
    float4 r1 = *(const float4*)(rw + d * 8 + 4);
    acc[0] += hv * r0.x; acc[1] += hv * r0.y; acc[2] += hv * r0.z; acc[3] += hv * r0.w;
    acc[4] += hv * r1.x; acc[5] += hv * r1.y; acc[6] += hv * r1.z; acc[7] += hv * r1.w;
  }
#pragma unroll
  for (int m = 1; m < 64; m <<= 1)
#pragma unroll
    for (int e = 0; e < 8; ++e) acc[e] += __shfl_xor(acc[e], m);
  if (l == 0) {
    float mx = acc[0];
#pragma unroll
    for (int e = 1; e < 8; ++e) mx = fmaxf(mx, acc[e]);
    float p[8], sum = 0.f;
#pragma unroll
    for (int e = 0; e < 8; ++e) { p[e] = __expf(acc[e] - mx); sum += p[e]; }
    const float inv = 1.f / sum;
#pragma unroll
    for (int e = 0; e < 8; ++e) p[e] *= inv;
    int e0 = 0; float v0 = p[0];
#pragma unroll
    for (int e = 1; e < 8; ++e) if (p[e] > v0) { v0 = p[e]; e0 = e; }
    int e1 = (e0 == 0) ? 1 : 0; float v1 = p[e1];
#pragma unroll
    for (int e = 0; e < 8; ++e) if (e != e0 && p[e] > v1) { v1 = p[e]; e1 = e; }
    const float wsum = v0 + v1;
    topi2[tok * 2] = e0; topi2[tok * 2 + 1] = e1;
    topw2[tok * 2] = v0 / wsum; topw2[tok * 2 + 1] = v1 / wsum;
    atomicAdd(&lc[e0], 1); atomicAdd(&lc[e1], 1);
#pragma unroll
    for (int e = 0; e < 8; ++e) atomicAdd(&lp[e], (u64)((double)p[e] * 4294967296.0));
  }
  __syncthreads();
  if (t < 8) {
    if (lc[t]) atomicAdd(&counts[t], lc[t]);
    if (lp[t]) atomicAdd(&pmean[t], lp[t]);
  }
}

__global__ __launch_bounds__(256) void zero_k(int* __restrict__ counts, u64* __restrict__ pmean,
                                              int* __restrict__ slot_tok, float* __restrict__ slot_w) {
  const int i = blockIdx.x * 256 + threadIdx.x;
  if (i < 5120) { slot_tok[i] = 0; slot_w[i] = 0.f; }
  if (i < 8) { counts[i] = 0; pmean[i] = 0ull; }
}

__global__ void scan_k(const int* __restrict__ counts, int* __restrict__ cursors,
                       int* __restrict__ tiletab, const u64* __restrict__ pmean,
                       float* __restrict__ auxout) {
  if (threadIdx.x == 0) {
    int off = 0, nt = 0;
    double aux = 0.0;
    for (int e = 0; e < 8; ++e) {
      cursors[e] = off;
      const int c = counts[e];
      const int nte = (c + 127) >> 7;
      for (int i = 0; i < nte; ++i) {
        tiletab[1 + nt * 2] = e;
        tiletab[2 + nt * 2] = off + i * 128;
        ++nt;
      }
      off += nte * 128;
      const double pm = ((double)pmean[e] / 4294967296.0) / 2048.0;
      aux += ((double)c / 4096.0) * pm;
    }
    tiletab[0] = nt;
    *auxout = (float)(8.0 * aux);
  }
}

__global__ __launch_bounds__(256) void assign_k(const int* __restrict__ topi2,
                                                const float* __restrict__ topw2,
                                                int* __restrict__ cursors,
                                                int* __restrict__ slot_tok,
                                                float* __restrict__ slot_w,
                                                int* __restrict__ tok_slot) {
  const int tok = blockIdx.x * 256 + threadIdx.x;
#pragma unroll
  for (int j = 0; j < 2; ++j) {
    const int e = topi2[tok * 2 + j];
    const int s = atomicAdd(&cursors[e], 1);
    slot_tok[s] = tok;
    slot_w[s] = topw2[tok * 2 + j];
    tok_slot[tok * 2 + j] = s;
  }
}

__global__ __launch_bounds__(256) void final_k(float* __restrict__ out,
                                               const u16* __restrict__ routed,
                                               const int* __restrict__ tok_slot) {
  const int tok = blockIdx.x, t = threadIdx.x;
  const int s0 = tok_slot[tok * 2], s1 = tok_slot[tok * 2 + 1];
  u16x8 a = ((const u16x8*)(routed + (size_t)s0 * DD))[t];
  u16x8 b = ((const u16x8*)(routed + (size_t)s1 * DD))[t];
  float* o = out + (size_t)tok * DD + t * 8;
  float4 o0 = *(const float4*)o;
  float4 o1 = *(const float4*)(o + 4);
  o0.x += bf2f(a[0]) + bf2f(b[0]); o0.y += bf2f(a[1]) + bf2f(b[1]);
  o0.z += bf2f(a[2]) + bf2f(b[2]); o0.w += bf2f(a[3]) + bf2f(b[3]);
  o1.x += bf2f(a[4]) + bf2f(b[4]); o1.y += bf2f(a[5]) + bf2f(b[5]);
  o1.z += bf2f(a[6]) + bf2f(b[6]); o1.w += bf2f(a[7]) + bf2f(b[7]);
  *(float4*)o = o0;
  *(float4*)(o + 4) = o1;
}

extern "C" void kernel_launch(void* const* d_in, const int* in_sizes, int n_in,
                              void* d_out, int out_size, void* d_ws, size_t ws_size,
                              hipStream_t stream) {
  (void)in_sizes; (void)n_in; (void)out_size; (void)ws_size;
  const float* x    = (const float*)d_in[0];
  const float* rc   = (const float*)d_in[1];
  const float* rs   = (const float*)d_in[2];
  const float* anw  = (const float*)d_in[3];
  const float* fnw  = (const float*)d_in[4];
  const float* wq   = (const float*)d_in[5];
  const float* bq   = (const float*)d_in[6];
  const float* wk   = (const float*)d_in[7];
  const float* bk   = (const float*)d_in[8];
  const float* wv   = (const float*)d_in[9];
  const float* bv   = (const float*)d_in[10];
  const float* wo   = (const float*)d_in[11];
  const float* rw   = (const float*)d_in[12];
  const float* wg   = (const float*)d_in[13];
  const float* wu   = (const float*)d_in[14];
  const float* wd   = (const float*)d_in[15];
  const float* wsg  = (const float*)d_in[16];
  const float* wsu  = (const float*)d_in[17];
  const float* wsd  = (const float*)d_in[18];

  const size_t MB = (size_t)1 << 20;
  char* ws = (char*)d_ws;
  float* X2  = (float*)(ws + 0);          // 16 MiB
  u16*   HN  = (u16*)(ws + 16 * MB);      // 8 MiB
  char*  SM  = ws + 24 * MB;              // 1 MiB small
  char*  AR  = ws + 25 * MB;              // 123 MiB arena

  int*   CNT   = (int*)(SM);
  u64*   PM    = (u64*)(SM + 64);
  int*   CURS  = (int*)(SM + 256);
  int*   TILT  = (int*)(SM + 512);
  int*   TOPI  = (int*)(SM + 4096);
  float* TOPW  = (float*)(SM + 40960);
  int*   STOK  = (int*)(SM + 73728);
  float* SW    = (float*)(SM + 98304);
  int*   TSLOT = (int*)(SM + 131072);

  // P1 (qkv)
  u16*   H      = (u16*)(AR);             // 8 MiB
  u16*   WTQ    = (u16*)(AR + 8 * MB);    // 12 MiB
  float* PARTSQ = (float*)(AR + 20 * MB); // 48 MiB
  float* QKVF   = (float*)(AR + 68 * MB); // 24 MiB
  // P2 (attn)
  u16*   QR    = (u16*)(AR);              // 8 MiB
  u16*   KR    = (u16*)(AR + 8 * MB);     // 2 MiB
  u16*   VBb   = (u16*)(AR + 10 * MB);    // 2 MiB
  u16*   ATTNO = (u16*)(AR + 12 * MB);    // 8 MiB
  // P3 (wo)
  u16*   WTO    = (u16*)(AR + 20 * MB);   // 8 MiB
  float* PARTSW = (float*)(AR + 28 * MB); // 64 MiB
  // P5 (shared expert, gemm8)
  u16*   WTS    = (u16*)(AR);             // 44 MiB
  u16*   G      = (u16*)(AR + 44 * MB);   // 44 MiB
  u16*   PARTSD = (u16*)(AR + 88 * MB);   // 32 MiB (4 x 8 MiB bf16 parts)
  // P6 (routed experts)
  u16*   WTE    = (u16*)(AR);             // 64 MiB
  u16*   GEXP   = (u16*)(AR + 64 * MB);   // 20 MiB
  u16*   ROUTED = (u16*)(AR + 84 * MB);   // 20 MiB

  float* out  = (float*)d_out;
  float* NK   = out + 4194304;
  float* NV   = out + 2 * 4194304;
  float* AUXO = out + 3 * 4194304;

  const dim3 b256(256);
  const dim3 b512(512);

  // P1: attn rmsnorm + QKV projection (gemm8 split-K x2)
  rmsnorm_k<<<TT, b256, 0, stream>>>(x, anw, H);
  transp_k<<<dim3(32, 32, 1), b256, 0, stream>>>(wq, WTQ, 2048, 2048);
  transp_k<<<dim3(8, 32, 1), b256, 0, stream>>>(wk, WTQ + (size_t)2048 * 2048, 2048, 512);
  transp_k<<<dim3(8, 32, 1), b256, 0, stream>>>(wv, WTQ + (size_t)2560 * 2048, 2048, 512);
  gemm8<11, true><<<dim3(12, 8, 2), b512, 0, stream>>>(H, WTQ, PARTSQ, nullptr, TT, 3072, 2048, 1024);
  red_k<2, false><<<6144, b256, 0, stream>>>(QKVF, nullptr, PARTSQ, 1572864);
  // P2: rope + attention
  rope_k<<<dim3(1024, 2), b256, 0, stream>>>(QKVF, rc, rs, bq, bk, bv, QR, KR, VBb, NK, NV);
  attn_k<<<dim3(16, 16, 2), b256, 0, stream>>>(QR, KR, VBb, ATTNO);
  // P3: x2 = x + attno @ wo (gemm8 split-K x4, f32 parts)
  transp_k<<<dim3(32, 32, 1), b256, 0, stream>>>(wo, WTO, 2048, 2048);
  gemm8<11, true><<<dim3(8, 8, 4), b512, 0, stream>>>(ATTNO, WTO, PARTSW, nullptr, TT, 2048, 2048, 512);
  red_k<4, true><<<4096, b256, 0, stream>>>(X2, x, PARTSW, 1048576);
  // P4: ffn rmsnorm + routing
  rmsnorm_k<<<TT, b256, 0, stream>>>(X2, fnw, HN);
  zero_k<<<20, b256, 0, stream>>>(CNT, PM, STOK, SW);
  router_k<<<512, b256, 0, stream>>>(X2, fnw, rw, TOPI, TOPW, CNT, PM);
  scan_k<<<1, 64, 0, stream>>>(CNT, CURS, TILT, PM, AUXO);
  assign_k<<<8, b256, 0, stream>>>(TOPI, TOPW, CURS, STOK, SW, TSLOT);
  // P5: shared expert via gemm8
  transp_k<<<dim3(172, 32, 1), b256, 0, stream>>>(wsg, WTS, 2048, FSH);
  gemm8<2, false><<<dim3(43, 8, 1), b512, 0, stream>>>(HN, WTS, G, nullptr, TT, FSH, 2048, 2048);
  transp_k<<<dim3(172, 32, 1), b256, 0, stream>>>(wsu, WTS, 2048, FSH);
  gemm8<3, false><<<dim3(43, 8, 1), b512, 0, stream>>>(HN, WTS, G, G, TT, FSH, 2048, 2048);
  transp_k<<<dim3(32, 172, 1), b256, 0, stream>>>(wsd, WTS, FSH, 2048);
  gemm8<10, true><<<dim3(8, 8, 4), b512, 0, stream>>>(G, WTS, PARTSD, nullptr, TT, 2048, FSH, 2816);
  redbf_k<<<2048, b256, 0, stream>>>(out, X2, PARTSD);
  // P6: routed experts (128^2, padded tile table)
  transp_k<<<dim3(32, 32, 8), b256, 0, stream>>>(wg, WTE, 2048, 2048);
  gemm2<2, true, true, false><<<dim3(16, 40, 1), b256, 0, stream>>>(
      HN, WTE, GEXP, nullptr, nullptr, STOK, TILT, 5120, 2048, 2048, 0);
  transp_k<<<dim3(32, 32, 8), b256, 0, stream>>>(wu, WTE, 2048, 2048);
  gemm2<3, true, true, false><<<dim3(16, 40, 1), b256, 0, stream>>>(
      HN, WTE, GEXP, GEXP, nullptr, STOK, TILT, 5120, 2048, 2048, 0);
  transp_k<<<dim3(32, 32, 8), b256, 0, stream>>>(wd, WTE, 2048, 2048);
  gemm2<4, true, false, false><<<dim3(16, 40, 1), b256, 0, stream>>>(
      GEXP, WTE, ROUTED, nullptr, SW, STOK, TILT, 5120, 2048, 2048, 0);
  // P7: out += routed
  final_k<<<TT, b256, 0, stream>>>(out, ROUTED, TSLOT);
}

// Round 5
// 936.213 us; speedup vs baseline: 1.5639x; 1.0584x over previous
//
#include <hip/hip_runtime.h>

typedef unsigned short u16;
typedef unsigned int u32;
typedef unsigned long long u64;
typedef __attribute__((ext_vector_type(4))) unsigned short u16x4;
typedef __attribute__((ext_vector_type(8))) unsigned short u16x8;
typedef __attribute__((ext_vector_type(4))) float f32x4;
typedef __attribute__((ext_vector_type(8))) __bf16 bf16x8;

#define DD 2048
#define TT 2048
#define FSH 11008

__device__ __forceinline__ float bf2f(u16 u) {
  union { u32 i; float f; } v; v.i = ((u32)u) << 16; return v.f;
}
__device__ __forceinline__ u16 f2bf(float f) {
  union { float f; u32 i; } v; v.f = f;
  u32 r = v.i + 0x7fffu + ((v.i >> 16) & 1u);
  return (u16)(r >> 16);
}
__device__ __forceinline__ void gld16(const void* g, void* l) {
  __builtin_amdgcn_global_load_lds((const __attribute__((address_space(1))) void*)g,
                                   (__attribute__((address_space(3))) void*)l, 16, 0, 0);
}

#define MFMA16(d, a, b) d = __builtin_amdgcn_mfma_f32_16x16x32_bf16(a, b, d, 0, 0, 0)

// ---------------- RMSNorm: f32 row -> bf16 row ----------------
__global__ __launch_bounds__(256) void rmsnorm_k(const float* __restrict__ x,
                                                 const float* __restrict__ w,
                                                 u16* __restrict__ out) {
  const int t = threadIdx.x;
  const float* xr = x + (size_t)blockIdx.x * DD;
  float4 a = *(const float4*)(xr + t * 8);
  float4 b = *(const float4*)(xr + t * 8 + 4);
  float ss = a.x*a.x + a.y*a.y + a.z*a.z + a.w*a.w
           + b.x*b.x + b.y*b.y + b.z*b.z + b.w*b.w;
#pragma unroll
  for (int m = 1; m < 64; m <<= 1) ss += __shfl_xor(ss, m);
  __shared__ float red[4];
  if ((t & 63) == 0) red[t >> 6] = ss;
  __syncthreads();
  float sc = rsqrtf((red[0] + red[1] + red[2] + red[3]) * (1.f / DD) + 1e-6f);
  float4 wa = *(const float4*)(w + t * 8);
  float4 wb = *(const float4*)(w + t * 8 + 4);
  u16x8 o;
  o[0] = f2bf(a.x * sc * wa.x); o[1] = f2bf(a.y * sc * wa.y);
  o[2] = f2bf(a.z * sc * wa.z); o[3] = f2bf(a.w * sc * wa.w);
  o[4] = f2bf(b.x * sc * wb.x); o[5] = f2bf(b.y * sc * wb.y);
  o[6] = f2bf(b.z * sc * wb.z); o[7] = f2bf(b.w * sc * wb.w);
  *(u16x8*)(out + (size_t)blockIdx.x * DD + t * 8) = o;
}

// ---------------- Transpose+convert v2: W[R][C] f32 -> Wt[C][R] bf16 ----------------
__global__ __launch_bounds__(256) void transp_k(const float* __restrict__ W,
                                                u16* __restrict__ Wt, int R, int C) {
  __shared__ u16 tile[64 * 80];
  const size_t msz = (size_t)R * C;
  const float* Wm = W + msz * blockIdx.z;
  u16* Wtm = Wt + msz * blockIdx.z;
  const int t = threadIdx.x;
  const int n0 = blockIdx.x * 64, k0 = blockIdx.y * 64;
#pragma unroll
  for (int p = 0; p < 4; ++p) {
    const int kk = (t >> 4) + p * 16;
    const int nn = (t & 15) * 4;
    float4 v = *(const float4*)(Wm + (size_t)(k0 + kk) * C + n0 + nn);
    tile[(nn + 0) * 80 + kk] = f2bf(v.x);
    tile[(nn + 1) * 80 + kk] = f2bf(v.y);
    tile[(nn + 2) * 80 + kk] = f2bf(v.z);
    tile[(nn + 3) * 80 + kk] = f2bf(v.w);
  }
  __syncthreads();
#pragma unroll
  for (int p = 0; p < 2; ++p) {
    const int n = (t >> 3) + p * 32;
    const int c = t & 7;
    u16x8 v = *(const u16x8*)(tile + n * 80 + c * 8);
    *(u16x8*)(Wtm + (size_t)(n0 + n) * R + k0 + c * 8) = v;
  }
}

// ---------------- GEMM2 (128^2 m97-style) ----------------
template <int EPI, bool EXPERT, bool INDIR, bool SPLITK>
__global__ __launch_bounds__(256) void gemm2(
    const u16* __restrict__ A, const u16* __restrict__ Bt, void* __restrict__ Cp,
    const void* __restrict__ aux, const float* __restrict__ slotw,
    const int* __restrict__ slot_tok, const int* __restrict__ tiletab,
    int M, int N, int K, int Kc) {
  __shared__ u16 lA[128 * 32];
  __shared__ u16 lB[128 * 32];
  const int t = threadIdx.x, w = t >> 6, l = t & 63;
  const int n0 = blockIdx.x * 128;
  int m0;
  if constexpr (EXPERT) {
    const int ntil = tiletab[0];
    if ((int)blockIdx.y >= ntil) return;
    const int e = tiletab[1 + blockIdx.y * 2];
    m0 = tiletab[2 + blockIdx.y * 2];
    Bt += (size_t)e * N * K;
  } else {
    m0 = blockIdx.y * 128;
  }
  int kbase = 0, KC = K;
  if constexpr (SPLITK) { kbase = blockIdx.z * Kc; KC = Kc; }
  const int srow = w * 16 + (l >> 2);
  const int scol = (l & 3) * 8;
  const int r0 = m0 + srow, r1 = m0 + srow + 64;
  const u16 *ag0, *ag1;
  if constexpr (INDIR) {
    ag0 = A + (size_t)slot_tok[r0] * K + scol + kbase;
    ag1 = A + (size_t)slot_tok[r1] * K + scol + kbase;
  } else {
    ag0 = A + (size_t)r0 * K + scol + kbase;
    ag1 = A + (size_t)r1 * K + scol + kbase;
  }
  const u16* bg0 = Bt + (size_t)(n0 + srow) * K + scol + kbase;
  const u16* bg1 = Bt + (size_t)(n0 + srow + 64) * K + scol + kbase;
  u16* la = lA + w * 512;
  u16* lb = lB + w * 512;
  const int l15 = l & 15, l4 = l >> 4;
  const int wm = w >> 1, wn = w & 1;
  const int fa = (wm * 64 + l15) * 32 + l4 * 8;
  const int fb = (wn * 64 + l15) * 32 + l4 * 8;
  f32x4 acc[4][4] = {};
  for (int ko = 0; ko < KC; ko += 32) {
    __syncthreads();
    gld16(ag0 + ko, la);
    gld16(ag1 + ko, la + 2048);
    gld16(bg0 + ko, lb);
    gld16(bg1 + ko, lb + 2048);
    asm volatile("s_waitcnt vmcnt(0)" ::: "memory");
    __syncthreads();
    bf16x8 af[4], bf[4];
#pragma unroll
    for (int i = 0; i < 4; ++i) {
      af[i] = *(const bf16x8*)(lA + fa + i * 512);
      bf[i] = *(const bf16x8*)(lB + fb + i * 512);
    }
#pragma unroll
    for (int mi = 0; mi < 4; ++mi)
#pragma unroll
      for (int ni = 0; ni < 4; ++ni)
        MFMA16(acc[mi][ni], af[mi], bf[ni]);
  }
  float* Cf = (float*)Cp;
  if constexpr (SPLITK) Cf += (size_t)blockIdx.z * M * N;
#pragma unroll
  for (int mi = 0; mi < 4; ++mi) {
#pragma unroll
    for (int r = 0; r < 4; ++r) {
      const int row = m0 + wm * 64 + mi * 16 + l4 * 4 + r;
#pragma unroll
      for (int ni = 0; ni < 4; ++ni) {
        const int col = n0 + wn * 64 + ni * 16 + l15;
        const size_t idx = (size_t)row * N + col;
        const float v = acc[mi][ni][r];
        if constexpr (EPI == 0) Cf[idx] = v;
        else if constexpr (EPI == 2) ((u16*)Cp)[idx] = f2bf(v);
        else if constexpr (EPI == 3) {
          const float g = bf2f(((const u16*)aux)[idx]);
          ((u16*)Cp)[idx] = f2bf(v * g / (1.f + __expf(-g)));
        } else {
          ((u16*)Cp)[idx] = f2bf(slotw[row] * v);
        }
      }
    }
  }
}

// ---------------- GEMM8: 256^2, 8-wave, 8-phase, n-major XCD swizzle ----------------
// EPI: 2=bf16 store, 3=bf16 silu(aux)*acc, 10=bf16 split-K parts, 11=f32 split-K parts
template <int EPI, bool SPLITK>
__global__ __launch_bounds__(512, 2) void gemm8(
    const u16* __restrict__ A, const u16* __restrict__ Bt, void* __restrict__ Cp,
    const u16* __restrict__ aux, int M, int N, int K, int Kc) {
  __shared__ char lds[131072];
  const int t = threadIdx.x, w = t >> 6, l = t & 63;
  const int gx = gridDim.x, gy = gridDim.y;
  const int nwg = gx * gy;            // % 8 == 0
  int wg = blockIdx.y * gx + blockIdx.x;
  wg = (wg & 7) * (nwg >> 3) + (wg >> 3);   // XCD swizzle (bijective)
  const int m0 = (wg % gy) * 256;     // n-major: XCD chunk spans all m, few n
  const int n0 = (wg / gy) * 256;
  int kbase = 0, KC = K;
  if constexpr (SPLITK) {
    kbase = blockIdx.z * Kc;
    const int rem = K - kbase;
    KC = rem < Kc ? rem : Kc;
  }
  const int ktiles = KC >> 6;
  const int wm = w >> 2, wn = w & 3;
  const int l15 = l & 15, l4 = l >> 4;
  const int sro = l >> 3, sc = l & 7;

  const u16* sgp[2][2][2];
  u32 sdo[2][2][2];
#pragma unroll
  for (int isB = 0; isB < 2; ++isB)
#pragma unroll
    for (int h = 0; h < 2; ++h)
#pragma unroll
      for (int i = 0; i < 2; ++i) {
        const int q = i * 8 + w;
        const int r0 = isB ? (((q >> 2) << 6) + h * 32 + (q & 3) * 8)
                           : (((q & 8) << 4) + h * 64 + (q & 7) * 8);
        const int r = r0 + sro;
        const int cl = sc ^ (r & 7);
        const u16* base = isB ? (Bt + (size_t)(n0 + r) * K) : (A + (size_t)(m0 + r) * K);
        sgp[isB][h][i] = base + kbase + cl * 8;
        sdo[isB][h][i] = (u32)(isB * 32768 + r0 * 128);
      }
  auto stage = [&](int b, int isB, int h, int kt) {
    const int kk = kt < ktiles ? kt : ktiles - 1;
#pragma unroll
    for (int i = 0; i < 2; ++i)
      gld16(sgp[isB][h][i] + kk * 64, lds + b * 65536 + sdo[isB][h][i]);
  };
  auto ldA = [&](int b, int mi, int ks) {
    const int row = wm * 128 + mi * 16 + l15;
    const int ch = (ks * 4 + l4) ^ (row & 7);
    return *(const bf16x8*)(lds + b * 65536 + row * 128 + ch * 16);
  };
  auto ldB = [&](int b, int ni, int ks) {
    const int row = wn * 64 + ni * 16 + l15;
    const int ch = (ks * 4 + l4) ^ (row & 7);
    return *(const bf16x8*)(lds + b * 65536 + 32768 + row * 128 + ch * 16);
  };

  f32x4 acc[8][4] = {};
  bf16x8 aR[4][2], b0[2][2], b1[2][2];

  stage(0, 0, 0, 0); stage(0, 1, 0, 0); stage(0, 1, 1, 0); stage(0, 0, 1, 0);
  stage(1, 0, 0, 1); stage(1, 1, 1, 1); stage(1, 0, 1, 1);
  asm volatile("s_waitcnt vmcnt(6)" ::: "memory");
  __builtin_amdgcn_s_barrier();

  for (int kt = 0; kt < ktiles; kt += 2) {
#pragma unroll
    for (int mi = 0; mi < 4; ++mi) { aR[mi][0] = ldA(0, mi, 0); aR[mi][1] = ldA(0, mi, 1); }
#pragma unroll
    for (int ni = 0; ni < 2; ++ni) { b0[ni][0] = ldB(0, ni, 0); b0[ni][1] = ldB(0, ni, 1); }
    stage(1, 1, 0, kt + 1);
    __builtin_amdgcn_s_barrier();
    asm volatile("s_waitcnt lgkmcnt(0)" ::: "memory");
    __builtin_amdgcn_s_setprio(1);
#pragma unroll
    for (int mi = 0; mi < 4; ++mi)
#pragma unroll
      for (int ni = 0; ni < 2; ++ni) {
        MFMA16(acc[mi][ni], aR[mi][0], b0[ni][0]);
        MFMA16(acc[mi][ni], aR[mi][1], b0[ni][1]);
      }
    __builtin_amdgcn_s_setprio(0);
    __builtin_amdgcn_s_barrier();
#pragma unroll
    for (int ni = 0; ni < 2; ++ni) { b1[ni][0] = ldB(0, ni + 2, 0); b1[ni][1] = ldB(0, ni + 2, 1); }
    stage(0, 0, 0, kt + 2);
    __builtin_amdgcn_s_barrier();
    asm volatile("s_waitcnt lgkmcnt(0)" ::: "memory");
    __builtin_amdgcn_s_setprio(1);
#pragma unroll
    for (int mi = 0; mi < 4; ++mi)
#pragma unroll
      for (int ni = 0; ni < 2; ++ni) {
        MFMA16(acc[mi][ni + 2], aR[mi][0], b1[ni][0]);
        MFMA16(acc[mi][ni + 2], aR[mi][1], b1[ni][1]);
      }
    __builtin_amdgcn_s_setprio(0);
    __builtin_amdgcn_s_barrier();
#pragma unroll
    for (int mi = 0; mi < 4; ++mi) { aR[mi][0] = ldA(0, mi + 4, 0); aR[mi][1] = ldA(0, mi + 4, 1); }
    stage(0, 1, 1, kt + 2);
    __builtin_amdgcn_s_barrier();
    asm volatile("s_waitcnt lgkmcnt(0)" ::: "memory");
    __builtin_amdgcn_s_setprio(1);
#pragma unroll
    for (int mi = 0; mi < 4; ++mi)
#pragma unroll
      for (int ni = 0; ni < 2; ++ni) {
        MFMA16(acc[mi + 4][ni + 2], aR[mi][0], b1[ni][0]);
        MFMA16(acc[mi + 4][ni + 2], aR[mi][1], b1[ni][1]);
      }
    __builtin_amdgcn_s_setprio(0);
    __builtin_amdgcn_s_barrier();
    stage(0, 0, 1, kt + 2);
    __builtin_amdgcn_s_barrier();
    __builtin_amdgcn_s_setprio(1);
#pragma unroll
    for (int mi = 0; mi < 4; ++mi)
#pragma unroll
      for (int ni = 0; ni < 2; ++ni) {
        MFMA16(acc[mi + 4][ni], aR[mi][0], b0[ni][0]);
        MFMA16(acc[mi + 4][ni], aR[mi][1], b0[ni][1]);
      }
    __builtin_amdgcn_s_setprio(0);
    asm volatile("s_waitcnt vmcnt(6)" ::: "memory");
    __builtin_amdgcn_s_barrier();
#pragma unroll
    for (int mi = 0; mi < 4; ++mi) { aR[mi][0] = ldA(1, mi, 0); aR[mi][1] = ldA(1, mi, 1); }
#pragma unroll
    for (int ni = 0; ni < 2; ++ni) { b0[ni][0] = ldB(1, ni, 0); b0[ni][1] = ldB(1, ni, 1); }
    stage(0, 1, 0, kt + 2);
    __builtin_amdgcn_s_barrier();
    asm volatile("s_waitcnt lgkmcnt(0)" ::: "memory");
    __builtin_amdgcn_s_setprio(1);
#pragma unroll
    for (int mi = 0; mi < 4; ++mi)
#pragma unroll
      for (int ni = 0; ni < 2; ++ni) {
        MFMA16(acc[mi][ni], aR[mi][0], b0[ni][0]);
        MFMA16(acc[mi][ni], aR[mi][1], b0[ni][1]);
      }
    __builtin_amdgcn_s_setprio(0);
    __builtin_amdgcn_s_barrier();
#pragma unroll
    for (int ni = 0; ni < 2; ++ni) { b1[ni][0] = ldB(1, ni + 2, 0); b1[ni][1] = ldB(1, ni + 2, 1); }
    stage(1, 0, 0, kt + 3);
    __builtin_amdgcn_s_barrier();
    asm volatile("s_waitcnt lgkmcnt(0)" ::: "memory");
    __builtin_amdgcn_s_setprio(1);
#pragma unroll
    for (int mi = 0; mi < 4; ++mi)
#pragma unroll
      for (int ni = 0; ni < 2; ++ni) {
        MFMA16(acc[mi][ni + 2], aR[mi][0], b1[ni][0]);
        MFMA16(acc[mi][ni + 2], aR[mi][1], b1[ni][1]);
      }
    __builtin_amdgcn_s_setprio(0);
    __builtin_amdgcn_s_barrier();
#pragma unroll
    for (int mi = 0; mi < 4; ++mi) { aR[mi][0] = ldA(1, mi + 4, 0); aR[mi][1] = ldA(1, mi + 4, 1); }
    stage(1, 1, 1, kt + 3);
    __builtin_amdgcn_s_barrier();
    asm volatile("s_waitcnt lgkmcnt(0)" ::: "memory");
    __builtin_amdgcn_s_setprio(1);
#pragma unroll
    for (int mi = 0; mi < 4; ++mi)
#pragma unroll
      for (int ni = 0; ni < 2; ++ni) {
        MFMA16(acc[mi + 4][ni + 2], aR[mi][0], b1[ni][0]);
        MFMA16(acc[mi + 4][ni + 2], aR[mi][1], b1[ni][1]);
      }
    __builtin_amdgcn_s_setprio(0);
    __builtin_amdgcn_s_barrier();
    stage(1, 0, 1, kt + 3);
    __builtin_amdgcn_s_barrier();
    __builtin_amdgcn_s_setprio(1);
#pragma unroll
    for (int mi = 0; mi < 4; ++mi)
#pragma unroll
      for (int ni = 0; ni < 2; ++ni) {
        MFMA16(acc[mi + 4][ni], aR[mi][0], b0[ni][0]);
        MFMA16(acc[mi + 4][ni], aR[mi][1], b0[ni][1]);
      }
    __builtin_amdgcn_s_setprio(0);
    asm volatile("s_waitcnt vmcnt(6)" ::: "memory");
    __builtin_amdgcn_s_barrier();
  }

  u16* C16 = (u16*)Cp;
  float* Cf = (float*)Cp;
  if constexpr (EPI == 10) C16 += (size_t)blockIdx.z * ((size_t)M * N);
  if constexpr (EPI == 11) Cf += (size_t)blockIdx.z * ((size_t)M * N);
#pragma unroll
  for (int mi = 0; mi < 8; ++mi)
#pragma unroll
    for (int rr = 0; rr < 4; ++rr) {
      const int row = m0 + wm * 128 + mi * 16 + l4 * 4 + rr;
#pragma unroll
      for (int ni = 0; ni < 4; ++ni) {
        const int col = n0 + wn * 64 + ni * 16 + l15;
        const size_t idx = (size_t)row * N + col;
        const float v = acc[mi][ni][rr];
        if constexpr (EPI == 11) {
          Cf[idx] = v;
        } else if constexpr (EPI == 3) {
          const float g = bf2f(aux[idx]);
          C16[idx] = f2bf(v * g / (1.f + __expf(-g)));
        } else {
          C16[idx] = f2bf(v);
        }
      }
    }
}

// ---------------- GEMM_GU: fused gate+up, 256x128-per-matrix, 8-phase mirror of gemm8 ----
// Writes act = silu(g)*u (bf16). A [M][K], Btg/Btu slab-local [ncols][K].
__global__ __launch_bounds__(512, 2) void gemm_gu(
    const u16* __restrict__ A, const u16* __restrict__ Btg, const u16* __restrict__ Btu,
    u16* __restrict__ act, int K, int LDC, int cg0) {
  __shared__ char lds[131072];  // per buf: A 32K @0 | Bg 16K @32768 | Bu 16K @49152
  const int t = threadIdx.x, w = t >> 6, l = t & 63;
  const int gx = gridDim.x;            // n-tiles (128 wide)
  const int nwg = gx * 8;              // % 8 == 0
  int wg = blockIdx.y * gx + blockIdx.x;
  wg = (wg & 7) * (nwg >> 3) + (wg >> 3);
  const int m0 = (wg & 7) * 256;       // n-major: wg%8 = m-tile
  const int nt = wg >> 3;
  const int ktiles = K >> 6;
  const int wm = w >> 2, wn = w & 3;
  const int l15 = l & 15, l4 = l >> 4;
  const int sro = l >> 3, sc = l & 7;

  const u16* sga[2][2]; u32 sda[2][2];
#pragma unroll
  for (int h = 0; h < 2; ++h)
#pragma unroll
    for (int i = 0; i < 2; ++i) {
      const int q = i * 8 + w;
      const int r0 = ((q & 8) << 4) + h * 64 + (q & 7) * 8;
      const int r = r0 + sro;
      const int cl = sc ^ (r & 7);
      sga[h][i] = A + (size_t)(m0 + r) * K + cl * 8;
      sda[h][i] = (u32)(r0 * 128);
    }
  const u16* sgb[2][2]; u32 sdb[2][2];
#pragma unroll
  for (int mat = 0; mat < 2; ++mat)
#pragma unroll
    for (int i = 0; i < 2; ++i) {
      const int q = i * 8 + w;
      const int r0 = q * 8;
      const int r = r0 + sro;
      const int cl = sc ^ (r & 7);
      const u16* B = mat ? Btu : Btg;
      sgb[mat][i] = B + (size_t)(nt * 128 + r) * K + cl * 8;
      sdb[mat][i] = (u32)(32768 + mat * 16384 + r0 * 128);
    }
  auto stgA = [&](int b, int h, int kt) {
    const int kk = kt < ktiles ? kt : ktiles - 1;
#pragma unroll
    for (int i = 0; i < 2; ++i) gld16(sga[h][i] + kk * 64, lds + b * 65536 + sda[h][i]);
  };
  auto stgB = [&](int b, int mat, int kt) {
    const int kk = kt < ktiles ? kt : ktiles - 1;
#pragma unroll
    for (int i = 0; i < 2; ++i) gld16(sgb[mat][i] + kk * 64, lds + b * 65536 + sdb[mat][i]);
  };
  auto ldA = [&](int b, int mi, int ks) {
    const int row = wm * 128 + mi * 16 + l15;
    const int ch = (ks * 4 + l4) ^ (row & 7);
    return *(const bf16x8*)(lds + b * 65536 + row * 128 + ch * 16);
  };
  auto ldB = [&](int b, int mat, int ni, int ks) {
    const int row = wn * 32 + ni * 16 + l15;
    const int ch = (ks * 4 + l4) ^ (row & 7);
    return *(const bf16x8*)(lds + b * 65536 + 32768 + mat * 16384 + row * 128 + ch * 16);
  };

  f32x4 accg[8][2] = {}, accu[8][2] = {};
  bf16x8 aR[4][2], bg[2][2], bu[2][2];

  // prologue: tile0 {A0,Bg,Bu,A1}(buf0) + tile1 {A0,Bu,A1}(buf1); Bg(t1) staged at P1
  stgA(0, 0, 0); stgB(0, 0, 0); stgB(0, 1, 0); stgA(0, 1, 0);
  stgA(1, 0, 1); stgB(1, 1, 1); stgA(1, 1, 1);
  asm volatile("s_waitcnt vmcnt(6)" ::: "memory");
  __builtin_amdgcn_s_barrier();

  for (int kt = 0; kt < ktiles; kt += 2) {
    // P1: aR=mh0(b0), bg(b0); stage Bg(t+1)->b1; MFMA accg mh0
#pragma unroll
    for (int mi = 0; mi < 4; ++mi) { aR[mi][0] = ldA(0, mi, 0); aR[mi][1] = ldA(0, mi, 1); }
#pragma unroll
    for (int ni = 0; ni < 2; ++ni) { bg[ni][0] = ldB(0, 0, ni, 0); bg[ni][1] = ldB(0, 0, ni, 1); }
    stgB(1, 0, kt + 1);
    __builtin_amdgcn_s_barrier();
    asm volatile("s_waitcnt lgkmcnt(0)" ::: "memory");
    __builtin_amdgcn_s_setprio(1);
#pragma unroll
    for (int mi = 0; mi < 4; ++mi)
#pragma unroll
      for (int ni = 0; ni < 2; ++ni) {
        MFMA16(accg[mi][ni], aR[mi][0], bg[ni][0]);
        MFMA16(accg[mi][ni], aR[mi][1], bg[ni][1]);
      }
    __builtin_amdgcn_s_setprio(0);
    __builtin_amdgcn_s_barrier();
    // P2: bu(b0); stage A0(t+2)->b0; MFMA accu mh0
#pragma unroll
    for (int ni = 0; ni < 2; ++ni) { bu[ni][0] = ldB(0, 1, ni, 0); bu[ni][1] = ldB(0, 1, ni, 1); }
    stgA(0, 0, kt + 2);
    __builtin_amdgcn_s_barrier();
    asm volatile("s_waitcnt lgkmcnt(0)" ::: "memory");
    __builtin_amdgcn_s_setprio(1);
#pragma unroll
    for (int mi = 0; mi < 4; ++mi)
#pragma unroll
      for (int ni = 0; ni < 2; ++ni) {
        MFMA16(accu[mi][ni], aR[mi][0], bu[ni][0]);
        MFMA16(accu[mi][ni], aR[mi][1], bu[ni][1]);
      }
    __builtin_amdgcn_s_setprio(0);
    __builtin_amdgcn_s_barrier();
    // P3: aR=mh1(b0); stage Bu(t+2)->b0; MFMA accu mh1
#pragma unroll
    for (int mi = 0; mi < 4; ++mi) { aR[mi][0] = ldA(0, mi + 4, 0); aR[mi][1] = ldA(0, mi + 4, 1); }
    stgB(0, 1, kt + 2);
    __builtin_amdgcn_s_barrier();
    asm volatile("s_waitcnt lgkmcnt(0)" ::: "memory");
    __builtin_amdgcn_s_setprio(1);
#pragma unroll
    for (int mi = 0; mi < 4; ++mi)
#pragma unroll
      for (int ni = 0; ni < 2; ++ni) {
        MFMA16(accu[mi + 4][ni], aR[mi][0], bu[ni][0]);
        MFMA16(accu[mi + 4][ni], aR[mi][1], bu[ni][1]);
      }
    __builtin_amdgcn_s_setprio(0);
    __builtin_amdgcn_s_barrier();
    // P4: stage A1(t+2)->b0; MFMA accg mh1; vmcnt(6); barrier
    stgA(0, 1, kt + 2);
    __builtin_amdgcn_s_barrier();
    __builtin_amdgcn_s_setprio(1);
#pragma unroll
    for (int mi = 0; mi < 4; ++mi)
#pragma unroll
      for (int ni = 0; ni < 2; ++ni) {
        MFMA16(accg[mi + 4][ni], aR[mi][0], bg[ni][0]);
        MFMA16(accg[mi + 4][ni], aR[mi][1], bg[ni][1]);
      }
    __builtin_amdgcn_s_setprio(0);
    asm volatile("s_waitcnt vmcnt(6)" ::: "memory");
    __builtin_amdgcn_s_barrier();
    // P5: aR=mh0(b1), bg(b1); stage Bg(t+2)->b0; MFMA accg mh0
#pragma unroll
    for (int mi = 0; mi < 4; ++mi) { aR[mi][0] = ldA(1, mi, 0); aR[mi][1] = ldA(1, mi, 1); }
#pragma unroll
    for (int ni = 0; ni < 2; ++ni) { bg[ni][0] = ldB(1, 0, ni, 0); bg[ni][1] = ldB(1, 0, ni, 1); }
    stgB(0, 0, kt + 2);
    __builtin_amdgcn_s_barrier();
    asm volatile("s_waitcnt lgkmcnt(0)" ::: "memory");
    __builtin_amdgcn_s_setprio(1);
#pragma unroll
    for (int mi = 0; mi < 4; ++mi)
#pragma unroll
      for (int ni = 0; ni < 2; ++ni) {
        MFMA16(accg[mi][ni], aR[mi][0], bg[ni][0]);
        MFMA16(accg[mi][ni], aR[mi][1], bg[ni][1]);
      }
    __builtin_amdgcn_s_setprio(0);
    __builtin_amdgcn_s_barrier();
    // P6: bu(b1); stage A0(t+3)->b1; MFMA accu mh0
#pragma unroll
    for (int ni = 0; ni < 2; ++ni) { bu[ni][0] = ldB(1, 1, ni, 0); bu[ni][1] = ldB(1, 1, ni, 1); }
    stgA(1, 0, kt + 3);
    __builtin_amdgcn_s_barrier();
    asm volatile("s_waitcnt lgkmcnt(0)" ::: "memory");
    __builtin_amdgcn_s_setprio(1);
#pragma unroll
    for (int mi = 0; mi < 4; ++mi)
#pragma unroll
      for (int ni = 0; ni < 2; ++ni) {
        MFMA16(accu[mi][ni], aR[mi][0], bu[ni][0]);
        MFMA16(accu[mi][ni], aR[mi][1], bu[ni][1]);
      }
    __builtin_amdgcn_s_setprio(0);
    __builtin_amdgcn_s_barrier();
    // P7: aR=mh1(b1); stage Bu(t+3)->b1; MFMA accu mh1
#pragma unroll
    for (int mi = 0; mi < 4; ++mi) { aR[mi][0] = ldA(1, mi + 4, 0); aR[mi][1] = ldA(1, mi + 4, 1); }
    stgB(1, 1, kt + 3);
    __builtin_amdgcn_s_barrier();
    asm volatile("s_waitcnt lgkmcnt(0)" ::: "memory");
    __builtin_amdgcn_s_setprio(1);
#pragma unroll
    for (int mi = 0; mi < 4; ++mi)
#pragma unroll
      for (int ni = 0; ni < 2; ++ni) {
        MFMA16(accu[mi + 4][ni], aR[mi][0], bu[ni][0]);
        MFMA16(accu[mi + 4][ni], aR[mi][1], bu[ni][1]);
      }
    __builtin_amdgcn_s_setprio(0);
    __builtin_amdgcn_s_barrier();
    // P8: stage A1(t+3)->b1; MFMA accg mh1; vmcnt(6); barrier
    stgA(1, 1, kt + 3);
    __builtin_amdgcn_s_barrier();
    __builtin_amdgcn_s_setprio(1);
#pragma unroll
    for (int mi = 0; mi < 4; ++mi)
#pragma unroll
      for (int ni = 0; ni < 2; ++ni) {
        MFMA16(accg[mi + 4][ni], aR[mi][0], bg[ni][0]);
        MFMA16(accg[mi + 4][ni], aR[mi][1], bg[ni][1]);
      }
    __builtin_amdgcn_s_setprio(0);
    asm volatile("s_waitcnt vmcnt(6)" ::: "memory");
    __builtin_amdgcn_s_barrier();
  }

#pragma unroll
  for (int mi = 0; mi < 8; ++mi)
#pragma unroll
    for (int rr = 0; rr < 4; ++rr) {
      const int row = m0 + wm * 128 + mi * 16 + l4 * 4 + rr;
#pragma unroll
      for (int ni = 0; ni < 2; ++ni) {
        const int col = cg0 + nt * 128 + wn * 32 + ni * 16 + l15;
        const float g = accg[mi][ni][rr];
        const float u = accu[mi][ni][rr];
        act[(size_t)row * LDC + col] = f2bf(u * g / (1.f + __expf(-g)));
      }
    }
}

// ---------------- split-K reduce (f32 parts) ----------------
template <int NP, bool ADDB>
__global__ __launch_bounds__(256) void red_k(float* __restrict__ dst,
                                             const float* __restrict__ base,
                                             const float* __restrict__ parts,
                                             int mn4) {
  const int i = blockIdx.x * 256 + threadIdx.x;
  float4 s;
  if constexpr (ADDB) s = ((const float4*)base)[i];
  else { s.x = s.y = s.z = s.w = 0.f; }
#pragma unroll
  for (int p = 0; p < NP; ++p) {
    const float4 v = ((const float4*)parts)[(size_t)p * mn4 + i];
    s.x += v.x; s.y += v.y; s.z += v.z; s.w += v.w;
  }
  ((float4*)dst)[i] = s;
}

// ---------------- split-K reduce (bf16 parts x4): dst = base + sum ----------------
__global__ __launch_bounds__(256) void redbf_k(float* __restrict__ dst,
                                               const float* __restrict__ base,
                                               const u16* __restrict__ parts) {
  const int i = blockIdx.x * 256 + threadIdx.x;
  float s[8];
  const float* bp = base + (size_t)i * 8;
#pragma unroll
  for (int j = 0; j < 8; ++j) s[j] = bp[j];
#pragma unroll
  for (int p = 0; p < 4; ++p) {
    u16x8 v = ((const u16x8*)parts)[(size_t)p * 524288 + i];
#pragma unroll
    for (int j = 0; j < 8; ++j) s[j] += bf2f(v[j]);
  }
  float* dp = dst + (size_t)i * 8;
#pragma unroll
  for (int j = 0; j < 8; ++j) dp[j] = s[j];
}

// ---------------- RoPE from split-K parts + pack Q/K/V + emit new_k/new_v ----------------
__global__ __launch_bounds__(256) void rope_k(
    const float* __restrict__ p0, const float* __restrict__ p1,
    const float* __restrict__ cosb, const float* __restrict__ sinb,
    const float* __restrict__ bq, const float* __restrict__ bk, const float* __restrict__ bv,
    u16* __restrict__ QR, u16* __restrict__ KR, u16* __restrict__ VB,
    float* __restrict__ NK, float* __restrict__ NV) {
  const int s = blockIdx.x, b = blockIdx.y, t = threadIdx.x;
  const size_t tok = (size_t)b * 1024 + s;
  const float* r0 = p0 + tok * 3072;
  const float* r1 = p1 + tok * 3072;
  const float* cr = cosb + s * 128;
  const float* sr = sinb + s * 128;
  for (int i = t; i < 1024; i += 256) {
    const int h = i >> 6, d = i & 63;
    const float v1 = r0[h * 128 + d] + r1[h * 128 + d] + bq[h * 128 + d];
    const float v2 = r0[h * 128 + d + 64] + r1[h * 128 + d + 64] + bq[h * 128 + d + 64];
    const float o1 = v1 * cr[d] - v2 * sr[d];
    const float o2 = v2 * cr[d + 64] + v1 * sr[d + 64];
    const size_t qb = (((size_t)(b * 16 + h)) * 1024 + s) * 128;
    QR[qb + d] = f2bf(o1);
    QR[qb + d + 64] = f2bf(o2);
  }
  {
    const int h = t >> 6, d = t & 63;
    const float v1 = r0[2048 + h * 128 + d] + r1[2048 + h * 128 + d] + bk[h * 128 + d];
    const float v2 = r0[2048 + h * 128 + d + 64] + r1[2048 + h * 128 + d + 64] + bk[h * 128 + d + 64];
    const float o1 = v1 * cr[d] - v2 * sr[d];
    const float o2 = v2 * cr[d + 64] + v1 * sr[d + 64];
    const size_t kb = (((size_t)(b * 4 + h)) * 1024 + s) * 128;
    KR[kb + d] = f2bf(o1);
    KR[kb + d + 64] = f2bf(o2);
    const size_t ob = tok * 2048;
#pragma unroll
    for (int rep = 0; rep < 4; ++rep) {
      NK[ob + (h * 4 + rep) * 128 + d] = o1;
      NK[ob + (h * 4 + rep) * 128 + d + 64] = o2;
    }
  }
  for (int i = t; i < 512; i += 256) {
    const int h = i >> 7, d = i & 127;
    const float v = r0[2560 + i] + r1[2560 + i] + bv[i];
    VB[(((size_t)(b * 4 + h)) * 1024 + s) * 128 + d] = f2bf(v);
    const size_t ob = tok * 2048;
#pragma unroll
    for (int rep = 0; rep < 4; ++rep) NV[ob + (h * 4 + rep) * 128 + d] = v;
  }
}

// ---------------- Flash attention, 64 q-rows per block ----------------
__global__ __launch_bounds__(256) void attn_k(const u16* __restrict__ Q,
                                              const u16* __restrict__ Kc,
                                              const u16* __restrict__ Vc,
                                              u16* __restrict__ O) {
  const int qt = blockIdx.x, h = blockIdx.y, b = blockIdx.z;
  const int t = threadIdx.x, w = t >> 6, l = t & 63;
  const int kvh = h >> 2;
  __shared__ u16 Ks[64 * 128];
  __shared__ u16 Vt[128 * 66];
  __shared__ u16 Ps[4][16 * 68];
  const int l15 = l & 15, l4 = l >> 4;
  bf16x8 qf[4];
  {
    const u16* qb = Q + (((size_t)(b * 16 + h)) * 1024 + qt * 64 + w * 16 + l15) * 128 + l4 * 8;
#pragma unroll
    for (int c = 0; c < 4; ++c) qf[c] = *(const bf16x8*)(qb + c * 32);
  }
  float m_run[4] = {-1e30f, -1e30f, -1e30f, -1e30f};
  float l_run[4] = {0.f, 0.f, 0.f, 0.f};
  f32x4 accO[8] = {};
  const size_t kvbase = ((size_t)(b * 4 + kvh)) * 1024 * 128;
  const int ntiles = qt + 1;
  for (int kt = 0; kt < ntiles; ++kt) {
    __syncthreads();
    {
      const int key = t >> 2;
      const u16* kg = Kc + kvbase + (size_t)(kt * 64 + key) * 128;
      const u16* vg = Vc + kvbase + (size_t)(kt * 64 + key) * 128;
      const int sw = (key & 7) << 4;
#pragma unroll
      for (int p = 0; p < 4; ++p) {
        const int ch = (t & 3) * 4 + p;
        *(u16x8*)((char*)Ks + key * 256 + ((ch * 16) ^ sw)) = *(const u16x8*)(kg + ch * 8);
        const int d0 = ch * 8;
        u16x8 vv = *(const u16x8*)(vg + d0);
#pragma unroll
        for (int j = 0; j < 8; ++j) Vt[(d0 + j) * 66 + key] = vv[j];
      }
    }
    __syncthreads();
    f32x4 sf[4] = {};
#pragma unroll
    for (int nf = 0; nf < 4; ++nf) {
      const int keyl = nf * 16 + l15;
      const int sw = (keyl & 7) << 4;
      const char* kbase = (const char*)Ks + keyl * 256;
#pragma unroll
      for (int c = 0; c < 4; ++c) {
        bf16x8 kf = *(const bf16x8*)(kbase + ((c * 64 + l4 * 16) ^ sw));
        sf[nf] = __builtin_amdgcn_mfma_f32_16x16x32_bf16(qf[c], kf, sf[nf], 0, 0, 0);
      }
    }
    const int qg0 = qt * 64 + w * 16 + l4 * 4;
    float alpha[4];
#pragma unroll
    for (int r = 0; r < 4; ++r) {
      const int qg = qg0 + r;
      float tm = -1e30f;
#pragma unroll
      for (int nf = 0; nf < 4; ++nf) {
        const int kg = kt * 64 + nf * 16 + l15;
        float sv = sf[nf][r] * 0.088388347648318447f;
        sv = (kg <= qg) ? sv : -1e30f;
        sf[nf][r] = sv;
        tm = fmaxf(tm, sv);
      }
#pragma unroll
      for (int mm = 1; mm < 16; mm <<= 1) tm = fmaxf(tm, __shfl_xor(tm, mm));
      const float mn = fmaxf(m_run[r], tm);
      alpha[r] = __expf(m_run[r] - mn);
      m_run[r] = mn;
      float rs = 0.f;
#pragma unroll
      for (int nf = 0; nf < 4; ++nf) {
        const float p = __expf(sf[nf][r] - mn);
        sf[nf][r] = p;
        rs += p;
      }
#pragma unroll
      for (int mm = 1; mm < 16; mm <<= 1) rs += __shfl_xor(rs, mm);
      l_run[r] = l_run[r] * alpha[r] + rs;
    }
#pragma unroll
    for (int nf = 0; nf < 8; ++nf)
#pragma unroll
      for (int r = 0; r < 4; ++r) accO[nf][r] *= alpha[r];
#pragma unroll
    for (int nf = 0; nf < 4; ++nf)
#pragma unroll
      for (int r = 0; r < 4; ++r)
        Ps[w][(l4 * 4 + r) * 68 + nf * 16 + l15] = f2bf(sf[nf][r]);
    __syncthreads();
#pragma unroll
    for (int kc = 0; kc < 2; ++kc) {
      const u16* pb = &Ps[w][0] + l15 * 68 + kc * 32 + l4 * 8;
      union { u16x4 q[2]; bf16x8 v; } pu;
      pu.q[0] = *(const u16x4*)pb;
      pu.q[1] = *(const u16x4*)(pb + 4);
#pragma unroll
      for (int nf = 0; nf < 8; ++nf) {
        const int dd = nf * 16 + l15;
        const u16* vp = &Vt[0] + dd * 66 + kc * 32 + l4 * 8;
        union { u32 u[4]; bf16x8 v; } vu;
        vu.u[0] = *(const u32*)(vp);
        vu.u[1] = *(const u32*)(vp + 2);
        vu.u[2] = *(const u32*)(vp + 4);
        vu.u[3] = *(const u32*)(vp + 6);
        accO[nf] = __builtin_amdgcn_mfma_f32_16x16x32_bf16(pu.v, vu.v, accO[nf], 0, 0, 0);
      }
    }
  }
  const int qg0 = qt * 64 + w * 16 + l4 * 4;
#pragma unroll
  for (int nf = 0; nf < 8; ++nf) {
    const int dd = nf * 16 + l15;
#pragma unroll
    for (int r = 0; r < 4; ++r) {
      const float o = accO[nf][r] / l_run[r];
      O[((size_t)(b * 1024 + qg0 + r)) * 2048 + h * 128 + dd] = f2bf(o);
    }
  }
}

// ---------------- Router ----------------
__global__ __launch_bounds__(256) void router_k(
    const float* __restrict__ x2, const float* __restrict__ wn, const float* __restrict__ rw,
    int* __restrict__ topi2, float* __restrict__ topw2,
    int* __restrict__ counts, u64* __restrict__ pmean) {
  const int t = threadIdx.x, w = t >> 6, l = t & 63;
  const int tok = blockIdx.x * 4 + w;
  __shared__ int lc[8];
  __shared__ u64 lp[8];
  if (t < 8) { lc[t] = 0; lp[t] = 0ull; }
  __syncthreads();
  const float* xr = x2 + (size_t)tok * DD;
  float ss = 0.f;
#pragma unroll
  for (int i = 0; i < 8; ++i) {
    float4 v = *(const float4*)(xr + l * 32 + i * 4);
    ss += v.x * v.x + v.y * v.y + v.z * v.z + v.w * v.w;
  }
#pragma unroll
  for (int m = 1; m < 64; m <<= 1) ss += __shfl_xor(ss, m);
  const float sc = rsqrtf(ss * (1.f / DD) + 1e-6f);
  float acc[8] = {};
  for (int i = 0; i < 32; ++i) {
    const int d = l * 32 + i;
    const float hv = xr[d] * sc * wn[d];
    float4 r0 = *(const float4*)(rw + d * 8);
    float4 r1 = *(const float4*)(rw + d * 8 + 4);
    acc[0] += hv * r0.x; acc[1] += hv * r0.y; acc[2] += hv * r0.z; acc[3] += hv * r0.w;
    acc[4] += hv * r1.x; acc[5] += hv * r1.y; acc[6] += hv * r1.z; acc[7] += hv * r1.w;
  }
#pragma unroll
  for (int m = 1; m < 64; m <<= 1)
#pragma unroll
    for (int e = 0; e < 8; ++e) acc[e] += __shfl_xor(acc[e], m);
  if (l == 0) {
    float mx = acc[0];
#pragma unroll
    for (int e = 1; e < 8; ++e) mx = fmaxf(mx, acc[e]);
    float p[8], sum = 0.f;
#pragma unroll
    for (int e = 0; e < 8; ++e) { p[e] = __expf(acc[e] - mx); sum += p[e]; }
    const float inv = 1.f / sum;
#pragma unroll
    for (int e = 0; e < 8; ++e) p[e] *= inv;
    int e0 = 0; float v0 = p[0];
#pragma unroll
    for (int e = 1; e < 8; ++e) if (p[e] > v0) { v0 = p[e]; e0 = e; }
    int e1 = (e0 == 0) ? 1 : 0; float v1 = p[e1];
#pragma unroll
    for (int e = 0; e < 8; ++e) if (e != e0 && p[e] > v1) { v1 = p[e]; e1 = e; }
    const float wsum = v0 + v1;
    topi2[tok * 2] = e0; topi2[tok * 2 + 1] = e1;
    topw2[tok * 2] = v0 / wsum; topw2[tok * 2 + 1] = v1 / wsum;
    atomicAdd(&lc[e0], 1); atomicAdd(&lc[e1], 1);
#pragma unroll
    for (int e = 0; e < 8; ++e) atomicAdd(&lp[e], (u64)((double)p[e] * 4294967296.0));
  }
  __syncthreads();
  if (t < 8) {
    if (lc[t]) atomicAdd(&counts[t], lc[t]);
    if (lp[t]) atomicAdd(&pmean[t], lp[t]);
  }
}

__global__ __launch_bounds__(256) void zero_k(int* __restrict__ counts, u64* __restrict__ pmean,
                                              int* __restrict__ slot_tok, float* __restrict__ slot_w) {
  const int i = blockIdx.x * 256 + threadIdx.x;
  if (i < 5120) { slot_tok[i] = 0; slot_w[i] = 0.f; }
  if (i < 8) { counts[i] = 0; pmean[i] = 0ull; }
}

__global__ void scan_k(const int* __restrict__ counts, int* __restrict__ cursors,
                       int* __restrict__ tiletab, const u64* __restrict__ pmean,
                       float* __restrict__ auxout) {
  if (threadIdx.x == 0) {
    int off = 0, nt = 0;
    double aux = 0.0;
    for (int e = 0; e < 8; ++e) {
      cursors[e] = off;
      const int c = counts[e];
      const int nte = (c + 127) >> 7;
      for (int i = 0; i < nte; ++i) {
        tiletab[1 + nt * 2] = e;
        tiletab[2 + nt * 2] = off + i * 128;
        ++nt;
      }
      off += nte * 128;
      const double pm = ((double)pmean[e] / 4294967296.0) / 2048.0;
      aux += ((double)c / 4096.0) * pm;
    }
    tiletab[0] = nt;
    *auxout = (float)(8.0 * aux);
  }
}

__global__ __launch_bounds__(256) void assign_k(const int* __restrict__ topi2,
                                                const float* __restrict__ topw2,
                                                int* __restrict__ cursors,
                                                int* __restrict__ slot_tok,
                                                float* __restrict__ slot_w,
                                                int* __restrict__ tok_slot) {
  const int tok = blockIdx.x * 256 + threadIdx.x;
#pragma unroll
  for (int j = 0; j < 2; ++j) {
    const int e = topi2[tok * 2 + j];
    const int s = atomicAdd(&cursors[e], 1);
    slot_tok[s] = tok;
    slot_w[s] = topw2[tok * 2 + j];
    tok_slot[tok * 2 + j] = s;
  }
}

__global__ __launch_bounds__(256) void final_k(float* __restrict__ out,
                                               const u16* __restrict__ routed,
                                               const int* __restrict__ tok_slot) {
  const int tok = blockIdx.x, t = threadIdx.x;
  const int s0 = tok_slot[tok * 2], s1 = tok_slot[tok * 2 + 1];
  u16x8 a = ((const u16x8*)(routed + (size_t)s0 * DD))[t];
  u16x8 b = ((const u16x8*)(routed + (size_t)s1 * DD))[t];
  float* o = out + (size_t)tok * DD + t * 8;
  float4 o0 = *(const float4*)o;
  float4 o1 = *(const float4*)(o + 4);
  o0.x += bf2f(a[0]) + bf2f(b[0]); o0.y += bf2f(a[1]) + bf2f(b[1]);
  o0.z += bf2f(a[2]) + bf2f(b[2]); o0.w += bf2f(a[3]) + bf2f(b[3]);
  o1.x += bf2f(a[4]) + bf2f(b[4]); o1.y += bf2f(a[5]) + bf2f(b[5]);
  o1.z += bf2f(a[6]) + bf2f(b[6]); o1.w += bf2f(a[7]) + bf2f(b[7]);
  *(float4*)o = o0;
  *(float4*)(o + 4) = o1;
}

extern "C" void kernel_launch(void* const* d_in, const int* in_sizes, int n_in,
                              void* d_out, int out_size, void* d_ws, size_t ws_size,
                              hipStream_t stream) {
  (void)in_sizes; (void)n_in; (void)out_size; (void)ws_size;
  const float* x    = (const float*)d_in[0];
  const float* rc   = (const float*)d_in[1];
  const float* rs   = (const float*)d_in[2];
  const float* anw  = (const float*)d_in[3];
  const float* fnw  = (const float*)d_in[4];
  const float* wq   = (const float*)d_in[5];
  const float* bq   = (const float*)d_in[6];
  const float* wk   = (const float*)d_in[7];
  const float* bk   = (const float*)d_in[8];
  const float* wv   = (const float*)d_in[9];
  const float* bv   = (const float*)d_in[10];
  const float* wo   = (const float*)d_in[11];
  const float* rw   = (const float*)d_in[12];
  const float* wg   = (const float*)d_in[13];
  const float* wu   = (const float*)d_in[14];
  const float* wd   = (const float*)d_in[15];
  const float* wsg  = (const float*)d_in[16];
  const float* wsu  = (const float*)d_in[17];
  const float* wsd  = (const float*)d_in[18];

  const size_t MB = (size_t)1 << 20;
  char* ws = (char*)d_ws;
  float* X2  = (float*)(ws + 0);          // 16 MiB
  u16*   HN  = (u16*)(ws + 16 * MB);      // 8 MiB
  char*  SM  = ws + 24 * MB;              // 1 MiB small
  char*  AR  = ws + 25 * MB;              // 123 MiB arena

  int*   CNT   = (int*)(SM);
  u64*   PM    = (u64*)(SM + 64);
  int*   CURS  = (int*)(SM + 256);
  int*   TILT  = (int*)(SM + 512);
  int*   TOPI  = (int*)(SM + 4096);
  float* TOPW  = (float*)(SM + 40960);
  int*   STOK  = (int*)(SM + 73728);
  float* SW    = (float*)(SM + 98304);
  int*   TSLOT = (int*)(SM + 131072);

  // P1 (qkv): H@0(8) WTQ@8(12) PARTSQ@20(48)
  u16*   H      = (u16*)(AR);
  u16*   WTQ    = (u16*)(AR + 8 * MB);
  float* PARTSQ = (float*)(AR + 20 * MB);
  // P2 (attn): ATTNO@0(8, over H) QR@68(8) KR@76(2) VB@78(2)
  u16*   ATTNO = (u16*)(AR);
  u16*   QR    = (u16*)(AR + 68 * MB);
  u16*   KR    = (u16*)(AR + 76 * MB);
  u16*   VBb   = (u16*)(AR + 78 * MB);
  // P3 (wo): WTO@8?  use AR+8 (over WTQ); PARTSW@16(64)
  u16*   WTO    = (u16*)(AR + 8 * MB);
  float* PARTSW = (float*)(AR + 16 * MB);
  // P5 (shared expert): G@0(43) WTSg@43(16) WTSu@59(16) | WTSd@43(43) PARTSD@86(32)
  u16*   G      = (u16*)(AR);
  u16*   WTSg   = (u16*)(AR + 43 * MB);
  u16*   WTSu   = (u16*)(AR + 59 * MB);
  u16*   WTSd   = (u16*)(AR + 43 * MB);
  u16*   PARTSD = (u16*)(AR + 86 * MB);
  // P6 (routed experts): WTE@0(64) GEXP@64(20) ROUTED@84(20)
  u16*   WTE    = (u16*)(AR);
  u16*   GEXP   = (u16*)(AR + 64 * MB);
  u16*   ROUTED = (u16*)(AR + 84 * MB);

  float* out  = (float*)d_out;
  float* NK   = out + 4194304;
  float* NV   = out + 2 * 4194304;
  float* AUXO = out + 3 * 4194304;

  const dim3 b256(256);
  const dim3 b512(512);

  // P1: attn rmsnorm + QKV projection (gemm8 split-K x2, rope consumes parts directly)
  rmsnorm_k<<<TT, b256, 0, stream>>>(x, anw, H);
  transp_k<<<dim3(32, 32, 1), b256, 0, stream>>>(wq, WTQ, 2048, 2048);
  transp_k<<<dim3(8, 32, 1), b256, 0, stream>>>(wk, WTQ + (size_t)2048 * 2048, 2048, 512);
  transp_k<<<dim3(8, 32, 1), b256, 0, stream>>>(wv, WTQ + (size_t)2560 * 2048, 2048, 512);
  gemm8<11, true><<<dim3(12, 8, 2), b512, 0, stream>>>(H, WTQ, PARTSQ, nullptr, TT, 3072, 2048, 1024);
  // P2: rope (adds the two K-parts) + attention
  rope_k<<<dim3(1024, 2), b256, 0, stream>>>(PARTSQ, PARTSQ + (size_t)TT * 3072, rc, rs,
                                             bq, bk, bv, QR, KR, VBb, NK, NV);
  attn_k<<<dim3(16, 16, 2), b256, 0, stream>>>(QR, KR, VBb, ATTNO);
  // P3: x2 = x + attno @ wo (gemm8 split-K x4)
  transp_k<<<dim3(32, 32, 1), b256, 0, stream>>>(wo, WTO, 2048, 2048);
  gemm8<11, true><<<dim3(8, 8, 4), b512, 0, stream>>>(ATTNO, WTO, PARTSW, nullptr, TT, 2048, 2048, 512);
  red_k<4, true><<<4096, b256, 0, stream>>>(X2, x, PARTSW, 1048576);
  // P4: ffn rmsnorm + routing
  rmsnorm_k<<<TT, b256, 0, stream>>>(X2, fnw, HN);
  zero_k<<<20, b256, 0, stream>>>(CNT, PM, STOK, SW);
  router_k<<<512, b256, 0, stream>>>(X2, fnw, rw, TOPI, TOPW, CNT, PM);
  scan_k<<<1, 64, 0, stream>>>(CNT, CURS, TILT, PM, AUXO);
  assign_k<<<8, b256, 0, stream>>>(TOPI, TOPW, CURS, STOK, SW, TSLOT);
  // P5: shared expert — fused gate+up in 3 column groups, then down (split-K x4)
  {
    const int cg[4] = {0, 3712, 7424, 11008};
    for (int gi = 0; gi < 3; ++gi) {
      const int c0 = cg[gi], wgrp = cg[gi + 1] - c0, ngc = wgrp >> 7;
      transp_k<<<dim3(wgrp / 64, 32, 1), b256, 0, stream>>>(wsg + c0, WTSg, 2048, FSH);
      transp_k<<<dim3(wgrp / 64, 32, 1), b256, 0, stream>>>(wsu + c0, WTSu, 2048, FSH);
      gemm_gu<<<dim3(ngc, 8, 1), b512, 0, stream>>>(HN, WTSg, WTSu, G, 2048, FSH, c0);
    }
  }
  transp_k<<<dim3(32, 172, 1), b256, 0, stream>>>(wsd, WTSd, FSH, 2048);
  gemm8<10, true><<<dim3(8, 8, 4), b512, 0, stream>>>(G, WTSd, PARTSD, nullptr, TT, 2048, FSH, 2816);
  redbf_k<<<2048, b256, 0, stream>>>(out, X2, PARTSD);
  // P6: routed experts (128^2, padded tile table)
  transp_k<<<dim3(32, 32, 8), b256, 0, stream>>>(wg, WTE, 2048, 2048);
  gemm2<2, true, true, false><<<dim3(16, 40, 1), b256, 0, stream>>>(
      HN, WTE, GEXP, nullptr, nullptr, STOK, TILT, 5120, 2048, 2048, 0);
  transp_k<<<dim3(32, 32, 8), b256, 0, stream>>>(wu, WTE, 2048, 2048);
  gemm2<3, true, true, false><<<dim3(16, 40, 1), b256, 0, stream>>>(
      HN, WTE, GEXP, GEXP, nullptr, STOK, TILT, 5120, 2048, 2048, 0);
  transp_k<<<dim3(32, 32, 8), b256, 0, stream>>>(wd, WTE, 2048, 2048);
  gemm2<4, true, false, false><<<dim3(16, 40, 1), b256, 0, stream>>>(
      GEXP, WTE, ROUTED, nullptr, SW, STOK, TILT, 5120, 2048, 2048, 0);
  // P7: out += routed
  final_k<<<TT, b256, 0, stream>>>(out, ROUTED, TSLOT);
}